// Round 8
// baseline (289.867 us; speedup 1.0000x reference)
//
#include <hip/hip_runtime.h>
#include <math.h>

// Problem dims
#define Bn 8
#define Cn 64
#define Hn 128
#define Wn 128
#define HWn 16384

typedef __attribute__((ext_vector_type(8))) __bf16 bf16x8;
typedef __attribute__((ext_vector_type(4))) __bf16 bf16x4;
typedef __attribute__((ext_vector_type(4))) float f32x4;

// XCD-aware bijective swizzle: grid = 8*chunk blocks; XCD k (bid%8) gets the
// contiguous work range [k*chunk,(k+1)*chunk) => per-XCD L2-resident slice.
__device__ __forceinline__ int xcd_swz(int bid, int chunk) {
  return (bid & 7) * chunk + (bid >> 3);
}

// ---------------------------------------------------------------------------
// K0: beff (collapsed ELK bias) only.
// ---------------------------------------------------------------------------
__global__ void k_prep(const float* __restrict__ w1, const float* __restrict__ b3,
                       const float* __restrict__ b15, const float* __restrict__ b51,
                       const float* __restrict__ b1, float* __restrict__ beff)
{
  int e = threadIdx.x;
  if (e >= 64) return;
  float s = b1[e];
  for (int m = 0; m < 64; m++) {
    s = fmaf(w1[e * 192 + m],       b3[m],  s);
    s = fmaf(w1[e * 192 + 64 + m],  b15[m], s);
    s = fmaf(w1[e * 192 + 128 + m], b51[m], s);
  }
  beff[e] = s;
}

// ---------------------------------------------------------------------------
// K-xt: x (NCHW f32) -> xT[b][hp134][wp134][c64] bf16 (3-pad ring)
//                    -> xC[b][oct8][hp134][slot144][8ch] bf16 (conv1 staging)
// ---------------------------------------------------------------------------
__global__ __launch_bounds__(256) void k_xt(const float* __restrict__ x,
                                            __bf16* __restrict__ xT,
                                            __bf16* __restrict__ xC)
{
  int t = blockIdx.x * 256 + threadIdx.x;
  if (t >= 8 * 134 * 134) return;
  int wp = t % 134;
  int hp = (t / 134) % 134;
  int b  = t / (134 * 134);
  int h = hp - 3, w = wp - 3;
  bool inb = ((unsigned)h < 128u) && ((unsigned)w < 128u);
  const float* xb = x + (size_t)b * Cn * HWn + h * 128 + w;
  __bf16* dst = xT + (size_t)t * 64;
#pragma unroll
  for (int oct = 0; oct < 8; oct++) {
    bf16x8 v;
#pragma unroll
    for (int j = 0; j < 8; j++)
      v[j] = inb ? (__bf16)xb[(size_t)(oct * 8 + j) * HWn] : (__bf16)0.f;
    *(bf16x8*)(dst + oct * 8) = v;
    *(bf16x8*)(xC + ((((size_t)b * 8 + oct) * 134 + hp) * 144 + wp) * 8) = v;
  }
}

// ---------------------------------------------------------------------------
// K-wf: stn_w1 -> A-fragment layout for conv1 MFMA.
// ---------------------------------------------------------------------------
__global__ __launch_bounds__(256) void k_wf(const float* __restrict__ stn_w1,
                                            __bf16* __restrict__ wfrag)
{
  int t = blockIdx.x * 256 + threadIdx.x;
  if (t >= 100352) return;
  int e   = t & 7;
  int l   = (t >> 3) & 63;
  int o16 = (t >> 9) & 1;
  int ck  = (t >> 10) & 1;
  int tap = t >> 11;
  int o = o16 * 16 + (l & 15);
  int c = ck * 32 + (l >> 4) * 8 + e;
  wfrag[t] = (__bf16)stn_w1[(o * 64 + c) * 49 + tap];
}

// ---------------------------------------------------------------------------
// K-frag: A-fragments for DCN (9 taps), collapsed ELK (13 taps), conv2 (25 taps).
// ---------------------------------------------------------------------------
__global__ __launch_bounds__(256) void k_frag(
    const float* __restrict__ dcn_w, const float* __restrict__ w1,
    const float* __restrict__ w3, const float* __restrict__ w15,
    const float* __restrict__ w51, const float* __restrict__ stn_w2,
    __bf16* __restrict__ dcnD, __bf16* __restrict__ weffD,
    __bf16* __restrict__ w2frag)
{
  int t = blockIdx.x * 256 + threadIdx.x;
  if (t < 36864) {
    int e = t & 7, l = (t >> 3) & 63, mf = (t >> 9) & 3, s = (t >> 11) & 1;
    int tap = t >> 12;
    int o = mf * 16 + (l & 15), c = s * 32 + (l >> 4) * 8 + e;
    dcnD[t] = (__bf16)dcn_w[(o * 64 + c) * 9 + tap];
    return;
  }
  t -= 36864;
  if (t < 53248) {
    const int DY[13] = {-2,-1,-1,-1, 0, 0, 0, 0, 0, 1, 1, 1, 2};
    const int DX[13] = { 0,-1, 0, 1,-2,-1, 0, 1, 2,-1, 0, 1, 0};
    int e = t & 7, l = (t >> 3) & 63, mf = (t >> 9) & 3, s = (t >> 11) & 1;
    int tap = t >> 12;
    int o = mf * 16 + (l & 15), c = s * 32 + (l >> 4) * 8 + e;
    int dy = DY[tap], dx = DX[tap];
    float v = 0.f;
    if (dy >= -1 && dy <= 1 && dx >= -1 && dx <= 1) {
      int k3 = (dy + 1) * 3 + (dx + 1);
      for (int m = 0; m < 64; m++) v = fmaf(w1[o * 192 + m], w3[(m * 64 + c) * 9 + k3], v);
    }
    if (dy == 0) {
      int k15 = dx + 2;
      for (int m = 0; m < 64; m++) v = fmaf(w1[o * 192 + 64 + m], w15[(m * 64 + c) * 5 + k15], v);
    }
    if (dx == 0) {
      int k51 = dy + 2;
      for (int m = 0; m < 64; m++) v = fmaf(w1[o * 192 + 128 + m], w51[(m * 64 + c) * 5 + k51], v);
    }
    weffD[t] = (__bf16)v;
    return;
  }
  t -= 53248;
  if (t < 51200) {   // conv2 A-frags: [tap25][mf4][lane64][e8]
    int e = t & 7, l = (t >> 3) & 63, mf = (t >> 9) & 3;
    int tap = t >> 11;
    int o = mf * 16 + (l & 15), c = (l >> 4) * 8 + e;
    w2frag[t] = (__bf16)stn_w2[(o * 32 + c) * 25 + tap];
  }
}

// ---------------------------------------------------------------------------
// K1: STN conv1 via MFMA, contiguous 1KB global_load_lds staging from xC.
// ---------------------------------------------------------------------------
__global__ __launch_bounds__(128) void k_conv1m(
    const __bf16* __restrict__ xC, const __bf16* __restrict__ wfrag,
    const float* __restrict__ b1s, __bf16* __restrict__ t1T)
{
  __shared__ alignas(16) char tile[73728];   // [q4][r8][slot144][16B]
  const int lane = threadIdx.x & 63;
  const int wv   = threadIdx.x >> 6;
  const int swz  = xcd_swz(blockIdx.x, 64);
  const int b    = swz >> 6;
  const int h0   = (swz & 63) * 2;

  f32x4 acc[2][8];
#pragma unroll
  for (int o16 = 0; o16 < 2; o16++)
#pragma unroll
    for (int nf = 0; nf < 8; nf++) acc[o16][nf] = (f32x4){0.f, 0.f, 0.f, 0.f};

  const bf16x8* wf = (const bf16x8*)wfrag;
  const char* tb = (const char*)tile;
  const char* xCb = (const char*)xC;

  for (int ck = 0; ck < 2; ck++) {
    for (int i = wv; i < 72; i += 2) {
      int q = i / 18;
      int t = i - q * 18;
      const char* src = xCb
          + (((size_t)(b * 8 + ck * 4 + q) * 134 + h0) * 2304) + t * 1024 + lane * 16;
      char* dst = (char*)tile + i * 1024;
      __builtin_amdgcn_global_load_lds(
          (const __attribute__((address_space(1))) void*)src,
          (__attribute__((address_space(3))) void*)dst, 16, 0, 0);
    }
    __syncthreads();

    for (int tap = 0; tap < 49; tap++) {
      int dy7 = tap / 7;
      int dx7 = tap - dy7 * 7;
      bf16x8 a0 = wf[((tap * 2 + ck) * 2 + 0) * 64 + lane];
      bf16x8 a1 = wf[((tap * 2 + ck) * 2 + 1) * 64 + lane];
      const char* bp = tb + (lane >> 4) * 18432 + (wv + dy7) * 2304
                          + (dx7 + (lane & 15)) * 16;
#pragma unroll
      for (int nf = 0; nf < 8; nf++) {
        bf16x8 bv = *(const bf16x8*)(bp + nf * 256);
        acc[0][nf] = __builtin_amdgcn_mfma_f32_16x16x32_bf16(a0, bv, acc[0][nf], 0, 0, 0);
        acc[1][nf] = __builtin_amdgcn_mfma_f32_16x16x32_bf16(a1, bv, acc[1][nf], 0, 0, 0);
      }
    }
    __syncthreads();
  }

  int h = h0 + wv;
#pragma unroll
  for (int o16 = 0; o16 < 2; o16++) {
    int ob = o16 * 16 + ((lane >> 4) << 2);
    float bb0 = b1s[ob], bb1 = b1s[ob + 1], bb2 = b1s[ob + 2], bb3 = b1s[ob + 3];
#pragma unroll
    for (int nf = 0; nf < 8; nf++) {
      int px = nf * 16 + (lane & 15);
      bf16x4 r;
      r[0] = (__bf16)fmaxf(acc[o16][nf][0] + bb0, 0.f);
      r[1] = (__bf16)fmaxf(acc[o16][nf][1] + bb1, 0.f);
      r[2] = (__bf16)fmaxf(acc[o16][nf][2] + bb2, 0.f);
      r[3] = (__bf16)fmaxf(acc[o16][nf][3] + bb3, 0.f);
      *(bf16x4*)(t1T + (((size_t)(b * 128 + h) * 128 + px)) * 32 + ob) = r;
    }
  }
}

// ---------------------------------------------------------------------------
// K2: maxpool 2x2 -> p1T[b][hp68][wp68][32ch] bf16, zero-padded 2 ring.
// ---------------------------------------------------------------------------
__global__ __launch_bounds__(256) void k_pool(const __bf16* __restrict__ t1T,
                                              __bf16* __restrict__ p1T)
{
  int id = blockIdx.x * 256 + threadIdx.x;
  if (id >= 8 * 68 * 68) return;
  int wp = id % 68, hp = (id / 68) % 68, b = id / (68 * 68);
  __bf16* dst = p1T + (size_t)id * 32;
  int ph = hp - 2, pw = wp - 2;
  if (((unsigned)ph >= 64u) || ((unsigned)pw >= 64u)) {
    bf16x8 z = {};
#pragma unroll
    for (int g = 0; g < 4; g++) *(bf16x8*)(dst + g * 8) = z;
    return;
  }
  const __bf16* s = t1T + (((size_t)(b * 128) + ph * 2) * 128 + pw * 2) * 32;
#pragma unroll
  for (int g = 0; g < 4; g++) {
    bf16x8 v0 = *(const bf16x8*)(s + g * 8);
    bf16x8 v1 = *(const bf16x8*)(s + 32 + g * 8);
    bf16x8 v2 = *(const bf16x8*)(s + 4096 + g * 8);
    bf16x8 v3 = *(const bf16x8*)(s + 4128 + g * 8);
    bf16x8 r;
#pragma unroll
    for (int j = 0; j < 8; j++) {
      float m = fmaxf(fmaxf((float)v0[j], (float)v1[j]),
                      fmaxf((float)v2[j], (float)v3[j]));
      r[j] = (__bf16)m;
    }
    *(bf16x8*)(dst + g * 8) = r;
  }
}

// ---------------------------------------------------------------------------
// K3: conv2 via MFMA.
// ---------------------------------------------------------------------------
__global__ __launch_bounds__(256) void k_conv2m(
    const __bf16* __restrict__ p1T, const __bf16* __restrict__ w2frag,
    const float* __restrict__ b2s, float* __restrict__ t2)
{
  __shared__ alignas(16) char tile[34816];   // 8*68*64
  const int lane = threadIdx.x & 63;
  const int wv   = threadIdx.x >> 6;
  const int b    = blockIdx.x >> 4;
  const int h0   = (blockIdx.x & 15) * 4;

  f32x4 acc[4][4];
#pragma unroll
  for (int mf = 0; mf < 4; mf++)
#pragma unroll
    for (int nf = 0; nf < 4; nf++) acc[mf][nf] = (f32x4){0.f, 0.f, 0.f, 0.f};

  const char* src0 = (const char*)p1T + (((size_t)b * 68 + h0) * 68) * 64;
  for (int i = wv; i < 34; i += 4) {
    __builtin_amdgcn_global_load_lds(
        (const __attribute__((address_space(1))) void*)(src0 + i * 1024 + lane * 16),
        (__attribute__((address_space(3))) void*)((char*)tile + i * 1024), 16, 0, 0);
  }
  __syncthreads();

  const bf16x8* wf = (const bf16x8*)w2frag;
  const char* tb = (const char*)tile;
  for (int tap = 0; tap < 25; tap++) {
    int ky = tap / 5, kx = tap - ky * 5;
    bf16x8 a0 = wf[(tap * 4 + 0) * 64 + lane];
    bf16x8 a1 = wf[(tap * 4 + 1) * 64 + lane];
    bf16x8 a2 = wf[(tap * 4 + 2) * 64 + lane];
    bf16x8 a3 = wf[(tap * 4 + 3) * 64 + lane];
    const char* bp = tb + (((wv + ky) * 68 + kx + (lane & 15)) * 64) + (lane >> 4) * 16;
#pragma unroll
    for (int nf = 0; nf < 4; nf++) {
      bf16x8 bv = *(const bf16x8*)(bp + nf * 1024);
      acc[0][nf] = __builtin_amdgcn_mfma_f32_16x16x32_bf16(a0, bv, acc[0][nf], 0, 0, 0);
      acc[1][nf] = __builtin_amdgcn_mfma_f32_16x16x32_bf16(a1, bv, acc[1][nf], 0, 0, 0);
      acc[2][nf] = __builtin_amdgcn_mfma_f32_16x16x32_bf16(a2, bv, acc[2][nf], 0, 0, 0);
      acc[3][nf] = __builtin_amdgcn_mfma_f32_16x16x32_bf16(a3, bv, acc[3][nf], 0, 0, 0);
    }
  }

  int h = h0 + wv;
#pragma unroll
  for (int mf = 0; mf < 4; mf++) {
    int ob = mf * 16 + ((lane >> 4) << 2);
#pragma unroll
    for (int r = 0; r < 4; r++) {
      float bb = b2s[ob + r];
      float* orow = t2 + ((size_t)(b * 64 + ob + r)) * 4096 + h * 64 + (lane & 15);
#pragma unroll
      for (int nf = 0; nf < 4; nf++)
        orow[nf * 16] = fmaxf(acc[mf][nf][r] + bb, 0.f);
    }
  }
}

// ---------------------------------------------------------------------------
// K3b: deterministic spatial sum -> feat[b*64+co].
// ---------------------------------------------------------------------------
__global__ __launch_bounds__(256) void k_feat(const float* __restrict__ t2, float* __restrict__ feat)
{
  __shared__ float red[256];
  int bc = blockIdx.x;
  const float* s = t2 + (size_t)bc * 4096;
  float v = 0.f;
  for (int i = threadIdx.x; i < 4096; i += 256) v += s[i];
  red[threadIdx.x] = v;
  __syncthreads();
  for (int st = 128; st > 0; st >>= 1) {
    if (threadIdx.x < st) red[threadIdx.x] += red[threadIdx.x + st];
    __syncthreads();
  }
  if (threadIdx.x == 0) feat[bc] = red[0];
}

// ---------------------------------------------------------------------------
// K4: theta
// ---------------------------------------------------------------------------
__global__ void k_theta(const float* __restrict__ feat, const float* __restrict__ fc_w,
                        const float* __restrict__ fc_b, float* __restrict__ theta)
{
  int tid = threadIdx.x;
  if (tid >= 48) return;
  int b = tid / 6, i = tid - b * 6;
  float s = 0.f;
  for (int k = 0; k < 64; k++) s = fmaf(feat[b * 64 + k], fc_w[i * 64 + k], s);
  theta[tid] = fmaf(s, 1.f / 4096.f, fc_b[i]);
}

// ---------------------------------------------------------------------------
// K5: affine grid + bilinear sample from xT -> FsT. XCD swizzle chunk 64.
// ---------------------------------------------------------------------------
__global__ __launch_bounds__(256) void k_fs(const __bf16* __restrict__ xT,
                                            const float* __restrict__ theta,
                                            __bf16* __restrict__ FsT)
{
  int id = xcd_swz(blockIdx.x, 64) * 256 + threadIdx.x;
  int wi = id & 127, hi = (id >> 7) & 127, b = id >> 14;
  const float* t = theta + b * 6;
  float xn = (float)(2 * wi + 1) * (1.f / 128.f) - 1.f;
  float yn = (float)(2 * hi + 1) * (1.f / 128.f) - 1.f;
  float gx = t[0] * xn + t[1] * yn + t[2];
  float gy = t[3] * xn + t[4] * yn + t[5];
  float ix = fmaf(gx, 64.f, 63.5f);
  float iy = fmaf(gy, 64.f, 63.5f);

  float y0f = floorf(iy), x0f = floorf(ix);
  float wy1 = iy - y0f, wy0 = 1.f - wy1;
  float wx1 = ix - x0f, wx0 = 1.f - wx1;
  bool vy0 = (y0f >= 0.f) && (y0f <= 127.f);
  bool vy1 = (y0f >= -1.f) && (y0f <= 126.f);
  bool vx0 = (x0f >= 0.f) && (x0f <= 127.f);
  bool vx1 = (x0f >= -1.f) && (x0f <= 126.f);
  int yi0 = (int)fminf(fmaxf(y0f, 0.f), 127.f);
  int yi1 = (int)fminf(fmaxf(y0f + 1.f, 0.f), 127.f);
  int xi0 = (int)fminf(fmaxf(x0f, 0.f), 127.f);
  int xi1 = (int)fminf(fmaxf(x0f + 1.f, 0.f), 127.f);
  float w00 = wy0 * wx0 * ((vy0 && vx0) ? 1.f : 0.f);
  float w01 = wy0 * wx1 * ((vy0 && vx1) ? 1.f : 0.f);
  float w10 = wy1 * wx0 * ((vy1 && vx0) ? 1.f : 0.f);
  float w11 = wy1 * wx1 * ((vy1 && vx1) ? 1.f : 0.f);

  const __bf16* xb = xT + (size_t)b * 134 * 134 * 64;
  const __bf16* c00 = xb + ((size_t)(yi0 + 3) * 134 + xi0 + 3) * 64;
  const __bf16* c01 = xb + ((size_t)(yi0 + 3) * 134 + xi1 + 3) * 64;
  const __bf16* c10 = xb + ((size_t)(yi1 + 3) * 134 + xi0 + 3) * 64;
  const __bf16* c11 = xb + ((size_t)(yi1 + 3) * 134 + xi1 + 3) * 64;
  __bf16* dst = FsT + ((size_t)b * HWn + hi * 128 + wi) * 64;
#pragma unroll 2
  for (int oct = 0; oct < 8; oct++) {
    bf16x8 v00 = *(const bf16x8*)(c00 + oct * 8);
    bf16x8 v01 = *(const bf16x8*)(c01 + oct * 8);
    bf16x8 v10 = *(const bf16x8*)(c10 + oct * 8);
    bf16x8 v11 = *(const bf16x8*)(c11 + oct * 8);
    bf16x8 r;
#pragma unroll
    for (int j = 0; j < 8; j++) {
      float f = w00 * (float)v00[j] + w01 * (float)v01[j]
              + w10 * (float)v10[j] + w11 * (float)v11[j];
      r[j] = (__bf16)f;
    }
    *(bf16x8*)(dst + oct * 8) = r;
  }
}

// ---------------------------------------------------------------------------
// K6: deformable conv via MFMA — R7 restructure: NO LDS (operand swap).
// Wave = 16 px x 64 out. Lane (l&15)=pixel, (l>>4)=channel octet. Each lane
// bilinearly samples ch s*32+(l>>4)*8..+8 of its pixel -> the register IS the
// MFMA A-fragment (rows=pixels, k=channels). D = samples x W gives
// D[row=pixel][col=out-ch]; dcnD table works unchanged as the B operand.
// One memory round trip per tap (was 2 with the LDS transpose).
// 2048 blocks x 4 waves = 8192 waves. XCD swizzle chunk 256 => XCD = batch.
// ---------------------------------------------------------------------------
__global__ __launch_bounds__(256) void k_dcnm(
    const __bf16* __restrict__ xT, const float* __restrict__ off,
    const __bf16* __restrict__ dcnD, const float* __restrict__ dcn_b,
    __bf16* __restrict__ FdT)
{
  const int lane = threadIdx.x & 63;
  const int wv   = threadIdx.x >> 6;
  const int swz  = xcd_swz(blockIdx.x, 256);
  const int b    = swz >> 8;
  const int rem  = swz & 255;
  const int h    = rem >> 1;
  const int px0  = (rem & 1) * 64 + wv * 16;
  const int l15  = lane & 15;
  const int g    = lane >> 4;
  const int w    = px0 + l15;          // this lane's pixel (as A-row)

  f32x4 acc[4];
#pragma unroll
  for (int mf = 0; mf < 4; mf++) acc[mf] = (f32x4){0.f, 0.f, 0.f, 0.f};

  // hoist all 9 taps' offsets (dy,dx) for this pixel
  const float* ob = off + (size_t)b * 18 * HWn + h * 128 + w;
  float offs[18];
#pragma unroll
  for (int i = 0; i < 18; i++) offs[i] = ob[(size_t)i * HWn];

  const bf16x8* aD = (const bf16x8*)dcnD;
  const __bf16* xb = xT + (size_t)b * 134 * 134 * 64 + g * 8;  // + ch octet

  for (int k = 0; k < 9; k++) {
    float sy = (float)(h + k / 3 - 1) + offs[2 * k];
    float sx = (float)(w + (k % 3) - 1) + offs[2 * k + 1];

    float y0f = floorf(sy), x0f = floorf(sx);
    float wy1 = sy - y0f, wy0 = 1.f - wy1;
    float wx1 = sx - x0f, wx0 = 1.f - wx1;
    bool vy0 = (y0f >= 0.f) && (y0f <= 127.f);
    bool vy1 = (y0f >= -1.f) && (y0f <= 126.f);
    bool vx0 = (x0f >= 0.f) && (x0f <= 127.f);
    bool vx1 = (x0f >= -1.f) && (x0f <= 126.f);
    int yi0 = (int)fminf(fmaxf(y0f, 0.f), 127.f);
    int yi1 = (int)fminf(fmaxf(y0f + 1.f, 0.f), 127.f);
    int xi0 = (int)fminf(fmaxf(x0f, 0.f), 127.f);
    int xi1 = (int)fminf(fmaxf(x0f + 1.f, 0.f), 127.f);
    float w00 = wy0 * wx0 * ((vy0 && vx0) ? 1.f : 0.f);
    float w01 = wy0 * wx1 * ((vy0 && vx1) ? 1.f : 0.f);
    float w10 = wy1 * wx0 * ((vy1 && vx0) ? 1.f : 0.f);
    float w11 = wy1 * wx1 * ((vy1 && vx1) ? 1.f : 0.f);

    const __bf16* c00 = xb + ((size_t)((yi0 + 3) * 134) + xi0 + 3) * 64;
    const __bf16* c01 = xb + ((size_t)((yi0 + 3) * 134) + xi1 + 3) * 64;
    const __bf16* c10 = xb + ((size_t)((yi1 + 3) * 134) + xi0 + 3) * 64;
    const __bf16* c11 = xb + ((size_t)((yi1 + 3) * 134) + xi1 + 3) * 64;

#pragma unroll
    for (int s = 0; s < 2; s++) {
      bf16x8 v00 = *(const bf16x8*)(c00 + s * 32);
      bf16x8 v01 = *(const bf16x8*)(c01 + s * 32);
      bf16x8 v10 = *(const bf16x8*)(c10 + s * 32);
      bf16x8 v11 = *(const bf16x8*)(c11 + s * 32);
      bf16x8 a;
#pragma unroll
      for (int j = 0; j < 8; j++) {
        float f = w00 * (float)v00[j] + w01 * (float)v01[j]
                + w10 * (float)v10[j] + w11 * (float)v11[j];
        a[j] = (__bf16)f;
      }
      // 4 out-channel groups: D[px][o] accumulate
      acc[0] = __builtin_amdgcn_mfma_f32_16x16x32_bf16(
          a, aD[((k * 2 + s) * 4 + 0) * 64 + lane], acc[0], 0, 0, 0);
      acc[1] = __builtin_amdgcn_mfma_f32_16x16x32_bf16(
          a, aD[((k * 2 + s) * 4 + 1) * 64 + lane], acc[1], 0, 0, 0);
      acc[2] = __builtin_amdgcn_mfma_f32_16x16x32_bf16(
          a, aD[((k * 2 + s) * 4 + 2) * 64 + lane], acc[2], 0, 0, 0);
      acc[3] = __builtin_amdgcn_mfma_f32_16x16x32_bf16(
          a, aD[((k * 2 + s) * 4 + 3) * 64 + lane], acc[3], 0, 0, 0);
    }
  }

  // D layout: row(pixel) = g*4 + r, col(out-ch) = mf*16 + l15.
  __bf16* fb = FdT + ((size_t)b * HWn + h * 128 + px0) * 64;
#pragma unroll
  for (int mf = 0; mf < 4; mf++) {
    int o = mf * 16 + l15;
    float bias = dcn_b[o];
#pragma unroll
    for (int r = 0; r < 4; r++) {
      int pxl = g * 4 + r;
      fb[(size_t)pxl * 64 + o] = (__bf16)(acc[mf][r] + bias);
    }
  }
}

// ---------------------------------------------------------------------------
// K7: fusion -> fusedT bf16 channels-last, zero-padded 2 ring [b][132][132][64].
// ---------------------------------------------------------------------------
__global__ __launch_bounds__(256) void k_fuseT(
    const __bf16* __restrict__ FsT, const __bf16* __restrict__ FdT,
    const float* __restrict__ wg_w, const float* __restrict__ wg_b,
    __bf16* __restrict__ fusedT)
{
  int id = blockIdx.x * 256 + threadIdx.x;
  if (id >= 8 * 132 * 132) return;
  int wp = id % 132;
  int hp = (id / 132) % 132;
  int b  = id / (132 * 132);
  __bf16* dst = fusedT + (size_t)id * 64;
  int h = hp - 2, w = wp - 2;
  if (((unsigned)h >= 128u) || ((unsigned)w >= 128u)) {
    bf16x8 z = {};
#pragma unroll
    for (int oct = 0; oct < 8; oct++) *(bf16x8*)(dst + oct * 8) = z;
    return;
  }
  const bf16x8* fs = (const bf16x8*)(FsT + ((size_t)b * HWn + h * 128 + w) * 64);
  const bf16x8* fd = (const bf16x8*)(FdT + ((size_t)b * HWn + h * 128 + w) * 64);
  bf16x8 fsv[8], fdv[8];
  float s0 = wg_b[0], s1 = wg_b[1];
#pragma unroll
  for (int oct = 0; oct < 8; oct++) {
    fsv[oct] = fs[oct];
    fdv[oct] = fd[oct];
#pragma unroll
    for (int j = 0; j < 8; j++) {
      int c = oct * 8 + j;
      float a = (float)fsv[oct][j], d = (float)fdv[oct][j];
      s0 = fmaf(wg_w[c],       a, fmaf(wg_w[64 + c],  d, s0));
      s1 = fmaf(wg_w[128 + c], a, fmaf(wg_w[192 + c], d, s1));
    }
  }
  float p0 = 1.f / (1.f + __expf(s1 - s0));
  float p1 = 1.f - p0;
#pragma unroll
  for (int oct = 0; oct < 8; oct++) {
    bf16x8 r;
#pragma unroll
    for (int j = 0; j < 8; j++)
      r[j] = (__bf16)(p0 * (float)fsv[oct][j] + p1 * (float)fdv[oct][j]);
    *(bf16x8*)(dst + oct * 8) = r;
  }
}

// ---------------------------------------------------------------------------
// K8: collapsed ELK via MFMA. XCD swizzle chunk 64 => XCD k = batch k.
// ---------------------------------------------------------------------------
__global__ __launch_bounds__(256) void k_elkm(
    const __bf16* __restrict__ fusedT, const __bf16* __restrict__ weffD,
    const float* __restrict__ beff, float* __restrict__ out)
{
  const int DY[13] = {-2,-1,-1,-1, 0, 0, 0, 0, 0, 1, 1, 1, 2};
  const int DX[13] = { 0,-1, 0, 1,-2,-1, 0, 1, 2,-1, 0, 1, 0};
  const int lane = threadIdx.x & 63;
  const int wv   = threadIdx.x >> 6;
  const int swz  = xcd_swz(blockIdx.x, 64);
  const int b    = swz >> 6;
  const int h    = (swz & 63) * 2 + (wv >> 1);
  const int half = wv & 1;

  f32x4 acc[4][4];
#pragma unroll
  for (int mf = 0; mf < 4; mf++)
#pragma unroll
    for (int nf = 0; nf < 4; nf++) acc[mf][nf] = (f32x4){0.f, 0.f, 0.f, 0.f};

  const bf16x8* aD = (const bf16x8*)weffD;

  for (int t = 0; t < 13; t++) {
    int hp = h + 2 + DY[t];
    const __bf16* base = fusedT
        + ((size_t)((b * 132 + hp) * 132) + half * 64 + 2 + DX[t]) * 64;
#pragma unroll
    for (int s = 0; s < 2; s++) {
      bf16x8 a0 = aD[((t * 2 + s) * 4 + 0) * 64 + lane];
      bf16x8 a1 = aD[((t * 2 + s) * 4 + 1) * 64 + lane];
      bf16x8 a2 = aD[((t * 2 + s) * 4 + 2) * 64 + lane];
      bf16x8 a3 = aD[((t * 2 + s) * 4 + 3) * 64 + lane];
#pragma unroll
      for (int nf = 0; nf < 4; nf++) {
        bf16x8 bv = *(const bf16x8*)(base + (size_t)(nf * 16 + (lane & 15)) * 64
                                          + s * 32 + (lane >> 4) * 8);
        acc[0][nf] = __builtin_amdgcn_mfma_f32_16x16x32_bf16(a0, bv, acc[0][nf], 0, 0, 0);
        acc[1][nf] = __builtin_amdgcn_mfma_f32_16x16x32_bf16(a1, bv, acc[1][nf], 0, 0, 0);
        acc[2][nf] = __builtin_amdgcn_mfma_f32_16x16x32_bf16(a2, bv, acc[2][nf], 0, 0, 0);
        acc[3][nf] = __builtin_amdgcn_mfma_f32_16x16x32_bf16(a3, bv, acc[3][nf], 0, 0, 0);
      }
    }
  }

#pragma unroll
  for (int mf = 0; mf < 4; mf++) {
    int ob = mf * 16 + ((lane >> 4) << 2);
#pragma unroll
    for (int r = 0; r < 4; r++) {
      int o = ob + r;
      float bb = beff[o];
      float* orow = out + ((size_t)(b * 64 + o)) * HWn + h * 128 + half * 64 + (lane & 15);
#pragma unroll
      for (int nf = 0; nf < 4; nf++)
        orow[nf * 16] = acc[mf][nf][r] + bb;
    }
  }
}

// ---------------------------------------------------------------------------
// Workspace layout unchanged from R5 (all sizes verified in floats):
// Region A [0, 4,596,736): xT -> fusedT (after k_dcnm).
// Region B [4,596,736, 9,536,512): xC -> FsT (after k_conv1m).
// Region C [9,536,512, 14,322,688): t1T/p1T/t2 -> FdT (after k_feat).
// Tail: feat/theta/wfrag/w2frag/beff/dcnD/weffD @14,322,688.. end 14,444,160.
// ---------------------------------------------------------------------------
extern "C" void kernel_launch(void* const* d_in, const int* in_sizes, int n_in,
                              void* d_out, int out_size, void* d_ws, size_t ws_size,
                              hipStream_t stream)
{
  (void)in_sizes; (void)n_in; (void)out_size; (void)ws_size;
  const float* x      = (const float*)d_in[0];
  const float* offset = (const float*)d_in[1];
  const float* stn_w1 = (const float*)d_in[2];
  const float* stn_b1 = (const float*)d_in[3];
  const float* stn_w2 = (const float*)d_in[4];
  const float* stn_b2 = (const float*)d_in[5];
  const float* fc_w   = (const float*)d_in[6];
  const float* fc_b   = (const float*)d_in[7];
  const float* dcn_w  = (const float*)d_in[8];
  const float* dcn_b  = (const float*)d_in[9];
  const float* wg_w   = (const float*)d_in[10];
  const float* wg_b   = (const float*)d_in[11];
  const float* w3     = (const float*)d_in[12];
  const float* b3     = (const float*)d_in[13];
  const float* w15    = (const float*)d_in[14];
  const float* b15    = (const float*)d_in[15];
  const float* w51    = (const float*)d_in[16];
  const float* b51    = (const float*)d_in[17];
  const float* w1     = (const float*)d_in[18];
  const float* b1     = (const float*)d_in[19];

  float* ws      = (float*)d_ws;
  __bf16* xT     = (__bf16*)ws;
  __bf16* fusedT = (__bf16*)ws;
  __bf16* xC     = (__bf16*)(ws + 4596736);
  __bf16* FsT    = (__bf16*)(ws + 4596736);
  __bf16* t1T    = (__bf16*)(ws + 9536512);
  __bf16* FdT    = (__bf16*)(ws + 9536512);
  __bf16* p1T    = (__bf16*)(ws + 11633664);
  float*  t2     = ws + 12225536;
  float*  feat   = ws + 14322688;
  float*  theta  = ws + 14323200;
  __bf16* wfrag  = (__bf16*)(ws + 14323264);
  __bf16* w2frag = (__bf16*)(ws + 14373440);
  float*  beff   = ws + 14399040;
  __bf16* dcnD   = (__bf16*)(ws + 14399104);
  __bf16* weffD  = (__bf16*)(ws + 14417536);
  float*  out    = (float*)d_out;

  k_prep  <<<1,    64,  0, stream>>>(w1, b3, b15, b51, b1, beff);
  k_xt    <<<562,  256, 0, stream>>>(x, xT, xC);
  k_wf    <<<392,  256, 0, stream>>>(stn_w1, wfrag);
  k_frag  <<<552,  256, 0, stream>>>(dcn_w, w1, w3, w15, w51, stn_w2, dcnD, weffD, w2frag);
  k_conv1m<<<512,  128, 0, stream>>>(xC, wfrag, stn_b1, t1T);
  k_pool  <<<145,  256, 0, stream>>>(t1T, p1T);
  k_conv2m<<<128,  256, 0, stream>>>(p1T, w2frag, stn_b2, t2);
  k_feat  <<<512,  256, 0, stream>>>(t2, feat);
  k_theta <<<1,    64,  0, stream>>>(feat, fc_w, fc_b, theta);
  k_fs    <<<512,  256, 0, stream>>>(xT, theta, FsT);
  k_dcnm  <<<2048, 256, 0, stream>>>(xT, offset, dcnD, dcn_b, FdT);
  k_fuseT <<<545,  256, 0, stream>>>(FsT, FdT, wg_w, wg_b, fusedT);
  k_elkm  <<<512,  256, 0, stream>>>(fusedT, weffD, beff, out);
}

// Round 9
// 275.750 us; speedup vs baseline: 1.0512x; 1.0512x over previous
//
#include <hip/hip_runtime.h>
#include <math.h>

// Problem dims
#define Bn 8
#define Cn 64
#define Hn 128
#define Wn 128
#define HWn 16384

typedef __attribute__((ext_vector_type(8))) __bf16 bf16x8;
typedef __attribute__((ext_vector_type(4))) __bf16 bf16x4;
typedef __attribute__((ext_vector_type(4))) float f32x4;

// XCD-aware bijective swizzle: grid = 8*chunk blocks; XCD k (bid%8) gets the
// contiguous work range [k*chunk,(k+1)*chunk) => per-XCD L2-resident slice.
__device__ __forceinline__ int xcd_swz(int bid, int chunk) {
  return (bid & 7) * chunk + (bid >> 3);
}

// ---------------------------------------------------------------------------
// K0: beff (collapsed ELK bias) only.
// ---------------------------------------------------------------------------
__global__ void k_prep(const float* __restrict__ w1, const float* __restrict__ b3,
                       const float* __restrict__ b15, const float* __restrict__ b51,
                       const float* __restrict__ b1, float* __restrict__ beff)
{
  int e = threadIdx.x;
  if (e >= 64) return;
  float s = b1[e];
  for (int m = 0; m < 64; m++) {
    s = fmaf(w1[e * 192 + m],       b3[m],  s);
    s = fmaf(w1[e * 192 + 64 + m],  b15[m], s);
    s = fmaf(w1[e * 192 + 128 + m], b51[m], s);
  }
  beff[e] = s;
}

// ---------------------------------------------------------------------------
// K-xt: x (NCHW f32) -> xT[b][hp134][wp134][c64] bf16 (3-pad ring)
//                    -> xC[b][oct8][hp134][slot144][8ch] bf16 (conv1 staging)
// ---------------------------------------------------------------------------
__global__ __launch_bounds__(256) void k_xt(const float* __restrict__ x,
                                            __bf16* __restrict__ xT,
                                            __bf16* __restrict__ xC)
{
  int t = blockIdx.x * 256 + threadIdx.x;
  if (t >= 8 * 134 * 134) return;
  int wp = t % 134;
  int hp = (t / 134) % 134;
  int b  = t / (134 * 134);
  int h = hp - 3, w = wp - 3;
  bool inb = ((unsigned)h < 128u) && ((unsigned)w < 128u);
  const float* xb = x + (size_t)b * Cn * HWn + h * 128 + w;
  __bf16* dst = xT + (size_t)t * 64;
#pragma unroll
  for (int oct = 0; oct < 8; oct++) {
    bf16x8 v;
#pragma unroll
    for (int j = 0; j < 8; j++)
      v[j] = inb ? (__bf16)xb[(size_t)(oct * 8 + j) * HWn] : (__bf16)0.f;
    *(bf16x8*)(dst + oct * 8) = v;
    *(bf16x8*)(xC + ((((size_t)b * 8 + oct) * 134 + hp) * 144 + wp) * 8) = v;
  }
}

// ---------------------------------------------------------------------------
// K-wf: stn_w1 -> A-fragment layout for conv1 MFMA.
// ---------------------------------------------------------------------------
__global__ __launch_bounds__(256) void k_wf(const float* __restrict__ stn_w1,
                                            __bf16* __restrict__ wfrag)
{
  int t = blockIdx.x * 256 + threadIdx.x;
  if (t >= 100352) return;
  int e   = t & 7;
  int l   = (t >> 3) & 63;
  int o16 = (t >> 9) & 1;
  int ck  = (t >> 10) & 1;
  int tap = t >> 11;
  int o = o16 * 16 + (l & 15);
  int c = ck * 32 + (l >> 4) * 8 + e;
  wfrag[t] = (__bf16)stn_w1[(o * 64 + c) * 49 + tap];
}

// ---------------------------------------------------------------------------
// K-frag: A-fragments for DCN (9 taps), collapsed ELK (13 taps), conv2 (25 taps).
// ---------------------------------------------------------------------------
__global__ __launch_bounds__(256) void k_frag(
    const float* __restrict__ dcn_w, const float* __restrict__ w1,
    const float* __restrict__ w3, const float* __restrict__ w15,
    const float* __restrict__ w51, const float* __restrict__ stn_w2,
    __bf16* __restrict__ dcnD, __bf16* __restrict__ weffD,
    __bf16* __restrict__ w2frag)
{
  int t = blockIdx.x * 256 + threadIdx.x;
  if (t < 36864) {
    int e = t & 7, l = (t >> 3) & 63, mf = (t >> 9) & 3, s = (t >> 11) & 1;
    int tap = t >> 12;
    int o = mf * 16 + (l & 15), c = s * 32 + (l >> 4) * 8 + e;
    dcnD[t] = (__bf16)dcn_w[(o * 64 + c) * 9 + tap];
    return;
  }
  t -= 36864;
  if (t < 53248) {
    const int DY[13] = {-2,-1,-1,-1, 0, 0, 0, 0, 0, 1, 1, 1, 2};
    const int DX[13] = { 0,-1, 0, 1,-2,-1, 0, 1, 2,-1, 0, 1, 0};
    int e = t & 7, l = (t >> 3) & 63, mf = (t >> 9) & 3, s = (t >> 11) & 1;
    int tap = t >> 12;
    int o = mf * 16 + (l & 15), c = s * 32 + (l >> 4) * 8 + e;
    int dy = DY[tap], dx = DX[tap];
    float v = 0.f;
    if (dy >= -1 && dy <= 1 && dx >= -1 && dx <= 1) {
      int k3 = (dy + 1) * 3 + (dx + 1);
      for (int m = 0; m < 64; m++) v = fmaf(w1[o * 192 + m], w3[(m * 64 + c) * 9 + k3], v);
    }
    if (dy == 0) {
      int k15 = dx + 2;
      for (int m = 0; m < 64; m++) v = fmaf(w1[o * 192 + 64 + m], w15[(m * 64 + c) * 5 + k15], v);
    }
    if (dx == 0) {
      int k51 = dy + 2;
      for (int m = 0; m < 64; m++) v = fmaf(w1[o * 192 + 128 + m], w51[(m * 64 + c) * 5 + k51], v);
    }
    weffD[t] = (__bf16)v;
    return;
  }
  t -= 53248;
  if (t < 51200) {   // conv2 A-frags: [tap25][mf4][lane64][e8]
    int e = t & 7, l = (t >> 3) & 63, mf = (t >> 9) & 3;
    int tap = t >> 11;
    int o = mf * 16 + (l & 15), c = (l >> 4) * 8 + e;
    w2frag[t] = (__bf16)stn_w2[(o * 32 + c) * 25 + tap];
  }
}

// ---------------------------------------------------------------------------
// K1: STN conv1 via MFMA, contiguous 1KB global_load_lds staging from xC.
// ---------------------------------------------------------------------------
__global__ __launch_bounds__(128) void k_conv1m(
    const __bf16* __restrict__ xC, const __bf16* __restrict__ wfrag,
    const float* __restrict__ b1s, __bf16* __restrict__ t1T)
{
  __shared__ alignas(16) char tile[73728];   // [q4][r8][slot144][16B]
  const int lane = threadIdx.x & 63;
  const int wv   = threadIdx.x >> 6;
  const int swz  = xcd_swz(blockIdx.x, 64);
  const int b    = swz >> 6;
  const int h0   = (swz & 63) * 2;

  f32x4 acc[2][8];
#pragma unroll
  for (int o16 = 0; o16 < 2; o16++)
#pragma unroll
    for (int nf = 0; nf < 8; nf++) acc[o16][nf] = (f32x4){0.f, 0.f, 0.f, 0.f};

  const bf16x8* wf = (const bf16x8*)wfrag;
  const char* tb = (const char*)tile;
  const char* xCb = (const char*)xC;

  for (int ck = 0; ck < 2; ck++) {
    for (int i = wv; i < 72; i += 2) {
      int q = i / 18;
      int t = i - q * 18;
      const char* src = xCb
          + (((size_t)(b * 8 + ck * 4 + q) * 134 + h0) * 2304) + t * 1024 + lane * 16;
      char* dst = (char*)tile + i * 1024;
      __builtin_amdgcn_global_load_lds(
          (const __attribute__((address_space(1))) void*)src,
          (__attribute__((address_space(3))) void*)dst, 16, 0, 0);
    }
    __syncthreads();

    for (int tap = 0; tap < 49; tap++) {
      int dy7 = tap / 7;
      int dx7 = tap - dy7 * 7;
      bf16x8 a0 = wf[((tap * 2 + ck) * 2 + 0) * 64 + lane];
      bf16x8 a1 = wf[((tap * 2 + ck) * 2 + 1) * 64 + lane];
      const char* bp = tb + (lane >> 4) * 18432 + (wv + dy7) * 2304
                          + (dx7 + (lane & 15)) * 16;
#pragma unroll
      for (int nf = 0; nf < 8; nf++) {
        bf16x8 bv = *(const bf16x8*)(bp + nf * 256);
        acc[0][nf] = __builtin_amdgcn_mfma_f32_16x16x32_bf16(a0, bv, acc[0][nf], 0, 0, 0);
        acc[1][nf] = __builtin_amdgcn_mfma_f32_16x16x32_bf16(a1, bv, acc[1][nf], 0, 0, 0);
      }
    }
    __syncthreads();
  }

  int h = h0 + wv;
#pragma unroll
  for (int o16 = 0; o16 < 2; o16++) {
    int ob = o16 * 16 + ((lane >> 4) << 2);
    float bb0 = b1s[ob], bb1 = b1s[ob + 1], bb2 = b1s[ob + 2], bb3 = b1s[ob + 3];
#pragma unroll
    for (int nf = 0; nf < 8; nf++) {
      int px = nf * 16 + (lane & 15);
      bf16x4 r;
      r[0] = (__bf16)fmaxf(acc[o16][nf][0] + bb0, 0.f);
      r[1] = (__bf16)fmaxf(acc[o16][nf][1] + bb1, 0.f);
      r[2] = (__bf16)fmaxf(acc[o16][nf][2] + bb2, 0.f);
      r[3] = (__bf16)fmaxf(acc[o16][nf][3] + bb3, 0.f);
      *(bf16x4*)(t1T + (((size_t)(b * 128 + h) * 128 + px)) * 32 + ob) = r;
    }
  }
}

// ---------------------------------------------------------------------------
// K2: maxpool 2x2 -> p1T[b][hp68][wp68][32ch] bf16, zero-padded 2 ring.
// ---------------------------------------------------------------------------
__global__ __launch_bounds__(256) void k_pool(const __bf16* __restrict__ t1T,
                                              __bf16* __restrict__ p1T)
{
  int id = blockIdx.x * 256 + threadIdx.x;
  if (id >= 8 * 68 * 68) return;
  int wp = id % 68, hp = (id / 68) % 68, b = id / (68 * 68);
  __bf16* dst = p1T + (size_t)id * 32;
  int ph = hp - 2, pw = wp - 2;
  if (((unsigned)ph >= 64u) || ((unsigned)pw >= 64u)) {
    bf16x8 z = {};
#pragma unroll
    for (int g = 0; g < 4; g++) *(bf16x8*)(dst + g * 8) = z;
    return;
  }
  const __bf16* s = t1T + (((size_t)(b * 128) + ph * 2) * 128 + pw * 2) * 32;
#pragma unroll
  for (int g = 0; g < 4; g++) {
    bf16x8 v0 = *(const bf16x8*)(s + g * 8);
    bf16x8 v1 = *(const bf16x8*)(s + 32 + g * 8);
    bf16x8 v2 = *(const bf16x8*)(s + 4096 + g * 8);
    bf16x8 v3 = *(const bf16x8*)(s + 4128 + g * 8);
    bf16x8 r;
#pragma unroll
    for (int j = 0; j < 8; j++) {
      float m = fmaxf(fmaxf((float)v0[j], (float)v1[j]),
                      fmaxf((float)v2[j], (float)v3[j]));
      r[j] = (__bf16)m;
    }
    *(bf16x8*)(dst + g * 8) = r;
  }
}

// ---------------------------------------------------------------------------
// K3: conv2 via MFMA.
// ---------------------------------------------------------------------------
__global__ __launch_bounds__(256) void k_conv2m(
    const __bf16* __restrict__ p1T, const __bf16* __restrict__ w2frag,
    const float* __restrict__ b2s, float* __restrict__ t2)
{
  __shared__ alignas(16) char tile[34816];   // 8*68*64
  const int lane = threadIdx.x & 63;
  const int wv   = threadIdx.x >> 6;
  const int b    = blockIdx.x >> 4;
  const int h0   = (blockIdx.x & 15) * 4;

  f32x4 acc[4][4];
#pragma unroll
  for (int mf = 0; mf < 4; mf++)
#pragma unroll
    for (int nf = 0; nf < 4; nf++) acc[mf][nf] = (f32x4){0.f, 0.f, 0.f, 0.f};

  const char* src0 = (const char*)p1T + (((size_t)b * 68 + h0) * 68) * 64;
  for (int i = wv; i < 34; i += 4) {
    __builtin_amdgcn_global_load_lds(
        (const __attribute__((address_space(1))) void*)(src0 + i * 1024 + lane * 16),
        (__attribute__((address_space(3))) void*)((char*)tile + i * 1024), 16, 0, 0);
  }
  __syncthreads();

  const bf16x8* wf = (const bf16x8*)w2frag;
  const char* tb = (const char*)tile;
  for (int tap = 0; tap < 25; tap++) {
    int ky = tap / 5, kx = tap - ky * 5;
    bf16x8 a0 = wf[(tap * 4 + 0) * 64 + lane];
    bf16x8 a1 = wf[(tap * 4 + 1) * 64 + lane];
    bf16x8 a2 = wf[(tap * 4 + 2) * 64 + lane];
    bf16x8 a3 = wf[(tap * 4 + 3) * 64 + lane];
    const char* bp = tb + (((wv + ky) * 68 + kx + (lane & 15)) * 64) + (lane >> 4) * 16;
#pragma unroll
    for (int nf = 0; nf < 4; nf++) {
      bf16x8 bv = *(const bf16x8*)(bp + nf * 1024);
      acc[0][nf] = __builtin_amdgcn_mfma_f32_16x16x32_bf16(a0, bv, acc[0][nf], 0, 0, 0);
      acc[1][nf] = __builtin_amdgcn_mfma_f32_16x16x32_bf16(a1, bv, acc[1][nf], 0, 0, 0);
      acc[2][nf] = __builtin_amdgcn_mfma_f32_16x16x32_bf16(a2, bv, acc[2][nf], 0, 0, 0);
      acc[3][nf] = __builtin_amdgcn_mfma_f32_16x16x32_bf16(a3, bv, acc[3][nf], 0, 0, 0);
    }
  }

  int h = h0 + wv;
#pragma unroll
  for (int mf = 0; mf < 4; mf++) {
    int ob = mf * 16 + ((lane >> 4) << 2);
#pragma unroll
    for (int r = 0; r < 4; r++) {
      float bb = b2s[ob + r];
      float* orow = t2 + ((size_t)(b * 64 + ob + r)) * 4096 + h * 64 + (lane & 15);
#pragma unroll
      for (int nf = 0; nf < 4; nf++)
        orow[nf * 16] = fmaxf(acc[mf][nf][r] + bb, 0.f);
    }
  }
}

// ---------------------------------------------------------------------------
// K3b: deterministic spatial sum -> feat[b*64+co].
// ---------------------------------------------------------------------------
__global__ __launch_bounds__(256) void k_feat(const float* __restrict__ t2, float* __restrict__ feat)
{
  __shared__ float red[256];
  int bc = blockIdx.x;
  const float* s = t2 + (size_t)bc * 4096;
  float v = 0.f;
  for (int i = threadIdx.x; i < 4096; i += 256) v += s[i];
  red[threadIdx.x] = v;
  __syncthreads();
  for (int st = 128; st > 0; st >>= 1) {
    if (threadIdx.x < st) red[threadIdx.x] += red[threadIdx.x + st];
    __syncthreads();
  }
  if (threadIdx.x == 0) feat[bc] = red[0];
}

// ---------------------------------------------------------------------------
// K4: theta
// ---------------------------------------------------------------------------
__global__ void k_theta(const float* __restrict__ feat, const float* __restrict__ fc_w,
                        const float* __restrict__ fc_b, float* __restrict__ theta)
{
  int tid = threadIdx.x;
  if (tid >= 48) return;
  int b = tid / 6, i = tid - b * 6;
  float s = 0.f;
  for (int k = 0; k < 64; k++) s = fmaf(feat[b * 64 + k], fc_w[i * 64 + k], s);
  theta[tid] = fmaf(s, 1.f / 4096.f, fc_b[i]);
}

// ---------------------------------------------------------------------------
// Shared bilinear corner-address helper (clamped + masked weights).
// ---------------------------------------------------------------------------
__device__ __forceinline__ void bilin_setup(
    const __bf16* __restrict__ xb, float sy, float sx,
    const __bf16*& c00, const __bf16*& c01,
    const __bf16*& c10, const __bf16*& c11,
    float& w00, float& w01, float& w10, float& w11)
{
  float y0f = floorf(sy), x0f = floorf(sx);
  float wy1 = sy - y0f, wy0 = 1.f - wy1;
  float wx1 = sx - x0f, wx0 = 1.f - wx1;
  bool vy0 = (y0f >= 0.f) && (y0f <= 127.f);
  bool vy1 = (y0f >= -1.f) && (y0f <= 126.f);
  bool vx0 = (x0f >= 0.f) && (x0f <= 127.f);
  bool vx1 = (x0f >= -1.f) && (x0f <= 126.f);
  int yi0 = (int)fminf(fmaxf(y0f, 0.f), 127.f);
  int yi1 = (int)fminf(fmaxf(y0f + 1.f, 0.f), 127.f);
  int xi0 = (int)fminf(fmaxf(x0f, 0.f), 127.f);
  int xi1 = (int)fminf(fmaxf(x0f + 1.f, 0.f), 127.f);
  w00 = wy0 * wx0 * ((vy0 && vx0) ? 1.f : 0.f);
  w01 = wy0 * wx1 * ((vy0 && vx1) ? 1.f : 0.f);
  w10 = wy1 * wx0 * ((vy1 && vx0) ? 1.f : 0.f);
  w11 = wy1 * wx1 * ((vy1 && vx1) ? 1.f : 0.f);
  c00 = xb + ((size_t)((yi0 + 3) * 134) + xi0 + 3) * 64;
  c01 = xb + ((size_t)((yi0 + 3) * 134) + xi1 + 3) * 64;
  c10 = xb + ((size_t)((yi1 + 3) * 134) + xi0 + 3) * 64;
  c11 = xb + ((size_t)((yi1 + 3) * 134) + xi1 + 3) * 64;
}

__device__ __forceinline__ bf16x8 bilin_blend8(
    const __bf16* c00, const __bf16* c01, const __bf16* c10, const __bf16* c11,
    int byteoff, float w00, float w01, float w10, float w11)
{
  bf16x8 v00 = *(const bf16x8*)(c00 + byteoff);
  bf16x8 v01 = *(const bf16x8*)(c01 + byteoff);
  bf16x8 v10 = *(const bf16x8*)(c10 + byteoff);
  bf16x8 v11 = *(const bf16x8*)(c11 + byteoff);
  bf16x8 r;
#pragma unroll
  for (int j = 0; j < 8; j++) {
    float f = w00 * (float)v00[j] + w01 * (float)v01[j]
            + w10 * (float)v10[j] + w11 * (float)v11[j];
    r[j] = (__bf16)f;
  }
  return r;
}

// ---------------------------------------------------------------------------
// K6: deformable conv via MFMA + FUSED STN grid-sample (was k_fs).
// Wave = 16 px x 64 out. Lane (l&15)=pixel, (l>>4)=channel octet; the blended
// register IS the MFMA A-fragment. R9 fix: FULL UNROLL of the tap loop so the
// compiler constant-folds indices and pipelines gather loads across taps
// (R8's rolled loop serialized one tap's full latency per iteration).
// The STN sample is a 10th tap writing FsT (saves a separate xT pass).
// 2048 blocks x 4 waves; XCD swizzle chunk 256 => XCD = batch.
// ---------------------------------------------------------------------------
__global__ __launch_bounds__(256) void k_dcnm(
    const __bf16* __restrict__ xT, const float* __restrict__ off,
    const float* __restrict__ theta,
    const __bf16* __restrict__ dcnD, const float* __restrict__ dcn_b,
    __bf16* __restrict__ FdT, __bf16* __restrict__ FsT)
{
  const int lane = threadIdx.x & 63;
  const int wv   = threadIdx.x >> 6;
  const int swz  = xcd_swz(blockIdx.x, 256);
  const int b    = swz >> 8;
  const int rem  = swz & 255;
  const int h    = rem >> 1;
  const int px0  = (rem & 1) * 64 + wv * 16;
  const int l15  = lane & 15;
  const int g    = lane >> 4;
  const int w    = px0 + l15;

  const __bf16* xb = xT + (size_t)b * 134 * 134 * 64 + g * 8;  // + ch octet

  // ---- fused STN sample (tap 10): coords from theta, store to FsT ----
  {
    const float* t = theta + b * 6;
    float xn = (float)(2 * w + 1) * (1.f / 128.f) - 1.f;
    float yn = (float)(2 * h + 1) * (1.f / 128.f) - 1.f;
    float gxv = t[0] * xn + t[1] * yn + t[2];
    float gyv = t[3] * xn + t[4] * yn + t[5];
    float ix = fmaf(gxv, 64.f, 63.5f);
    float iy = fmaf(gyv, 64.f, 63.5f);
    const __bf16 *c00, *c01, *c10, *c11;
    float w00, w01, w10, w11;
    bilin_setup(xb, iy, ix, c00, c01, c10, c11, w00, w01, w10, w11);
    __bf16* dst = FsT + ((size_t)b * HWn + h * 128 + w) * 64 + g * 8;
#pragma unroll
    for (int s = 0; s < 2; s++) {
      bf16x8 r = bilin_blend8(c00, c01, c10, c11, s * 32, w00, w01, w10, w11);
      *(bf16x8*)(dst + s * 32) = r;
    }
  }

  // ---- deformable conv: 9 taps, fully unrolled ----
  f32x4 acc[4];
#pragma unroll
  for (int mf = 0; mf < 4; mf++) acc[mf] = (f32x4){0.f, 0.f, 0.f, 0.f};

  const float* ob = off + (size_t)b * 18 * HWn + h * 128 + w;
  const bf16x8* aD = (const bf16x8*)dcnD;

#pragma unroll
  for (int k = 0; k < 9; k++) {
    float dy = ob[(size_t)(2 * k) * HWn];
    float dx = ob[(size_t)(2 * k + 1) * HWn];
    float sy = (float)(h + k / 3 - 1) + dy;
    float sx = (float)(w + (k % 3) - 1) + dx;

    const __bf16 *c00, *c01, *c10, *c11;
    float w00, w01, w10, w11;
    bilin_setup(xb, sy, sx, c00, c01, c10, c11, w00, w01, w10, w11);

#pragma unroll
    for (int s = 0; s < 2; s++) {
      bf16x8 a = bilin_blend8(c00, c01, c10, c11, s * 32, w00, w01, w10, w11);
      acc[0] = __builtin_amdgcn_mfma_f32_16x16x32_bf16(
          a, aD[((k * 2 + s) * 4 + 0) * 64 + lane], acc[0], 0, 0, 0);
      acc[1] = __builtin_amdgcn_mfma_f32_16x16x32_bf16(
          a, aD[((k * 2 + s) * 4 + 1) * 64 + lane], acc[1], 0, 0, 0);
      acc[2] = __builtin_amdgcn_mfma_f32_16x16x32_bf16(
          a, aD[((k * 2 + s) * 4 + 2) * 64 + lane], acc[2], 0, 0, 0);
      acc[3] = __builtin_amdgcn_mfma_f32_16x16x32_bf16(
          a, aD[((k * 2 + s) * 4 + 3) * 64 + lane], acc[3], 0, 0, 0);
    }
  }

  // D layout: row(pixel) = g*4 + r, col(out-ch) = mf*16 + l15.
  __bf16* fb = FdT + ((size_t)b * HWn + h * 128 + px0) * 64;
#pragma unroll
  for (int mf = 0; mf < 4; mf++) {
    int o = mf * 16 + l15;
    float bias = dcn_b[o];
#pragma unroll
    for (int r = 0; r < 4; r++) {
      int pxl = g * 4 + r;
      fb[(size_t)pxl * 64 + o] = (__bf16)(acc[mf][r] + bias);
    }
  }
}

// ---------------------------------------------------------------------------
// K7: fusion -> fusedT bf16 channels-last, zero-padded 2 ring [b][132][132][64].
// ---------------------------------------------------------------------------
__global__ __launch_bounds__(256) void k_fuseT(
    const __bf16* __restrict__ FsT, const __bf16* __restrict__ FdT,
    const float* __restrict__ wg_w, const float* __restrict__ wg_b,
    __bf16* __restrict__ fusedT)
{
  int id = blockIdx.x * 256 + threadIdx.x;
  if (id >= 8 * 132 * 132) return;
  int wp = id % 132;
  int hp = (id / 132) % 132;
  int b  = id / (132 * 132);
  __bf16* dst = fusedT + (size_t)id * 64;
  int h = hp - 2, w = wp - 2;
  if (((unsigned)h >= 128u) || ((unsigned)w >= 128u)) {
    bf16x8 z = {};
#pragma unroll
    for (int oct = 0; oct < 8; oct++) *(bf16x8*)(dst + oct * 8) = z;
    return;
  }
  const bf16x8* fs = (const bf16x8*)(FsT + ((size_t)b * HWn + h * 128 + w) * 64);
  const bf16x8* fd = (const bf16x8*)(FdT + ((size_t)b * HWn + h * 128 + w) * 64);
  bf16x8 fsv[8], fdv[8];
  float s0 = wg_b[0], s1 = wg_b[1];
#pragma unroll
  for (int oct = 0; oct < 8; oct++) {
    fsv[oct] = fs[oct];
    fdv[oct] = fd[oct];
#pragma unroll
    for (int j = 0; j < 8; j++) {
      int c = oct * 8 + j;
      float a = (float)fsv[oct][j], d = (float)fdv[oct][j];
      s0 = fmaf(wg_w[c],       a, fmaf(wg_w[64 + c],  d, s0));
      s1 = fmaf(wg_w[128 + c], a, fmaf(wg_w[192 + c], d, s1));
    }
  }
  float p0 = 1.f / (1.f + __expf(s1 - s0));
  float p1 = 1.f - p0;
#pragma unroll
  for (int oct = 0; oct < 8; oct++) {
    bf16x8 r;
#pragma unroll
    for (int j = 0; j < 8; j++)
      r[j] = (__bf16)(p0 * (float)fsv[oct][j] + p1 * (float)fdv[oct][j]);
    *(bf16x8*)(dst + oct * 8) = r;
  }
}

// ---------------------------------------------------------------------------
// K8: collapsed ELK via MFMA. XCD swizzle chunk 64 => XCD k = batch k.
// ---------------------------------------------------------------------------
__global__ __launch_bounds__(256) void k_elkm(
    const __bf16* __restrict__ fusedT, const __bf16* __restrict__ weffD,
    const float* __restrict__ beff, float* __restrict__ out)
{
  const int DY[13] = {-2,-1,-1,-1, 0, 0, 0, 0, 0, 1, 1, 1, 2};
  const int DX[13] = { 0,-1, 0, 1,-2,-1, 0, 1, 2,-1, 0, 1, 0};
  const int lane = threadIdx.x & 63;
  const int wv   = threadIdx.x >> 6;
  const int swz  = xcd_swz(blockIdx.x, 64);
  const int b    = swz >> 6;
  const int h    = (swz & 63) * 2 + (wv >> 1);
  const int half = wv & 1;

  f32x4 acc[4][4];
#pragma unroll
  for (int mf = 0; mf < 4; mf++)
#pragma unroll
    for (int nf = 0; nf < 4; nf++) acc[mf][nf] = (f32x4){0.f, 0.f, 0.f, 0.f};

  const bf16x8* aD = (const bf16x8*)weffD;

  for (int t = 0; t < 13; t++) {
    int hp = h + 2 + DY[t];
    const __bf16* base = fusedT
        + ((size_t)((b * 132 + hp) * 132) + half * 64 + 2 + DX[t]) * 64;
#pragma unroll
    for (int s = 0; s < 2; s++) {
      bf16x8 a0 = aD[((t * 2 + s) * 4 + 0) * 64 + lane];
      bf16x8 a1 = aD[((t * 2 + s) * 4 + 1) * 64 + lane];
      bf16x8 a2 = aD[((t * 2 + s) * 4 + 2) * 64 + lane];
      bf16x8 a3 = aD[((t * 2 + s) * 4 + 3) * 64 + lane];
#pragma unroll
      for (int nf = 0; nf < 4; nf++) {
        bf16x8 bv = *(const bf16x8*)(base + (size_t)(nf * 16 + (lane & 15)) * 64
                                          + s * 32 + (lane >> 4) * 8);
        acc[0][nf] = __builtin_amdgcn_mfma_f32_16x16x32_bf16(a0, bv, acc[0][nf], 0, 0, 0);
        acc[1][nf] = __builtin_amdgcn_mfma_f32_16x16x32_bf16(a1, bv, acc[1][nf], 0, 0, 0);
        acc[2][nf] = __builtin_amdgcn_mfma_f32_16x16x32_bf16(a2, bv, acc[2][nf], 0, 0, 0);
        acc[3][nf] = __builtin_amdgcn_mfma_f32_16x16x32_bf16(a3, bv, acc[3][nf], 0, 0, 0);
      }
    }
  }

#pragma unroll
  for (int mf = 0; mf < 4; mf++) {
    int ob = mf * 16 + ((lane >> 4) << 2);
#pragma unroll
    for (int r = 0; r < 4; r++) {
      int o = ob + r;
      float bb = beff[o];
      float* orow = out + ((size_t)(b * 64 + o)) * HWn + h * 128 + half * 64 + (lane & 15);
#pragma unroll
      for (int nf = 0; nf < 4; nf++)
        orow[nf * 16] = acc[mf][nf][r] + bb;
    }
  }
}

// ---------------------------------------------------------------------------
// Workspace layout unchanged from R5/R6 (sizes verified in floats):
// Region A [0, 4,596,736): xT -> fusedT (after k_dcnm).
// Region B [4,596,736, 9,536,512): xC -> FsT (xC dead after conv1m; FsT now
//          written by k_dcnm, which runs after conv1m). OK.
// Region C [9,536,512, 14,322,688): t1T/p1T/t2 -> FdT (after k_feat).
// Tail: feat/theta/wfrag/w2frag/beff/dcnD/weffD @14,322,688.. end 14,444,160.
// ---------------------------------------------------------------------------
extern "C" void kernel_launch(void* const* d_in, const int* in_sizes, int n_in,
                              void* d_out, int out_size, void* d_ws, size_t ws_size,
                              hipStream_t stream)
{
  (void)in_sizes; (void)n_in; (void)out_size; (void)ws_size;
  const float* x      = (const float*)d_in[0];
  const float* offset = (const float*)d_in[1];
  const float* stn_w1 = (const float*)d_in[2];
  const float* stn_b1 = (const float*)d_in[3];
  const float* stn_w2 = (const float*)d_in[4];
  const float* stn_b2 = (const float*)d_in[5];
  const float* fc_w   = (const float*)d_in[6];
  const float* fc_b   = (const float*)d_in[7];
  const float* dcn_w  = (const float*)d_in[8];
  const float* dcn_b  = (const float*)d_in[9];
  const float* wg_w   = (const float*)d_in[10];
  const float* wg_b   = (const float*)d_in[11];
  const float* w3     = (const float*)d_in[12];
  const float* b3     = (const float*)d_in[13];
  const float* w15    = (const float*)d_in[14];
  const float* b15    = (const float*)d_in[15];
  const float* w51    = (const float*)d_in[16];
  const float* b51    = (const float*)d_in[17];
  const float* w1     = (const float*)d_in[18];
  const float* b1     = (const float*)d_in[19];

  float* ws      = (float*)d_ws;
  __bf16* xT     = (__bf16*)ws;
  __bf16* fusedT = (__bf16*)ws;
  __bf16* xC     = (__bf16*)(ws + 4596736);
  __bf16* FsT    = (__bf16*)(ws + 4596736);
  __bf16* t1T    = (__bf16*)(ws + 9536512);
  __bf16* FdT    = (__bf16*)(ws + 9536512);
  __bf16* p1T    = (__bf16*)(ws + 11633664);
  float*  t2     = ws + 12225536;
  float*  feat   = ws + 14322688;
  float*  theta  = ws + 14323200;
  __bf16* wfrag  = (__bf16*)(ws + 14323264);
  __bf16* w2frag = (__bf16*)(ws + 14373440);
  float*  beff   = ws + 14399040;
  __bf16* dcnD   = (__bf16*)(ws + 14399104);
  __bf16* weffD  = (__bf16*)(ws + 14417536);
  float*  out    = (float*)d_out;

  k_prep  <<<1,    64,  0, stream>>>(w1, b3, b15, b51, b1, beff);
  k_xt    <<<562,  256, 0, stream>>>(x, xT, xC);
  k_wf    <<<392,  256, 0, stream>>>(stn_w1, wfrag);
  k_frag  <<<552,  256, 0, stream>>>(dcn_w, w1, w3, w15, w51, stn_w2, dcnD, weffD, w2frag);
  k_conv1m<<<512,  128, 0, stream>>>(xC, wfrag, stn_b1, t1T);
  k_pool  <<<145,  256, 0, stream>>>(t1T, p1T);
  k_conv2m<<<128,  256, 0, stream>>>(p1T, w2frag, stn_b2, t2);
  k_feat  <<<512,  256, 0, stream>>>(t2, feat);
  k_theta <<<1,    64,  0, stream>>>(feat, fc_w, fc_b, theta);
  k_dcnm  <<<2048, 256, 0, stream>>>(xT, offset, theta, dcnD, dcn_b, FdT, FsT);
  k_fuseT <<<545,  256, 0, stream>>>(FsT, FdT, wg_w, wg_b, fusedT);
  k_elkm  <<<512,  256, 0, stream>>>(fusedT, weffD, beff, out);
}

// Round 10
// 275.477 us; speedup vs baseline: 1.0522x; 1.0010x over previous
//
#include <hip/hip_runtime.h>
#include <math.h>

// Problem dims
#define Bn 8
#define Cn 64
#define Hn 128
#define Wn 128
#define HWn 16384

typedef __attribute__((ext_vector_type(8))) __bf16 bf16x8;
typedef __attribute__((ext_vector_type(4))) __bf16 bf16x4;
typedef __attribute__((ext_vector_type(4))) float f32x4;

// XCD-aware bijective swizzle: grid = 8*chunk blocks; XCD k (bid%8) gets the
// contiguous work range [k*chunk,(k+1)*chunk) => per-XCD L2-resident slice.
__device__ __forceinline__ int xcd_swz(int bid, int chunk) {
  return (bid & 7) * chunk + (bid >> 3);
}

// ---------------------------------------------------------------------------
// K0: beff (collapsed ELK bias) only.
// ---------------------------------------------------------------------------
__global__ void k_prep(const float* __restrict__ w1, const float* __restrict__ b3,
                       const float* __restrict__ b15, const float* __restrict__ b51,
                       const float* __restrict__ b1, float* __restrict__ beff)
{
  int e = threadIdx.x;
  if (e >= 64) return;
  float s = b1[e];
  for (int m = 0; m < 64; m++) {
    s = fmaf(w1[e * 192 + m],       b3[m],  s);
    s = fmaf(w1[e * 192 + 64 + m],  b15[m], s);
    s = fmaf(w1[e * 192 + 128 + m], b51[m], s);
  }
  beff[e] = s;
}

// ---------------------------------------------------------------------------
// K-xt: x (NCHW f32) -> xT[b][hp134][wp134][c64] bf16 (3-pad ring)
//                    -> xC[b][oct8][hp134][slot144][8ch] bf16 (conv1 staging)
// ---------------------------------------------------------------------------
__global__ __launch_bounds__(256) void k_xt(const float* __restrict__ x,
                                            __bf16* __restrict__ xT,
                                            __bf16* __restrict__ xC)
{
  int t = blockIdx.x * 256 + threadIdx.x;
  if (t >= 8 * 134 * 134) return;
  int wp = t % 134;
  int hp = (t / 134) % 134;
  int b  = t / (134 * 134);
  int h = hp - 3, w = wp - 3;
  bool inb = ((unsigned)h < 128u) && ((unsigned)w < 128u);
  const float* xb = x + (size_t)b * Cn * HWn + h * 128 + w;
  __bf16* dst = xT + (size_t)t * 64;
#pragma unroll
  for (int oct = 0; oct < 8; oct++) {
    bf16x8 v;
#pragma unroll
    for (int j = 0; j < 8; j++)
      v[j] = inb ? (__bf16)xb[(size_t)(oct * 8 + j) * HWn] : (__bf16)0.f;
    *(bf16x8*)(dst + oct * 8) = v;
    *(bf16x8*)(xC + ((((size_t)b * 8 + oct) * 134 + hp) * 144 + wp) * 8) = v;
  }
}

// ---------------------------------------------------------------------------
// K-wf: stn_w1 -> A-fragment layout for conv1 MFMA.
// ---------------------------------------------------------------------------
__global__ __launch_bounds__(256) void k_wf(const float* __restrict__ stn_w1,
                                            __bf16* __restrict__ wfrag)
{
  int t = blockIdx.x * 256 + threadIdx.x;
  if (t >= 100352) return;
  int e   = t & 7;
  int l   = (t >> 3) & 63;
  int o16 = (t >> 9) & 1;
  int ck  = (t >> 10) & 1;
  int tap = t >> 11;
  int o = o16 * 16 + (l & 15);
  int c = ck * 32 + (l >> 4) * 8 + e;
  wfrag[t] = (__bf16)stn_w1[(o * 64 + c) * 49 + tap];
}

// ---------------------------------------------------------------------------
// K-frag: A-fragments for DCN (9 taps), collapsed ELK (13 taps), conv2 (25 taps).
// ---------------------------------------------------------------------------
__global__ __launch_bounds__(256) void k_frag(
    const float* __restrict__ dcn_w, const float* __restrict__ w1,
    const float* __restrict__ w3, const float* __restrict__ w15,
    const float* __restrict__ w51, const float* __restrict__ stn_w2,
    __bf16* __restrict__ dcnD, __bf16* __restrict__ weffD,
    __bf16* __restrict__ w2frag)
{
  int t = blockIdx.x * 256 + threadIdx.x;
  if (t < 36864) {
    int e = t & 7, l = (t >> 3) & 63, mf = (t >> 9) & 3, s = (t >> 11) & 1;
    int tap = t >> 12;
    int o = mf * 16 + (l & 15), c = s * 32 + (l >> 4) * 8 + e;
    dcnD[t] = (__bf16)dcn_w[(o * 64 + c) * 9 + tap];
    return;
  }
  t -= 36864;
  if (t < 53248) {
    const int DY[13] = {-2,-1,-1,-1, 0, 0, 0, 0, 0, 1, 1, 1, 2};
    const int DX[13] = { 0,-1, 0, 1,-2,-1, 0, 1, 2,-1, 0, 1, 0};
    int e = t & 7, l = (t >> 3) & 63, mf = (t >> 9) & 3, s = (t >> 11) & 1;
    int tap = t >> 12;
    int o = mf * 16 + (l & 15), c = s * 32 + (l >> 4) * 8 + e;
    int dy = DY[tap], dx = DX[tap];
    float v = 0.f;
    if (dy >= -1 && dy <= 1 && dx >= -1 && dx <= 1) {
      int k3 = (dy + 1) * 3 + (dx + 1);
      for (int m = 0; m < 64; m++) v = fmaf(w1[o * 192 + m], w3[(m * 64 + c) * 9 + k3], v);
    }
    if (dy == 0) {
      int k15 = dx + 2;
      for (int m = 0; m < 64; m++) v = fmaf(w1[o * 192 + 64 + m], w15[(m * 64 + c) * 5 + k15], v);
    }
    if (dx == 0) {
      int k51 = dy + 2;
      for (int m = 0; m < 64; m++) v = fmaf(w1[o * 192 + 128 + m], w51[(m * 64 + c) * 5 + k51], v);
    }
    weffD[t] = (__bf16)v;
    return;
  }
  t -= 53248;
  if (t < 51200) {   // conv2 A-frags: [tap25][mf4][lane64][e8]
    int e = t & 7, l = (t >> 3) & 63, mf = (t >> 9) & 3;
    int tap = t >> 11;
    int o = mf * 16 + (l & 15), c = (l >> 4) * 8 + e;
    w2frag[t] = (__bf16)stn_w2[(o * 32 + c) * 25 + tap];
  }
}

// ---------------------------------------------------------------------------
// K1: STN conv1 via MFMA, contiguous 1KB global_load_lds staging from xC.
// ---------------------------------------------------------------------------
__global__ __launch_bounds__(128) void k_conv1m(
    const __bf16* __restrict__ xC, const __bf16* __restrict__ wfrag,
    const float* __restrict__ b1s, __bf16* __restrict__ t1T)
{
  __shared__ alignas(16) char tile[73728];   // [q4][r8][slot144][16B]
  const int lane = threadIdx.x & 63;
  const int wv   = threadIdx.x >> 6;
  const int swz  = xcd_swz(blockIdx.x, 64);
  const int b    = swz >> 6;
  const int h0   = (swz & 63) * 2;

  f32x4 acc[2][8];
#pragma unroll
  for (int o16 = 0; o16 < 2; o16++)
#pragma unroll
    for (int nf = 0; nf < 8; nf++) acc[o16][nf] = (f32x4){0.f, 0.f, 0.f, 0.f};

  const bf16x8* wf = (const bf16x8*)wfrag;
  const char* tb = (const char*)tile;
  const char* xCb = (const char*)xC;

  for (int ck = 0; ck < 2; ck++) {
    for (int i = wv; i < 72; i += 2) {
      int q = i / 18;
      int t = i - q * 18;
      const char* src = xCb
          + (((size_t)(b * 8 + ck * 4 + q) * 134 + h0) * 2304) + t * 1024 + lane * 16;
      char* dst = (char*)tile + i * 1024;
      __builtin_amdgcn_global_load_lds(
          (const __attribute__((address_space(1))) void*)src,
          (__attribute__((address_space(3))) void*)dst, 16, 0, 0);
    }
    __syncthreads();

    for (int tap = 0; tap < 49; tap++) {
      int dy7 = tap / 7;
      int dx7 = tap - dy7 * 7;
      bf16x8 a0 = wf[((tap * 2 + ck) * 2 + 0) * 64 + lane];
      bf16x8 a1 = wf[((tap * 2 + ck) * 2 + 1) * 64 + lane];
      const char* bp = tb + (lane >> 4) * 18432 + (wv + dy7) * 2304
                          + (dx7 + (lane & 15)) * 16;
#pragma unroll
      for (int nf = 0; nf < 8; nf++) {
        bf16x8 bv = *(const bf16x8*)(bp + nf * 256);
        acc[0][nf] = __builtin_amdgcn_mfma_f32_16x16x32_bf16(a0, bv, acc[0][nf], 0, 0, 0);
        acc[1][nf] = __builtin_amdgcn_mfma_f32_16x16x32_bf16(a1, bv, acc[1][nf], 0, 0, 0);
      }
    }
    __syncthreads();
  }

  int h = h0 + wv;
#pragma unroll
  for (int o16 = 0; o16 < 2; o16++) {
    int ob = o16 * 16 + ((lane >> 4) << 2);
    float bb0 = b1s[ob], bb1 = b1s[ob + 1], bb2 = b1s[ob + 2], bb3 = b1s[ob + 3];
#pragma unroll
    for (int nf = 0; nf < 8; nf++) {
      int px = nf * 16 + (lane & 15);
      bf16x4 r;
      r[0] = (__bf16)fmaxf(acc[o16][nf][0] + bb0, 0.f);
      r[1] = (__bf16)fmaxf(acc[o16][nf][1] + bb1, 0.f);
      r[2] = (__bf16)fmaxf(acc[o16][nf][2] + bb2, 0.f);
      r[3] = (__bf16)fmaxf(acc[o16][nf][3] + bb3, 0.f);
      *(bf16x4*)(t1T + (((size_t)(b * 128 + h) * 128 + px)) * 32 + ob) = r;
    }
  }
}

// ---------------------------------------------------------------------------
// K2: maxpool 2x2 -> p1T[b][hp68][wp68][32ch] bf16, zero-padded 2 ring.
// ---------------------------------------------------------------------------
__global__ __launch_bounds__(256) void k_pool(const __bf16* __restrict__ t1T,
                                              __bf16* __restrict__ p1T)
{
  int id = blockIdx.x * 256 + threadIdx.x;
  if (id >= 8 * 68 * 68) return;
  int wp = id % 68, hp = (id / 68) % 68, b = id / (68 * 68);
  __bf16* dst = p1T + (size_t)id * 32;
  int ph = hp - 2, pw = wp - 2;
  if (((unsigned)ph >= 64u) || ((unsigned)pw >= 64u)) {
    bf16x8 z = {};
#pragma unroll
    for (int g = 0; g < 4; g++) *(bf16x8*)(dst + g * 8) = z;
    return;
  }
  const __bf16* s = t1T + (((size_t)(b * 128) + ph * 2) * 128 + pw * 2) * 32;
#pragma unroll
  for (int g = 0; g < 4; g++) {
    bf16x8 v0 = *(const bf16x8*)(s + g * 8);
    bf16x8 v1 = *(const bf16x8*)(s + 32 + g * 8);
    bf16x8 v2 = *(const bf16x8*)(s + 4096 + g * 8);
    bf16x8 v3 = *(const bf16x8*)(s + 4128 + g * 8);
    bf16x8 r;
#pragma unroll
    for (int j = 0; j < 8; j++) {
      float m = fmaxf(fmaxf((float)v0[j], (float)v1[j]),
                      fmaxf((float)v2[j], (float)v3[j]));
      r[j] = (__bf16)m;
    }
    *(bf16x8*)(dst + g * 8) = r;
  }
}

// ---------------------------------------------------------------------------
// K3: conv2 via MFMA.
// ---------------------------------------------------------------------------
__global__ __launch_bounds__(256) void k_conv2m(
    const __bf16* __restrict__ p1T, const __bf16* __restrict__ w2frag,
    const float* __restrict__ b2s, float* __restrict__ t2)
{
  __shared__ alignas(16) char tile[34816];   // 8*68*64
  const int lane = threadIdx.x & 63;
  const int wv   = threadIdx.x >> 6;
  const int b    = blockIdx.x >> 4;
  const int h0   = (blockIdx.x & 15) * 4;

  f32x4 acc[4][4];
#pragma unroll
  for (int mf = 0; mf < 4; mf++)
#pragma unroll
    for (int nf = 0; nf < 4; nf++) acc[mf][nf] = (f32x4){0.f, 0.f, 0.f, 0.f};

  const char* src0 = (const char*)p1T + (((size_t)b * 68 + h0) * 68) * 64;
  for (int i = wv; i < 34; i += 4) {
    __builtin_amdgcn_global_load_lds(
        (const __attribute__((address_space(1))) void*)(src0 + i * 1024 + lane * 16),
        (__attribute__((address_space(3))) void*)((char*)tile + i * 1024), 16, 0, 0);
  }
  __syncthreads();

  const bf16x8* wf = (const bf16x8*)w2frag;
  const char* tb = (const char*)tile;
  for (int tap = 0; tap < 25; tap++) {
    int ky = tap / 5, kx = tap - ky * 5;
    bf16x8 a0 = wf[(tap * 4 + 0) * 64 + lane];
    bf16x8 a1 = wf[(tap * 4 + 1) * 64 + lane];
    bf16x8 a2 = wf[(tap * 4 + 2) * 64 + lane];
    bf16x8 a3 = wf[(tap * 4 + 3) * 64 + lane];
    const char* bp = tb + (((wv + ky) * 68 + kx + (lane & 15)) * 64) + (lane >> 4) * 16;
#pragma unroll
    for (int nf = 0; nf < 4; nf++) {
      bf16x8 bv = *(const bf16x8*)(bp + nf * 1024);
      acc[0][nf] = __builtin_amdgcn_mfma_f32_16x16x32_bf16(a0, bv, acc[0][nf], 0, 0, 0);
      acc[1][nf] = __builtin_amdgcn_mfma_f32_16x16x32_bf16(a1, bv, acc[1][nf], 0, 0, 0);
      acc[2][nf] = __builtin_amdgcn_mfma_f32_16x16x32_bf16(a2, bv, acc[2][nf], 0, 0, 0);
      acc[3][nf] = __builtin_amdgcn_mfma_f32_16x16x32_bf16(a3, bv, acc[3][nf], 0, 0, 0);
    }
  }

  int h = h0 + wv;
#pragma unroll
  for (int mf = 0; mf < 4; mf++) {
    int ob = mf * 16 + ((lane >> 4) << 2);
#pragma unroll
    for (int r = 0; r < 4; r++) {
      float bb = b2s[ob + r];
      float* orow = t2 + ((size_t)(b * 64 + ob + r)) * 4096 + h * 64 + (lane & 15);
#pragma unroll
      for (int nf = 0; nf < 4; nf++)
        orow[nf * 16] = fmaxf(acc[mf][nf][r] + bb, 0.f);
    }
  }
}

// ---------------------------------------------------------------------------
// K3b: deterministic spatial sum -> feat[b*64+co].
// ---------------------------------------------------------------------------
__global__ __launch_bounds__(256) void k_feat(const float* __restrict__ t2, float* __restrict__ feat)
{
  __shared__ float red[256];
  int bc = blockIdx.x;
  const float* s = t2 + (size_t)bc * 4096;
  float v = 0.f;
  for (int i = threadIdx.x; i < 4096; i += 256) v += s[i];
  red[threadIdx.x] = v;
  __syncthreads();
  for (int st = 128; st > 0; st >>= 1) {
    if (threadIdx.x < st) red[threadIdx.x] += red[threadIdx.x + st];
    __syncthreads();
  }
  if (threadIdx.x == 0) feat[bc] = red[0];
}

// ---------------------------------------------------------------------------
// K4: theta
// ---------------------------------------------------------------------------
__global__ void k_theta(const float* __restrict__ feat, const float* __restrict__ fc_w,
                        const float* __restrict__ fc_b, float* __restrict__ theta)
{
  int tid = threadIdx.x;
  if (tid >= 48) return;
  int b = tid / 6, i = tid - b * 6;
  float s = 0.f;
  for (int k = 0; k < 64; k++) s = fmaf(feat[b * 64 + k], fc_w[i * 64 + k], s);
  theta[tid] = fmaf(s, 1.f / 4096.f, fc_b[i]);
}

// ---------------------------------------------------------------------------
// Shared bilinear corner-address helper (clamped + masked weights).
// ---------------------------------------------------------------------------
__device__ __forceinline__ void bilin_setup(
    const __bf16* __restrict__ xb, float sy, float sx,
    const __bf16*& c00, const __bf16*& c01,
    const __bf16*& c10, const __bf16*& c11,
    float& w00, float& w01, float& w10, float& w11)
{
  float y0f = floorf(sy), x0f = floorf(sx);
  float wy1 = sy - y0f, wy0 = 1.f - wy1;
  float wx1 = sx - x0f, wx0 = 1.f - wx1;
  bool vy0 = (y0f >= 0.f) && (y0f <= 127.f);
  bool vy1 = (y0f >= -1.f) && (y0f <= 126.f);
  bool vx0 = (x0f >= 0.f) && (x0f <= 127.f);
  bool vx1 = (x0f >= -1.f) && (x0f <= 126.f);
  int yi0 = (int)fminf(fmaxf(y0f, 0.f), 127.f);
  int yi1 = (int)fminf(fmaxf(y0f + 1.f, 0.f), 127.f);
  int xi0 = (int)fminf(fmaxf(x0f, 0.f), 127.f);
  int xi1 = (int)fminf(fmaxf(x0f + 1.f, 0.f), 127.f);
  w00 = wy0 * wx0 * ((vy0 && vx0) ? 1.f : 0.f);
  w01 = wy0 * wx1 * ((vy0 && vx1) ? 1.f : 0.f);
  w10 = wy1 * wx0 * ((vy1 && vx0) ? 1.f : 0.f);
  w11 = wy1 * wx1 * ((vy1 && vx1) ? 1.f : 0.f);
  c00 = xb + ((size_t)((yi0 + 3) * 134) + xi0 + 3) * 64;
  c01 = xb + ((size_t)((yi0 + 3) * 134) + xi1 + 3) * 64;
  c10 = xb + ((size_t)((yi1 + 3) * 134) + xi0 + 3) * 64;
  c11 = xb + ((size_t)((yi1 + 3) * 134) + xi1 + 3) * 64;
}

// ---------------------------------------------------------------------------
// K6: deformable conv + fused STN sample, MANUAL 1-DEEP PIPELINE (R10).
// R9's unrolled loop still serialized (VGPR=64): compiler issued each tap's
// gathers then waited. Now tap k+1's 8 corner loads are issued BEFORE tap k's
// blend+MFMA, with named rotate registers -> gather latency hides under the
// ~300-cycle blend. All 18 offsets preloaded (static-indexed after unroll).
// ---------------------------------------------------------------------------
__global__ __launch_bounds__(256) void k_dcnm(
    const __bf16* __restrict__ xT, const float* __restrict__ off,
    const float* __restrict__ theta,
    const __bf16* __restrict__ dcnD, const float* __restrict__ dcn_b,
    __bf16* __restrict__ FdT, __bf16* __restrict__ FsT)
{
  const int lane = threadIdx.x & 63;
  const int wv   = threadIdx.x >> 6;
  const int swz  = xcd_swz(blockIdx.x, 256);
  const int b    = swz >> 8;
  const int rem  = swz & 255;
  const int h    = rem >> 1;
  const int px0  = (rem & 1) * 64 + wv * 16;
  const int l15  = lane & 15;
  const int g    = lane >> 4;
  const int w    = px0 + l15;

  const __bf16* xb = xT + (size_t)b * 134 * 134 * 64 + g * 8;  // + ch octet

  // ---- (1) issue STN-tap loads ----
  const __bf16 *sc00, *sc01, *sc10, *sc11;
  float sw00, sw01, sw10, sw11;
  {
    const float* t = theta + b * 6;
    float xn = (float)(2 * w + 1) * (1.f / 128.f) - 1.f;
    float yn = (float)(2 * h + 1) * (1.f / 128.f) - 1.f;
    float gxv = t[0] * xn + t[1] * yn + t[2];
    float gyv = t[3] * xn + t[4] * yn + t[5];
    float ix = fmaf(gxv, 64.f, 63.5f);
    float iy = fmaf(gyv, 64.f, 63.5f);
    bilin_setup(xb, iy, ix, sc00, sc01, sc10, sc11, sw00, sw01, sw10, sw11);
  }
  bf16x8 sa0 = *(const bf16x8*)(sc00),      sa1 = *(const bf16x8*)(sc01);
  bf16x8 sa2 = *(const bf16x8*)(sc10),      sa3 = *(const bf16x8*)(sc11);
  bf16x8 sb0 = *(const bf16x8*)(sc00 + 32), sb1 = *(const bf16x8*)(sc01 + 32);
  bf16x8 sb2 = *(const bf16x8*)(sc10 + 32), sb3 = *(const bf16x8*)(sc11 + 32);

  // ---- (2) preload all 18 offsets ----
  const float* ob = off + (size_t)b * 18 * HWn + h * 128 + w;
  float offs[18];
#pragma unroll
  for (int i = 0; i < 18; i++) offs[i] = ob[(size_t)i * HWn];

  // ---- (3) setup + issue tap-0 loads ----
  const __bf16 *cc00, *cc01, *cc10, *cc11;
  float cw00, cw01, cw10, cw11;
  {
    float sy = (float)(h - 1) + offs[0];
    float sx = (float)(w - 1) + offs[1];
    bilin_setup(xb, sy, sx, cc00, cc01, cc10, cc11, cw00, cw01, cw10, cw11);
  }
  bf16x8 ca0 = *(const bf16x8*)(cc00),      ca1 = *(const bf16x8*)(cc01);
  bf16x8 ca2 = *(const bf16x8*)(cc10),      ca3 = *(const bf16x8*)(cc11);
  bf16x8 cb0 = *(const bf16x8*)(cc00 + 32), cb1 = *(const bf16x8*)(cc01 + 32);
  bf16x8 cb2 = *(const bf16x8*)(cc10 + 32), cb3 = *(const bf16x8*)(cc11 + 32);

  // ---- (4) blend + store STN sample (tap-0 loads stay in flight) ----
  {
    __bf16* dst = FsT + ((size_t)b * HWn + h * 128 + w) * 64 + g * 8;
    bf16x8 r0, r1;
#pragma unroll
    for (int j = 0; j < 8; j++) {
      float f0 = sw00 * (float)sa0[j] + sw01 * (float)sa1[j]
               + sw10 * (float)sa2[j] + sw11 * (float)sa3[j];
      float f1 = sw00 * (float)sb0[j] + sw01 * (float)sb1[j]
               + sw10 * (float)sb2[j] + sw11 * (float)sb3[j];
      r0[j] = (__bf16)f0;
      r1[j] = (__bf16)f1;
    }
    *(bf16x8*)(dst) = r0;
    *(bf16x8*)(dst + 32) = r1;
  }

  // ---- (5) main pipeline: prefetch tap k+1, compute tap k ----
  f32x4 acc[4];
#pragma unroll
  for (int mf = 0; mf < 4; mf++) acc[mf] = (f32x4){0.f, 0.f, 0.f, 0.f};
  const bf16x8* aD = (const bf16x8*)dcnD;

#pragma unroll
  for (int k = 0; k < 9; k++) {
    // prefetch next tap
    bf16x8 na0 = ca0, na1 = ca1, na2 = ca2, na3 = ca3;
    bf16x8 nb0 = cb0, nb1 = cb1, nb2 = cb2, nb3 = cb3;
    float nw00 = 0.f, nw01 = 0.f, nw10 = 0.f, nw11 = 0.f;
    if (k < 8) {
      const __bf16 *n00, *n01, *n10, *n11;
      float sy = (float)(h + (k + 1) / 3 - 1) + offs[2 * (k + 1)];
      float sx = (float)(w + (k + 1) % 3 - 1) + offs[2 * (k + 1) + 1];
      bilin_setup(xb, sy, sx, n00, n01, n10, n11, nw00, nw01, nw10, nw11);
      na0 = *(const bf16x8*)(n00);      na1 = *(const bf16x8*)(n01);
      na2 = *(const bf16x8*)(n10);      na3 = *(const bf16x8*)(n11);
      nb0 = *(const bf16x8*)(n00 + 32); nb1 = *(const bf16x8*)(n01 + 32);
      nb2 = *(const bf16x8*)(n10 + 32); nb3 = *(const bf16x8*)(n11 + 32);
    }

    // compute current tap: s=0
    {
      bf16x8 a;
#pragma unroll
      for (int j = 0; j < 8; j++) {
        float f = cw00 * (float)ca0[j] + cw01 * (float)ca1[j]
                + cw10 * (float)ca2[j] + cw11 * (float)ca3[j];
        a[j] = (__bf16)f;
      }
      acc[0] = __builtin_amdgcn_mfma_f32_16x16x32_bf16(
          a, aD[((k * 2 + 0) * 4 + 0) * 64 + lane], acc[0], 0, 0, 0);
      acc[1] = __builtin_amdgcn_mfma_f32_16x16x32_bf16(
          a, aD[((k * 2 + 0) * 4 + 1) * 64 + lane], acc[1], 0, 0, 0);
      acc[2] = __builtin_amdgcn_mfma_f32_16x16x32_bf16(
          a, aD[((k * 2 + 0) * 4 + 2) * 64 + lane], acc[2], 0, 0, 0);
      acc[3] = __builtin_amdgcn_mfma_f32_16x16x32_bf16(
          a, aD[((k * 2 + 0) * 4 + 3) * 64 + lane], acc[3], 0, 0, 0);
    }
    // compute current tap: s=1
    {
      bf16x8 a;
#pragma unroll
      for (int j = 0; j < 8; j++) {
        float f = cw00 * (float)cb0[j] + cw01 * (float)cb1[j]
                + cw10 * (float)cb2[j] + cw11 * (float)cb3[j];
        a[j] = (__bf16)f;
      }
      acc[0] = __builtin_amdgcn_mfma_f32_16x16x32_bf16(
          a, aD[((k * 2 + 1) * 4 + 0) * 64 + lane], acc[0], 0, 0, 0);
      acc[1] = __builtin_amdgcn_mfma_f32_16x16x32_bf16(
          a, aD[((k * 2 + 1) * 4 + 1) * 64 + lane], acc[1], 0, 0, 0);
      acc[2] = __builtin_amdgcn_mfma_f32_16x16x32_bf16(
          a, aD[((k * 2 + 1) * 4 + 2) * 64 + lane], acc[2], 0, 0, 0);
      acc[3] = __builtin_amdgcn_mfma_f32_16x16x32_bf16(
          a, aD[((k * 2 + 1) * 4 + 3) * 64 + lane], acc[3], 0, 0, 0);
    }

    // rotate
    ca0 = na0; ca1 = na1; ca2 = na2; ca3 = na3;
    cb0 = nb0; cb1 = nb1; cb2 = nb2; cb3 = nb3;
    cw00 = nw00; cw01 = nw01; cw10 = nw10; cw11 = nw11;
  }

  // ---- (6) epilogue: D row(pixel)=g*4+r, col(out)=mf*16+l15 ----
  __bf16* fb = FdT + ((size_t)b * HWn + h * 128 + px0) * 64;
#pragma unroll
  for (int mf = 0; mf < 4; mf++) {
    int o = mf * 16 + l15;
    float bias = dcn_b[o];
#pragma unroll
    for (int r = 0; r < 4; r++) {
      int pxl = g * 4 + r;
      fb[(size_t)pxl * 64 + o] = (__bf16)(acc[mf][r] + bias);
    }
  }
}

// ---------------------------------------------------------------------------
// K7: fusion -> fusedT bf16 channels-last, zero-padded 2 ring [b][132][132][64].
// ---------------------------------------------------------------------------
__global__ __launch_bounds__(256) void k_fuseT(
    const __bf16* __restrict__ FsT, const __bf16* __restrict__ FdT,
    const float* __restrict__ wg_w, const float* __restrict__ wg_b,
    __bf16* __restrict__ fusedT)
{
  int id = blockIdx.x * 256 + threadIdx.x;
  if (id >= 8 * 132 * 132) return;
  int wp = id % 132;
  int hp = (id / 132) % 132;
  int b  = id / (132 * 132);
  __bf16* dst = fusedT + (size_t)id * 64;
  int h = hp - 2, w = wp - 2;
  if (((unsigned)h >= 128u) || ((unsigned)w >= 128u)) {
    bf16x8 z = {};
#pragma unroll
    for (int oct = 0; oct < 8; oct++) *(bf16x8*)(dst + oct * 8) = z;
    return;
  }
  const bf16x8* fs = (const bf16x8*)(FsT + ((size_t)b * HWn + h * 128 + w) * 64);
  const bf16x8* fd = (const bf16x8*)(FdT + ((size_t)b * HWn + h * 128 + w) * 64);
  bf16x8 fsv[8], fdv[8];
  float s0 = wg_b[0], s1 = wg_b[1];
#pragma unroll
  for (int oct = 0; oct < 8; oct++) {
    fsv[oct] = fs[oct];
    fdv[oct] = fd[oct];
#pragma unroll
    for (int j = 0; j < 8; j++) {
      int c = oct * 8 + j;
      float a = (float)fsv[oct][j], d = (float)fdv[oct][j];
      s0 = fmaf(wg_w[c],       a, fmaf(wg_w[64 + c],  d, s0));
      s1 = fmaf(wg_w[128 + c], a, fmaf(wg_w[192 + c], d, s1));
    }
  }
  float p0 = 1.f / (1.f + __expf(s1 - s0));
  float p1 = 1.f - p0;
#pragma unroll
  for (int oct = 0; oct < 8; oct++) {
    bf16x8 r;
#pragma unroll
    for (int j = 0; j < 8; j++)
      r[j] = (__bf16)(p0 * (float)fsv[oct][j] + p1 * (float)fdv[oct][j]);
    *(bf16x8*)(dst + oct * 8) = r;
  }
}

// ---------------------------------------------------------------------------
// K8: collapsed ELK via MFMA. XCD swizzle chunk 64 => XCD k = batch k.
// ---------------------------------------------------------------------------
__global__ __launch_bounds__(256) void k_elkm(
    const __bf16* __restrict__ fusedT, const __bf16* __restrict__ weffD,
    const float* __restrict__ beff, float* __restrict__ out)
{
  const int DY[13] = {-2,-1,-1,-1, 0, 0, 0, 0, 0, 1, 1, 1, 2};
  const int DX[13] = { 0,-1, 0, 1,-2,-1, 0, 1, 2,-1, 0, 1, 0};
  const int lane = threadIdx.x & 63;
  const int wv   = threadIdx.x >> 6;
  const int swz  = xcd_swz(blockIdx.x, 64);
  const int b    = swz >> 6;
  const int h    = (swz & 63) * 2 + (wv >> 1);
  const int half = wv & 1;

  f32x4 acc[4][4];
#pragma unroll
  for (int mf = 0; mf < 4; mf++)
#pragma unroll
    for (int nf = 0; nf < 4; nf++) acc[mf][nf] = (f32x4){0.f, 0.f, 0.f, 0.f};

  const bf16x8* aD = (const bf16x8*)weffD;

  for (int t = 0; t < 13; t++) {
    int hp = h + 2 + DY[t];
    const __bf16* base = fusedT
        + ((size_t)((b * 132 + hp) * 132) + half * 64 + 2 + DX[t]) * 64;
#pragma unroll
    for (int s = 0; s < 2; s++) {
      bf16x8 a0 = aD[((t * 2 + s) * 4 + 0) * 64 + lane];
      bf16x8 a1 = aD[((t * 2 + s) * 4 + 1) * 64 + lane];
      bf16x8 a2 = aD[((t * 2 + s) * 4 + 2) * 64 + lane];
      bf16x8 a3 = aD[((t * 2 + s) * 4 + 3) * 64 + lane];
#pragma unroll
      for (int nf = 0; nf < 4; nf++) {
        bf16x8 bv = *(const bf16x8*)(base + (size_t)(nf * 16 + (lane & 15)) * 64
                                          + s * 32 + (lane >> 4) * 8);
        acc[0][nf] = __builtin_amdgcn_mfma_f32_16x16x32_bf16(a0, bv, acc[0][nf], 0, 0, 0);
        acc[1][nf] = __builtin_amdgcn_mfma_f32_16x16x32_bf16(a1, bv, acc[1][nf], 0, 0, 0);
        acc[2][nf] = __builtin_amdgcn_mfma_f32_16x16x32_bf16(a2, bv, acc[2][nf], 0, 0, 0);
        acc[3][nf] = __builtin_amdgcn_mfma_f32_16x16x32_bf16(a3, bv, acc[3][nf], 0, 0, 0);
      }
    }
  }

#pragma unroll
  for (int mf = 0; mf < 4; mf++) {
    int ob = mf * 16 + ((lane >> 4) << 2);
#pragma unroll
    for (int r = 0; r < 4; r++) {
      int o = ob + r;
      float bb = beff[o];
      float* orow = out + ((size_t)(b * 64 + o)) * HWn + h * 128 + half * 64 + (lane & 15);
#pragma unroll
      for (int nf = 0; nf < 4; nf++)
        orow[nf * 16] = acc[mf][nf][r] + bb;
    }
  }
}

// ---------------------------------------------------------------------------
// Workspace layout unchanged from R5/R6 (sizes verified in floats):
// Region A [0, 4,596,736): xT -> fusedT (after k_dcnm).
// Region B [4,596,736, 9,536,512): xC -> FsT (xC dead after conv1m; FsT
//          written by k_dcnm which runs after conv1m). OK.
// Region C [9,536,512, 14,322,688): t1T/p1T/t2 -> FdT (after k_feat).
// Tail: feat/theta/wfrag/w2frag/beff/dcnD/weffD @14,322,688.. end 14,444,160.
// ---------------------------------------------------------------------------
extern "C" void kernel_launch(void* const* d_in, const int* in_sizes, int n_in,
                              void* d_out, int out_size, void* d_ws, size_t ws_size,
                              hipStream_t stream)
{
  (void)in_sizes; (void)n_in; (void)out_size; (void)ws_size;
  const float* x      = (const float*)d_in[0];
  const float* offset = (const float*)d_in[1];
  const float* stn_w1 = (const float*)d_in[2];
  const float* stn_b1 = (const float*)d_in[3];
  const float* stn_w2 = (const float*)d_in[4];
  const float* stn_b2 = (const float*)d_in[5];
  const float* fc_w   = (const float*)d_in[6];
  const float* fc_b   = (const float*)d_in[7];
  const float* dcn_w  = (const float*)d_in[8];
  const float* dcn_b  = (const float*)d_in[9];
  const float* wg_w   = (const float*)d_in[10];
  const float* wg_b   = (const float*)d_in[11];
  const float* w3     = (const float*)d_in[12];
  const float* b3     = (const float*)d_in[13];
  const float* w15    = (const float*)d_in[14];
  const float* b15    = (const float*)d_in[15];
  const float* w51    = (const float*)d_in[16];
  const float* b51    = (const float*)d_in[17];
  const float* w1     = (const float*)d_in[18];
  const float* b1     = (const float*)d_in[19];

  float* ws      = (float*)d_ws;
  __bf16* xT     = (__bf16*)ws;
  __bf16* fusedT = (__bf16*)ws;
  __bf16* xC     = (__bf16*)(ws + 4596736);
  __bf16* FsT    = (__bf16*)(ws + 4596736);
  __bf16* t1T    = (__bf16*)(ws + 9536512);
  __bf16* FdT    = (__bf16*)(ws + 9536512);
  __bf16* p1T    = (__bf16*)(ws + 11633664);
  float*  t2     = ws + 12225536;
  float*  feat   = ws + 14322688;
  float*  theta  = ws + 14323200;
  __bf16* wfrag  = (__bf16*)(ws + 14323264);
  __bf16* w2frag = (__bf16*)(ws + 14373440);
  float*  beff   = ws + 14399040;
  __bf16* dcnD   = (__bf16*)(ws + 14399104);
  __bf16* weffD  = (__bf16*)(ws + 14417536);
  float*  out    = (float*)d_out;

  k_prep  <<<1,    64,  0, stream>>>(w1, b3, b15, b51, b1, beff);
  k_xt    <<<562,  256, 0, stream>>>(x, xT, xC);
  k_wf    <<<392,  256, 0, stream>>>(stn_w1, wfrag);
  k_frag  <<<552,  256, 0, stream>>>(dcn_w, w1, w3, w15, w51, stn_w2, dcnD, weffD, w2frag);
  k_conv1m<<<512,  128, 0, stream>>>(xC, wfrag, stn_b1, t1T);
  k_pool  <<<145,  256, 0, stream>>>(t1T, p1T);
  k_conv2m<<<128,  256, 0, stream>>>(p1T, w2frag, stn_b2, t2);
  k_feat  <<<512,  256, 0, stream>>>(t2, feat);
  k_theta <<<1,    64,  0, stream>>>(feat, fc_w, fc_b, theta);
  k_dcnm  <<<2048, 256, 0, stream>>>(xT, offset, theta, dcnD, dcn_b, FdT, FsT);
  k_fuseT <<<545,  256, 0, stream>>>(FsT, FdT, wg_w, wg_b, fusedT);
  k_elkm  <<<512,  256, 0, stream>>>(fusedT, weffD, beff, out);
}

// Round 11
// 219.418 us; speedup vs baseline: 1.3211x; 1.2555x over previous
//
#include <hip/hip_runtime.h>
#include <math.h>

// Problem dims
#define Bn 8
#define Cn 64
#define Hn 128
#define Wn 128
#define HWn 16384

typedef __attribute__((ext_vector_type(8))) __bf16 bf16x8;
typedef __attribute__((ext_vector_type(4))) __bf16 bf16x4;
typedef __attribute__((ext_vector_type(4))) float f32x4;

// XCD-aware bijective swizzle: grid = 8*chunk blocks; XCD k (bid%8) gets the
// contiguous work range [k*chunk,(k+1)*chunk) => per-XCD L2-resident slice.
__device__ __forceinline__ int xcd_swz(int bid, int chunk) {
  return (bid & 7) * chunk + (bid >> 3);
}

// ---------------------------------------------------------------------------
// K0: beff (collapsed ELK bias) only.
// ---------------------------------------------------------------------------
__global__ void k_prep(const float* __restrict__ w1, const float* __restrict__ b3,
                       const float* __restrict__ b15, const float* __restrict__ b51,
                       const float* __restrict__ b1, float* __restrict__ beff)
{
  int e = threadIdx.x;
  if (e >= 64) return;
  float s = b1[e];
  for (int m = 0; m < 64; m++) {
    s = fmaf(w1[e * 192 + m],       b3[m],  s);
    s = fmaf(w1[e * 192 + 64 + m],  b15[m], s);
    s = fmaf(w1[e * 192 + 128 + m], b51[m], s);
  }
  beff[e] = s;
}

// ---------------------------------------------------------------------------
// K-xt: x (NCHW f32) -> xT[b][hp134][wp134][c64] bf16 (3-pad ring)
//                    -> xC[b][oct8][hp134][slot144][8ch] bf16 (conv1 staging)
// ---------------------------------------------------------------------------
__global__ __launch_bounds__(256) void k_xt(const float* __restrict__ x,
                                            __bf16* __restrict__ xT,
                                            __bf16* __restrict__ xC)
{
  int t = blockIdx.x * 256 + threadIdx.x;
  if (t >= 8 * 134 * 134) return;
  int wp = t % 134;
  int hp = (t / 134) % 134;
  int b  = t / (134 * 134);
  int h = hp - 3, w = wp - 3;
  bool inb = ((unsigned)h < 128u) && ((unsigned)w < 128u);
  const float* xb = x + (size_t)b * Cn * HWn + h * 128 + w;
  __bf16* dst = xT + (size_t)t * 64;
#pragma unroll
  for (int oct = 0; oct < 8; oct++) {
    bf16x8 v;
#pragma unroll
    for (int j = 0; j < 8; j++)
      v[j] = inb ? (__bf16)xb[(size_t)(oct * 8 + j) * HWn] : (__bf16)0.f;
    *(bf16x8*)(dst + oct * 8) = v;
    *(bf16x8*)(xC + ((((size_t)b * 8 + oct) * 134 + hp) * 144 + wp) * 8) = v;
  }
}

// ---------------------------------------------------------------------------
// K-wf: stn_w1 -> A-fragment layout for conv1 MFMA.
// ---------------------------------------------------------------------------
__global__ __launch_bounds__(256) void k_wf(const float* __restrict__ stn_w1,
                                            __bf16* __restrict__ wfrag)
{
  int t = blockIdx.x * 256 + threadIdx.x;
  if (t >= 100352) return;
  int e   = t & 7;
  int l   = (t >> 3) & 63;
  int o16 = (t >> 9) & 1;
  int ck  = (t >> 10) & 1;
  int tap = t >> 11;
  int o = o16 * 16 + (l & 15);
  int c = ck * 32 + (l >> 4) * 8 + e;
  wfrag[t] = (__bf16)stn_w1[(o * 64 + c) * 49 + tap];
}

// ---------------------------------------------------------------------------
// K-frag: A-fragments for DCN (9 taps), collapsed ELK (13 taps), conv2 (25 taps).
// ---------------------------------------------------------------------------
__global__ __launch_bounds__(256) void k_frag(
    const float* __restrict__ dcn_w, const float* __restrict__ w1,
    const float* __restrict__ w3, const float* __restrict__ w15,
    const float* __restrict__ w51, const float* __restrict__ stn_w2,
    __bf16* __restrict__ dcnD, __bf16* __restrict__ weffD,
    __bf16* __restrict__ w2frag)
{
  int t = blockIdx.x * 256 + threadIdx.x;
  if (t < 36864) {
    int e = t & 7, l = (t >> 3) & 63, mf = (t >> 9) & 3, s = (t >> 11) & 1;
    int tap = t >> 12;
    int o = mf * 16 + (l & 15), c = s * 32 + (l >> 4) * 8 + e;
    dcnD[t] = (__bf16)dcn_w[(o * 64 + c) * 9 + tap];
    return;
  }
  t -= 36864;
  if (t < 53248) {
    const int DY[13] = {-2,-1,-1,-1, 0, 0, 0, 0, 0, 1, 1, 1, 2};
    const int DX[13] = { 0,-1, 0, 1,-2,-1, 0, 1, 2,-1, 0, 1, 0};
    int e = t & 7, l = (t >> 3) & 63, mf = (t >> 9) & 3, s = (t >> 11) & 1;
    int tap = t >> 12;
    int o = mf * 16 + (l & 15), c = s * 32 + (l >> 4) * 8 + e;
    int dy = DY[tap], dx = DX[tap];
    float v = 0.f;
    if (dy >= -1 && dy <= 1 && dx >= -1 && dx <= 1) {
      int k3 = (dy + 1) * 3 + (dx + 1);
      for (int m = 0; m < 64; m++) v = fmaf(w1[o * 192 + m], w3[(m * 64 + c) * 9 + k3], v);
    }
    if (dy == 0) {
      int k15 = dx + 2;
      for (int m = 0; m < 64; m++) v = fmaf(w1[o * 192 + 64 + m], w15[(m * 64 + c) * 5 + k15], v);
    }
    if (dx == 0) {
      int k51 = dy + 2;
      for (int m = 0; m < 64; m++) v = fmaf(w1[o * 192 + 128 + m], w51[(m * 64 + c) * 5 + k51], v);
    }
    weffD[t] = (__bf16)v;
    return;
  }
  t -= 53248;
  if (t < 51200) {   // conv2 A-frags: [tap25][mf4][lane64][e8]
    int e = t & 7, l = (t >> 3) & 63, mf = (t >> 9) & 3;
    int tap = t >> 11;
    int o = mf * 16 + (l & 15), c = (l >> 4) * 8 + e;
    w2frag[t] = (__bf16)stn_w2[(o * 32 + c) * 25 + tap];
  }
}

// ---------------------------------------------------------------------------
// K1: STN conv1 via MFMA, contiguous 1KB global_load_lds staging from xC.
// ---------------------------------------------------------------------------
__global__ __launch_bounds__(128) void k_conv1m(
    const __bf16* __restrict__ xC, const __bf16* __restrict__ wfrag,
    const float* __restrict__ b1s, __bf16* __restrict__ t1T)
{
  __shared__ alignas(16) char tile[73728];   // [q4][r8][slot144][16B]
  const int lane = threadIdx.x & 63;
  const int wv   = threadIdx.x >> 6;
  const int swz  = xcd_swz(blockIdx.x, 64);
  const int b    = swz >> 6;
  const int h0   = (swz & 63) * 2;

  f32x4 acc[2][8];
#pragma unroll
  for (int o16 = 0; o16 < 2; o16++)
#pragma unroll
    for (int nf = 0; nf < 8; nf++) acc[o16][nf] = (f32x4){0.f, 0.f, 0.f, 0.f};

  const bf16x8* wf = (const bf16x8*)wfrag;
  const char* tb = (const char*)tile;
  const char* xCb = (const char*)xC;

  for (int ck = 0; ck < 2; ck++) {
    for (int i = wv; i < 72; i += 2) {
      int q = i / 18;
      int t = i - q * 18;
      const char* src = xCb
          + (((size_t)(b * 8 + ck * 4 + q) * 134 + h0) * 2304) + t * 1024 + lane * 16;
      char* dst = (char*)tile + i * 1024;
      __builtin_amdgcn_global_load_lds(
          (const __attribute__((address_space(1))) void*)src,
          (__attribute__((address_space(3))) void*)dst, 16, 0, 0);
    }
    __syncthreads();

    for (int tap = 0; tap < 49; tap++) {
      int dy7 = tap / 7;
      int dx7 = tap - dy7 * 7;
      bf16x8 a0 = wf[((tap * 2 + ck) * 2 + 0) * 64 + lane];
      bf16x8 a1 = wf[((tap * 2 + ck) * 2 + 1) * 64 + lane];
      const char* bp = tb + (lane >> 4) * 18432 + (wv + dy7) * 2304
                          + (dx7 + (lane & 15)) * 16;
#pragma unroll
      for (int nf = 0; nf < 8; nf++) {
        bf16x8 bv = *(const bf16x8*)(bp + nf * 256);
        acc[0][nf] = __builtin_amdgcn_mfma_f32_16x16x32_bf16(a0, bv, acc[0][nf], 0, 0, 0);
        acc[1][nf] = __builtin_amdgcn_mfma_f32_16x16x32_bf16(a1, bv, acc[1][nf], 0, 0, 0);
      }
    }
    __syncthreads();
  }

  int h = h0 + wv;
#pragma unroll
  for (int o16 = 0; o16 < 2; o16++) {
    int ob = o16 * 16 + ((lane >> 4) << 2);
    float bb0 = b1s[ob], bb1 = b1s[ob + 1], bb2 = b1s[ob + 2], bb3 = b1s[ob + 3];
#pragma unroll
    for (int nf = 0; nf < 8; nf++) {
      int px = nf * 16 + (lane & 15);
      bf16x4 r;
      r[0] = (__bf16)fmaxf(acc[o16][nf][0] + bb0, 0.f);
      r[1] = (__bf16)fmaxf(acc[o16][nf][1] + bb1, 0.f);
      r[2] = (__bf16)fmaxf(acc[o16][nf][2] + bb2, 0.f);
      r[3] = (__bf16)fmaxf(acc[o16][nf][3] + bb3, 0.f);
      *(bf16x4*)(t1T + (((size_t)(b * 128 + h) * 128 + px)) * 32 + ob) = r;
    }
  }
}

// ---------------------------------------------------------------------------
// K2: maxpool 2x2 -> p1T[b][hp68][wp68][32ch] bf16, zero-padded 2 ring.
// ---------------------------------------------------------------------------
__global__ __launch_bounds__(256) void k_pool(const __bf16* __restrict__ t1T,
                                              __bf16* __restrict__ p1T)
{
  int id = blockIdx.x * 256 + threadIdx.x;
  if (id >= 8 * 68 * 68) return;
  int wp = id % 68, hp = (id / 68) % 68, b = id / (68 * 68);
  __bf16* dst = p1T + (size_t)id * 32;
  int ph = hp - 2, pw = wp - 2;
  if (((unsigned)ph >= 64u) || ((unsigned)pw >= 64u)) {
    bf16x8 z = {};
#pragma unroll
    for (int g = 0; g < 4; g++) *(bf16x8*)(dst + g * 8) = z;
    return;
  }
  const __bf16* s = t1T + (((size_t)(b * 128) + ph * 2) * 128 + pw * 2) * 32;
#pragma unroll
  for (int g = 0; g < 4; g++) {
    bf16x8 v0 = *(const bf16x8*)(s + g * 8);
    bf16x8 v1 = *(const bf16x8*)(s + 32 + g * 8);
    bf16x8 v2 = *(const bf16x8*)(s + 4096 + g * 8);
    bf16x8 v3 = *(const bf16x8*)(s + 4128 + g * 8);
    bf16x8 r;
#pragma unroll
    for (int j = 0; j < 8; j++) {
      float m = fmaxf(fmaxf((float)v0[j], (float)v1[j]),
                      fmaxf((float)v2[j], (float)v3[j]));
      r[j] = (__bf16)m;
    }
    *(bf16x8*)(dst + g * 8) = r;
  }
}

// ---------------------------------------------------------------------------
// K3: conv2 via MFMA.
// ---------------------------------------------------------------------------
__global__ __launch_bounds__(256) void k_conv2m(
    const __bf16* __restrict__ p1T, const __bf16* __restrict__ w2frag,
    const float* __restrict__ b2s, float* __restrict__ t2)
{
  __shared__ alignas(16) char tile[34816];   // 8*68*64
  const int lane = threadIdx.x & 63;
  const int wv   = threadIdx.x >> 6;
  const int b    = blockIdx.x >> 4;
  const int h0   = (blockIdx.x & 15) * 4;

  f32x4 acc[4][4];
#pragma unroll
  for (int mf = 0; mf < 4; mf++)
#pragma unroll
    for (int nf = 0; nf < 4; nf++) acc[mf][nf] = (f32x4){0.f, 0.f, 0.f, 0.f};

  const char* src0 = (const char*)p1T + (((size_t)b * 68 + h0) * 68) * 64;
  for (int i = wv; i < 34; i += 4) {
    __builtin_amdgcn_global_load_lds(
        (const __attribute__((address_space(1))) void*)(src0 + i * 1024 + lane * 16),
        (__attribute__((address_space(3))) void*)((char*)tile + i * 1024), 16, 0, 0);
  }
  __syncthreads();

  const bf16x8* wf = (const bf16x8*)w2frag;
  const char* tb = (const char*)tile;
  for (int tap = 0; tap < 25; tap++) {
    int ky = tap / 5, kx = tap - ky * 5;
    bf16x8 a0 = wf[(tap * 4 + 0) * 64 + lane];
    bf16x8 a1 = wf[(tap * 4 + 1) * 64 + lane];
    bf16x8 a2 = wf[(tap * 4 + 2) * 64 + lane];
    bf16x8 a3 = wf[(tap * 4 + 3) * 64 + lane];
    const char* bp = tb + (((wv + ky) * 68 + kx + (lane & 15)) * 64) + (lane >> 4) * 16;
#pragma unroll
    for (int nf = 0; nf < 4; nf++) {
      bf16x8 bv = *(const bf16x8*)(bp + nf * 1024);
      acc[0][nf] = __builtin_amdgcn_mfma_f32_16x16x32_bf16(a0, bv, acc[0][nf], 0, 0, 0);
      acc[1][nf] = __builtin_amdgcn_mfma_f32_16x16x32_bf16(a1, bv, acc[1][nf], 0, 0, 0);
      acc[2][nf] = __builtin_amdgcn_mfma_f32_16x16x32_bf16(a2, bv, acc[2][nf], 0, 0, 0);
      acc[3][nf] = __builtin_amdgcn_mfma_f32_16x16x32_bf16(a3, bv, acc[3][nf], 0, 0, 0);
    }
  }

  int h = h0 + wv;
#pragma unroll
  for (int mf = 0; mf < 4; mf++) {
    int ob = mf * 16 + ((lane >> 4) << 2);
#pragma unroll
    for (int r = 0; r < 4; r++) {
      float bb = b2s[ob + r];
      float* orow = t2 + ((size_t)(b * 64 + ob + r)) * 4096 + h * 64 + (lane & 15);
#pragma unroll
      for (int nf = 0; nf < 4; nf++)
        orow[nf * 16] = fmaxf(acc[mf][nf][r] + bb, 0.f);
    }
  }
}

// ---------------------------------------------------------------------------
// K3b: deterministic spatial sum -> feat[b*64+co].
// ---------------------------------------------------------------------------
__global__ __launch_bounds__(256) void k_feat(const float* __restrict__ t2, float* __restrict__ feat)
{
  __shared__ float red[256];
  int bc = blockIdx.x;
  const float* s = t2 + (size_t)bc * 4096;
  float v = 0.f;
  for (int i = threadIdx.x; i < 4096; i += 256) v += s[i];
  red[threadIdx.x] = v;
  __syncthreads();
  for (int st = 128; st > 0; st >>= 1) {
    if (threadIdx.x < st) red[threadIdx.x] += red[threadIdx.x + st];
    __syncthreads();
  }
  if (threadIdx.x == 0) feat[bc] = red[0];
}

// ---------------------------------------------------------------------------
// K4: theta
// ---------------------------------------------------------------------------
__global__ void k_theta(const float* __restrict__ feat, const float* __restrict__ fc_w,
                        const float* __restrict__ fc_b, float* __restrict__ theta)
{
  int tid = threadIdx.x;
  if (tid >= 48) return;
  int b = tid / 6, i = tid - b * 6;
  float s = 0.f;
  for (int k = 0; k < 64; k++) s = fmaf(feat[b * 64 + k], fc_w[i * 64 + k], s);
  theta[tid] = fmaf(s, 1.f / 4096.f, fc_b[i]);
}

// ---------------------------------------------------------------------------
// Shared bilinear corner-address helper (clamped + masked weights).
// ---------------------------------------------------------------------------
__device__ __forceinline__ void bilin_setup(
    const __bf16* __restrict__ xb, float sy, float sx,
    const __bf16*& c00, const __bf16*& c01,
    const __bf16*& c10, const __bf16*& c11,
    float& w00, float& w01, float& w10, float& w11)
{
  float y0f = floorf(sy), x0f = floorf(sx);
  float wy1 = sy - y0f, wy0 = 1.f - wy1;
  float wx1 = sx - x0f, wx0 = 1.f - wx1;
  bool vy0 = (y0f >= 0.f) && (y0f <= 127.f);
  bool vy1 = (y0f >= -1.f) && (y0f <= 126.f);
  bool vx0 = (x0f >= 0.f) && (x0f <= 127.f);
  bool vx1 = (x0f >= -1.f) && (x0f <= 126.f);
  int yi0 = (int)fminf(fmaxf(y0f, 0.f), 127.f);
  int yi1 = (int)fminf(fmaxf(y0f + 1.f, 0.f), 127.f);
  int xi0 = (int)fminf(fmaxf(x0f, 0.f), 127.f);
  int xi1 = (int)fminf(fmaxf(x0f + 1.f, 0.f), 127.f);
  w00 = wy0 * wx0 * ((vy0 && vx0) ? 1.f : 0.f);
  w01 = wy0 * wx1 * ((vy0 && vx1) ? 1.f : 0.f);
  w10 = wy1 * wx0 * ((vy1 && vx0) ? 1.f : 0.f);
  w11 = wy1 * wx1 * ((vy1 && vx1) ? 1.f : 0.f);
  c00 = xb + ((size_t)((yi0 + 3) * 134) + xi0 + 3) * 64;
  c01 = xb + ((size_t)((yi0 + 3) * 134) + xi1 + 3) * 64;
  c10 = xb + ((size_t)((yi1 + 3) * 134) + xi0 + 3) * 64;
  c11 = xb + ((size_t)((yi1 + 3) * 134) + xi1 + 3) * 64;
}

// ---------------------------------------------------------------------------
// K6: deformable conv + fused STN sample — R11: QUAD-COALESCED gathers.
// Diagnosis: previous mapping (px=l&15, oct=l>>4) put 4 different cache lines
// in every 4-lane quad -> ~64 TA requests per gather instr (1 lane-req/cycle,
// 68us floor = observed). New gather mapping (px=l>>2, q=l&3): a quad reads
// one corner's contiguous 64B = 1 line -> 16 req/instr (4x fewer).
// Lane (px,q) holds all 4 corners' (q, s) chunks, blends octets {q, q+4},
// and a tiny same-wave LDS round-trip (XOR-swizzled, c^=px&7) re-lanes the
// blended sample into the MFMA A-fragment layout. STN tap: blend + direct
// coalesced FsT store. LDS 2KB/wave.
// ---------------------------------------------------------------------------
__global__ __launch_bounds__(256) void k_dcnm(
    const __bf16* __restrict__ xT, const float* __restrict__ off,
    const float* __restrict__ theta,
    const __bf16* __restrict__ dcnD, const float* __restrict__ dcn_b,
    __bf16* __restrict__ FdT, __bf16* __restrict__ FsT)
{
  __shared__ alignas(16) char smem[4][2048];
  const int lane = threadIdx.x & 63;
  const int wv   = threadIdx.x >> 6;
  const int swz  = xcd_swz(blockIdx.x, 256);
  const int b    = swz >> 8;
  const int rem  = swz & 255;
  const int h    = rem >> 1;
  const int px0  = (rem & 1) * 64 + wv * 16;
  const int l15  = lane & 15;
  const int g    = lane >> 4;
  const int pg   = lane >> 2;          // gather pixel 0..15
  const int q    = lane & 3;           // 16B chunk within 64B half
  const int wg   = px0 + pg;           // gather lane's pixel column

  const __bf16* xb = xT + (size_t)b * 134 * 134 * 64;
  char* sm = smem[wv];

  // offsets for the gather pixel (4 lanes share an address -> broadcast)
  const float* ob = off + (size_t)b * 18 * HWn + h * 128 + wg;
  float offs[18];
#pragma unroll
  for (int i = 0; i < 18; i++) offs[i] = ob[(size_t)i * HWn];

  // ---- fused STN sample: blend + coalesced store to FsT ----
  {
    const float* t = theta + b * 6;
    float xn = (float)(2 * wg + 1) * (1.f / 128.f) - 1.f;
    float yn = (float)(2 * h + 1) * (1.f / 128.f) - 1.f;
    float gxv = t[0] * xn + t[1] * yn + t[2];
    float gyv = t[3] * xn + t[4] * yn + t[5];
    float ix = fmaf(gxv, 64.f, 63.5f);
    float iy = fmaf(gyv, 64.f, 63.5f);
    const __bf16 *c00, *c01, *c10, *c11;
    float w00, w01, w10, w11;
    bilin_setup(xb, iy, ix, c00, c01, c10, c11, w00, w01, w10, w11);
    __bf16* dst = FsT + ((size_t)b * HWn + h * 128 + wg) * 64;
#pragma unroll
    for (int s = 0; s < 2; s++) {
      int eo = q * 8 + s * 32;
      bf16x8 v00 = *(const bf16x8*)(c00 + eo);
      bf16x8 v01 = *(const bf16x8*)(c01 + eo);
      bf16x8 v10 = *(const bf16x8*)(c10 + eo);
      bf16x8 v11 = *(const bf16x8*)(c11 + eo);
      bf16x8 r;
#pragma unroll
      for (int j = 0; j < 8; j++) {
        float f = w00 * (float)v00[j] + w01 * (float)v01[j]
                + w10 * (float)v10[j] + w11 * (float)v11[j];
        r[j] = (__bf16)f;
      }
      *(bf16x8*)(dst + eo) = r;
    }
  }

  // ---- deformable conv: 9 taps ----
  f32x4 acc[4];
#pragma unroll
  for (int mf = 0; mf < 4; mf++) acc[mf] = (f32x4){0.f, 0.f, 0.f, 0.f};
  const bf16x8* aD = (const bf16x8*)dcnD;

#pragma unroll
  for (int k = 0; k < 9; k++) {
    float sy = (float)(h + k / 3 - 1) + offs[2 * k];
    float sx = (float)(wg + k % 3 - 1) + offs[2 * k + 1];
    const __bf16 *c00, *c01, *c10, *c11;
    float w00, w01, w10, w11;
    bilin_setup(xb, sy, sx, c00, c01, c10, c11, w00, w01, w10, w11);

    // gather (quad-coalesced), blend, LDS write (swizzled)
#pragma unroll
    for (int s = 0; s < 2; s++) {
      int eo = q * 8 + s * 32;
      bf16x8 v00 = *(const bf16x8*)(c00 + eo);
      bf16x8 v01 = *(const bf16x8*)(c01 + eo);
      bf16x8 v10 = *(const bf16x8*)(c10 + eo);
      bf16x8 v11 = *(const bf16x8*)(c11 + eo);
      bf16x8 r;
#pragma unroll
      for (int j = 0; j < 8; j++) {
        float f = w00 * (float)v00[j] + w01 * (float)v01[j]
                + w10 * (float)v10[j] + w11 * (float)v11[j];
        r[j] = (__bf16)f;
      }
      int c = s * 4 + q;
      *(bf16x8*)(sm + pg * 128 + ((c ^ (pg & 7)) * 16)) = r;
    }

    // fragment read (swizzled) + MFMA; same-wave lockstep, no barrier
#pragma unroll
    for (int s = 0; s < 2; s++) {
      int c = s * 4 + g;
      bf16x8 a = *(const bf16x8*)(sm + l15 * 128 + ((c ^ (l15 & 7)) * 16));
      acc[0] = __builtin_amdgcn_mfma_f32_16x16x32_bf16(
          a, aD[((k * 2 + s) * 4 + 0) * 64 + lane], acc[0], 0, 0, 0);
      acc[1] = __builtin_amdgcn_mfma_f32_16x16x32_bf16(
          a, aD[((k * 2 + s) * 4 + 1) * 64 + lane], acc[1], 0, 0, 0);
      acc[2] = __builtin_amdgcn_mfma_f32_16x16x32_bf16(
          a, aD[((k * 2 + s) * 4 + 2) * 64 + lane], acc[2], 0, 0, 0);
      acc[3] = __builtin_amdgcn_mfma_f32_16x16x32_bf16(
          a, aD[((k * 2 + s) * 4 + 3) * 64 + lane], acc[3], 0, 0, 0);
    }
  }

  // ---- epilogue: D row(pixel)=g*4+r, col(out)=mf*16+l15 ----
  __bf16* fb = FdT + ((size_t)b * HWn + h * 128 + px0) * 64;
#pragma unroll
  for (int mf = 0; mf < 4; mf++) {
    int o = mf * 16 + l15;
    float bias = dcn_b[o];
#pragma unroll
    for (int r = 0; r < 4; r++) {
      int pxl = g * 4 + r;
      fb[(size_t)pxl * 64 + o] = (__bf16)(acc[mf][r] + bias);
    }
  }
}

// ---------------------------------------------------------------------------
// K7: fusion -> fusedT bf16 OCTET-PLANAR [b][oct8][132][132][8ch], 2-pad ring.
// Planar layout makes elkm's B-fragment reads quad-coalesced (R11).
// ---------------------------------------------------------------------------
#define FPL ((size_t)132 * 132 * 8)
__global__ __launch_bounds__(256) void k_fuseT(
    const __bf16* __restrict__ FsT, const __bf16* __restrict__ FdT,
    const float* __restrict__ wg_w, const float* __restrict__ wg_b,
    __bf16* __restrict__ fusedT)
{
  int id = blockIdx.x * 256 + threadIdx.x;
  if (id >= 8 * 132 * 132) return;
  int wp = id % 132;
  int hp = (id / 132) % 132;
  int b  = id / (132 * 132);
  size_t ppix = (size_t)(hp * 132 + wp) * 8;
  int h = hp - 2, w = wp - 2;
  if (((unsigned)h >= 128u) || ((unsigned)w >= 128u)) {
    bf16x8 z = {};
#pragma unroll
    for (int oct = 0; oct < 8; oct++)
      *(bf16x8*)(fusedT + ((size_t)b * 8 + oct) * FPL + ppix) = z;
    return;
  }
  const bf16x8* fs = (const bf16x8*)(FsT + ((size_t)b * HWn + h * 128 + w) * 64);
  const bf16x8* fd = (const bf16x8*)(FdT + ((size_t)b * HWn + h * 128 + w) * 64);
  bf16x8 fsv[8], fdv[8];
  float s0 = wg_b[0], s1 = wg_b[1];
#pragma unroll
  for (int oct = 0; oct < 8; oct++) {
    fsv[oct] = fs[oct];
    fdv[oct] = fd[oct];
#pragma unroll
    for (int j = 0; j < 8; j++) {
      int c = oct * 8 + j;
      float a = (float)fsv[oct][j], d = (float)fdv[oct][j];
      s0 = fmaf(wg_w[c],       a, fmaf(wg_w[64 + c],  d, s0));
      s1 = fmaf(wg_w[128 + c], a, fmaf(wg_w[192 + c], d, s1));
    }
  }
  float p0 = 1.f / (1.f + __expf(s1 - s0));
  float p1 = 1.f - p0;
#pragma unroll
  for (int oct = 0; oct < 8; oct++) {
    bf16x8 r;
#pragma unroll
    for (int j = 0; j < 8; j++)
      r[j] = (__bf16)(p0 * (float)fsv[oct][j] + p1 * (float)fdv[oct][j]);
    *(bf16x8*)(fusedT + ((size_t)b * 8 + oct) * FPL + ppix) = r;
  }
}

// ---------------------------------------------------------------------------
// K8: collapsed ELK via MFMA, planar fusedT reads (quad-coalesced, R11).
// B-fragment lane l: plane = s*4+(l>>4), pixel = base + nf*16 + (l&15):
// quads read 4 consecutive 16B = one 64B line.
// ---------------------------------------------------------------------------
__global__ __launch_bounds__(256) void k_elkm(
    const __bf16* __restrict__ fusedT, const __bf16* __restrict__ weffD,
    const float* __restrict__ beff, float* __restrict__ out)
{
  const int DY[13] = {-2,-1,-1,-1, 0, 0, 0, 0, 0, 1, 1, 1, 2};
  const int DX[13] = { 0,-1, 0, 1,-2,-1, 0, 1, 2,-1, 0, 1, 0};
  const int lane = threadIdx.x & 63;
  const int wv   = threadIdx.x >> 6;
  const int swz  = xcd_swz(blockIdx.x, 64);
  const int b    = swz >> 6;
  const int h    = (swz & 63) * 2 + (wv >> 1);
  const int half = wv & 1;
  const int l15  = lane & 15;
  const int g    = lane >> 4;

  f32x4 acc[4][4];
#pragma unroll
  for (int mf = 0; mf < 4; mf++)
#pragma unroll
    for (int nf = 0; nf < 4; nf++) acc[mf][nf] = (f32x4){0.f, 0.f, 0.f, 0.f};

  const bf16x8* aD = (const bf16x8*)weffD;
  const __bf16* pl0 = fusedT + ((size_t)b * 8 + g) * FPL;      // s=0 plane
  const __bf16* pl1 = pl0 + 4 * FPL;                            // s=1 plane

  for (int t = 0; t < 13; t++) {
    int hp = h + 2 + DY[t];
    size_t rowb = (size_t)(hp * 132 + half * 64 + 2 + DX[t] + l15) * 8;
#pragma unroll
    for (int s = 0; s < 2; s++) {
      const __bf16* pl = s ? pl1 : pl0;
      bf16x8 a0 = aD[((t * 2 + s) * 4 + 0) * 64 + lane];
      bf16x8 a1 = aD[((t * 2 + s) * 4 + 1) * 64 + lane];
      bf16x8 a2 = aD[((t * 2 + s) * 4 + 2) * 64 + lane];
      bf16x8 a3 = aD[((t * 2 + s) * 4 + 3) * 64 + lane];
#pragma unroll
      for (int nf = 0; nf < 4; nf++) {
        bf16x8 bv = *(const bf16x8*)(pl + rowb + (size_t)nf * 128);
        acc[0][nf] = __builtin_amdgcn_mfma_f32_16x16x32_bf16(a0, bv, acc[0][nf], 0, 0, 0);
        acc[1][nf] = __builtin_amdgcn_mfma_f32_16x16x32_bf16(a1, bv, acc[1][nf], 0, 0, 0);
        acc[2][nf] = __builtin_amdgcn_mfma_f32_16x16x32_bf16(a2, bv, acc[2][nf], 0, 0, 0);
        acc[3][nf] = __builtin_amdgcn_mfma_f32_16x16x32_bf16(a3, bv, acc[3][nf], 0, 0, 0);
      }
    }
  }

#pragma unroll
  for (int mf = 0; mf < 4; mf++) {
    int ob = mf * 16 + (g << 2);
#pragma unroll
    for (int r = 0; r < 4; r++) {
      int o = ob + r;
      float bb = beff[o];
      float* orow = out + ((size_t)(b * 64 + o)) * HWn + h * 128 + half * 64 + l15;
#pragma unroll
      for (int nf = 0; nf < 4; nf++)
        orow[nf * 16] = acc[mf][nf][r] + bb;
    }
  }
}

// ---------------------------------------------------------------------------
// Workspace layout unchanged from R5/R6 (sizes verified in floats):
// Region A [0, 4,596,736): xT -> fusedT (planar, same elem count; after dcnm).
// Region B [4,596,736, 9,536,512): xC -> FsT (after conv1m).
// Region C [9,536,512, 14,322,688): t1T/p1T/t2 -> FdT (after k_feat).
// Tail: feat/theta/wfrag/w2frag/beff/dcnD/weffD @14,322,688.. end 14,444,160.
// ---------------------------------------------------------------------------
extern "C" void kernel_launch(void* const* d_in, const int* in_sizes, int n_in,
                              void* d_out, int out_size, void* d_ws, size_t ws_size,
                              hipStream_t stream)
{
  (void)in_sizes; (void)n_in; (void)out_size; (void)ws_size;
  const float* x      = (const float*)d_in[0];
  const float* offset = (const float*)d_in[1];
  const float* stn_w1 = (const float*)d_in[2];
  const float* stn_b1 = (const float*)d_in[3];
  const float* stn_w2 = (const float*)d_in[4];
  const float* stn_b2 = (const float*)d_in[5];
  const float* fc_w   = (const float*)d_in[6];
  const float* fc_b   = (const float*)d_in[7];
  const float* dcn_w  = (const float*)d_in[8];
  const float* dcn_b  = (const float*)d_in[9];
  const float* wg_w   = (const float*)d_in[10];
  const float* wg_b   = (const float*)d_in[11];
  const float* w3     = (const float*)d_in[12];
  const float* b3     = (const float*)d_in[13];
  const float* w15    = (const float*)d_in[14];
  const float* b15    = (const float*)d_in[15];
  const float* w51    = (const float*)d_in[16];
  const float* b51    = (const float*)d_in[17];
  const float* w1     = (const float*)d_in[18];
  const float* b1     = (const float*)d_in[19];

  float* ws      = (float*)d_ws;
  __bf16* xT     = (__bf16*)ws;
  __bf16* fusedT = (__bf16*)ws;
  __bf16* xC     = (__bf16*)(ws + 4596736);
  __bf16* FsT    = (__bf16*)(ws + 4596736);
  __bf16* t1T    = (__bf16*)(ws + 9536512);
  __bf16* FdT    = (__bf16*)(ws + 9536512);
  __bf16* p1T    = (__bf16*)(ws + 11633664);
  float*  t2     = ws + 12225536;
  float*  feat   = ws + 14322688;
  float*  theta  = ws + 14323200;
  __bf16* wfrag  = (__bf16*)(ws + 14323264);
  __bf16* w2frag = (__bf16*)(ws + 14373440);
  float*  beff   = ws + 14399040;
  __bf16* dcnD   = (__bf16*)(ws + 14399104);
  __bf16* weffD  = (__bf16*)(ws + 14417536);
  float*  out    = (float*)d_out;

  k_prep  <<<1,    64,  0, stream>>>(w1, b3, b15, b51, b1, beff);
  k_xt    <<<562,  256, 0, stream>>>(x, xT, xC);
  k_wf    <<<392,  256, 0, stream>>>(stn_w1, wfrag);
  k_frag  <<<552,  256, 0, stream>>>(dcn_w, w1, w3, w15, w51, stn_w2, dcnD, weffD, w2frag);
  k_conv1m<<<512,  128, 0, stream>>>(xC, wfrag, stn_b1, t1T);
  k_pool  <<<145,  256, 0, stream>>>(t1T, p1T);
  k_conv2m<<<128,  256, 0, stream>>>(p1T, w2frag, stn_b2, t2);
  k_feat  <<<512,  256, 0, stream>>>(t2, feat);
  k_theta <<<1,    64,  0, stream>>>(feat, fc_w, fc_b, theta);
  k_dcnm  <<<2048, 256, 0, stream>>>(xT, offset, theta, dcnD, dcn_b, FdT, FsT);
  k_fuseT <<<545,  256, 0, stream>>>(FsT, FdT, wg_w, wg_b, fusedT);
  k_elkm  <<<512,  256, 0, stream>>>(fusedT, weffD, beff, out);
}

// Round 12
// 210.405 us; speedup vs baseline: 1.3777x; 1.0428x over previous
//
#include <hip/hip_runtime.h>
#include <math.h>

// Problem dims
#define Bn 8
#define Cn 64
#define Hn 128
#define Wn 128
#define HWn 16384

typedef __attribute__((ext_vector_type(8))) __bf16 bf16x8;
typedef __attribute__((ext_vector_type(4))) __bf16 bf16x4;
typedef __attribute__((ext_vector_type(4))) float f32x4;

// XCD-aware bijective swizzle: grid = 8*chunk blocks; XCD k (bid%8) gets the
// contiguous work range [k*chunk,(k+1)*chunk) => per-XCD L2-resident slice.
__device__ __forceinline__ int xcd_swz(int bid, int chunk) {
  return (bid & 7) * chunk + (bid >> 3);
}

// ---------------------------------------------------------------------------
// K0: beff (collapsed ELK bias) only.
// ---------------------------------------------------------------------------
__global__ void k_prep(const float* __restrict__ w1, const float* __restrict__ b3,
                       const float* __restrict__ b15, const float* __restrict__ b51,
                       const float* __restrict__ b1, float* __restrict__ beff)
{
  int e = threadIdx.x;
  if (e >= 64) return;
  float s = b1[e];
  for (int m = 0; m < 64; m++) {
    s = fmaf(w1[e * 192 + m],       b3[m],  s);
    s = fmaf(w1[e * 192 + 64 + m],  b15[m], s);
    s = fmaf(w1[e * 192 + 128 + m], b51[m], s);
  }
  beff[e] = s;
}

// ---------------------------------------------------------------------------
// K-xt v2 (R12): thread per (pixel, channel-half). 32 strided loads fully
// unrolled into regs BEFORE conversion (R11 was 2.2 waves/SIMD with 8-load
// batches -> VALUBusy 1.9%, latency-starved). 2x threads + 4x MLP.
// ---------------------------------------------------------------------------
__global__ __launch_bounds__(256) void k_xt(const float* __restrict__ x,
                                            __bf16* __restrict__ xT,
                                            __bf16* __restrict__ xC)
{
  int t = blockIdx.x * 256 + threadIdx.x;
  if (t >= 8 * 134 * 134 * 2) return;
  int half = t & 1;
  int p  = t >> 1;
  int wp = p % 134;
  int hp = (p / 134) % 134;
  int b  = p / (134 * 134);
  int h = hp - 3, w = wp - 3;
  bool inb = ((unsigned)h < 128u) && ((unsigned)w < 128u);
  const float* xb = x + (size_t)b * Cn * HWn + (size_t)(half * 32) * HWn + h * 128 + w;

  float v[32];
#pragma unroll
  for (int j = 0; j < 32; j++) v[j] = inb ? xb[(size_t)j * HWn] : 0.f;

  __bf16* dstT = xT + (size_t)p * 64 + half * 32;
#pragma unroll
  for (int g = 0; g < 4; g++) {
    bf16x8 r;
#pragma unroll
    for (int j = 0; j < 8; j++) r[j] = (__bf16)v[g * 8 + j];
    *(bf16x8*)(dstT + g * 8) = r;
    int oct = half * 4 + g;
    *(bf16x8*)(xC + ((((size_t)b * 8 + oct) * 134 + hp) * 144 + wp) * 8) = r;
  }
}

// ---------------------------------------------------------------------------
// K-wf: stn_w1 -> A-fragment layout for conv1 MFMA.
// ---------------------------------------------------------------------------
__global__ __launch_bounds__(256) void k_wf(const float* __restrict__ stn_w1,
                                            __bf16* __restrict__ wfrag)
{
  int t = blockIdx.x * 256 + threadIdx.x;
  if (t >= 100352) return;
  int e   = t & 7;
  int l   = (t >> 3) & 63;
  int o16 = (t >> 9) & 1;
  int ck  = (t >> 10) & 1;
  int tap = t >> 11;
  int o = o16 * 16 + (l & 15);
  int c = ck * 32 + (l >> 4) * 8 + e;
  wfrag[t] = (__bf16)stn_w1[(o * 64 + c) * 49 + tap];
}

// ---------------------------------------------------------------------------
// K-frag: A-fragments for DCN (9 taps), collapsed ELK (13 taps), conv2 (25 taps).
// ---------------------------------------------------------------------------
__global__ __launch_bounds__(256) void k_frag(
    const float* __restrict__ dcn_w, const float* __restrict__ w1,
    const float* __restrict__ w3, const float* __restrict__ w15,
    const float* __restrict__ w51, const float* __restrict__ stn_w2,
    __bf16* __restrict__ dcnD, __bf16* __restrict__ weffD,
    __bf16* __restrict__ w2frag)
{
  int t = blockIdx.x * 256 + threadIdx.x;
  if (t < 36864) {
    int e = t & 7, l = (t >> 3) & 63, mf = (t >> 9) & 3, s = (t >> 11) & 1;
    int tap = t >> 12;
    int o = mf * 16 + (l & 15), c = s * 32 + (l >> 4) * 8 + e;
    dcnD[t] = (__bf16)dcn_w[(o * 64 + c) * 9 + tap];
    return;
  }
  t -= 36864;
  if (t < 53248) {
    const int DY[13] = {-2,-1,-1,-1, 0, 0, 0, 0, 0, 1, 1, 1, 2};
    const int DX[13] = { 0,-1, 0, 1,-2,-1, 0, 1, 2,-1, 0, 1, 0};
    int e = t & 7, l = (t >> 3) & 63, mf = (t >> 9) & 3, s = (t >> 11) & 1;
    int tap = t >> 12;
    int o = mf * 16 + (l & 15), c = s * 32 + (l >> 4) * 8 + e;
    int dy = DY[tap], dx = DX[tap];
    float v = 0.f;
    if (dy >= -1 && dy <= 1 && dx >= -1 && dx <= 1) {
      int k3 = (dy + 1) * 3 + (dx + 1);
      for (int m = 0; m < 64; m++) v = fmaf(w1[o * 192 + m], w3[(m * 64 + c) * 9 + k3], v);
    }
    if (dy == 0) {
      int k15 = dx + 2;
      for (int m = 0; m < 64; m++) v = fmaf(w1[o * 192 + 64 + m], w15[(m * 64 + c) * 5 + k15], v);
    }
    if (dx == 0) {
      int k51 = dy + 2;
      for (int m = 0; m < 64; m++) v = fmaf(w1[o * 192 + 128 + m], w51[(m * 64 + c) * 5 + k51], v);
    }
    weffD[t] = (__bf16)v;
    return;
  }
  t -= 53248;
  if (t < 51200) {   // conv2 A-frags: [tap25][mf4][lane64][e8]
    int e = t & 7, l = (t >> 3) & 63, mf = (t >> 9) & 3;
    int tap = t >> 11;
    int o = mf * 16 + (l & 15), c = (l >> 4) * 8 + e;
    w2frag[t] = (__bf16)stn_w2[(o * 32 + c) * 25 + tap];
  }
}

// ---------------------------------------------------------------------------
// K1: STN conv1 via MFMA, contiguous 1KB global_load_lds staging from xC.
// ---------------------------------------------------------------------------
__global__ __launch_bounds__(128) void k_conv1m(
    const __bf16* __restrict__ xC, const __bf16* __restrict__ wfrag,
    const float* __restrict__ b1s, __bf16* __restrict__ t1T)
{
  __shared__ alignas(16) char tile[73728];   // [q4][r8][slot144][16B]
  const int lane = threadIdx.x & 63;
  const int wv   = threadIdx.x >> 6;
  const int swz  = xcd_swz(blockIdx.x, 64);
  const int b    = swz >> 6;
  const int h0   = (swz & 63) * 2;

  f32x4 acc[2][8];
#pragma unroll
  for (int o16 = 0; o16 < 2; o16++)
#pragma unroll
    for (int nf = 0; nf < 8; nf++) acc[o16][nf] = (f32x4){0.f, 0.f, 0.f, 0.f};

  const bf16x8* wf = (const bf16x8*)wfrag;
  const char* tb = (const char*)tile;
  const char* xCb = (const char*)xC;

  for (int ck = 0; ck < 2; ck++) {
    for (int i = wv; i < 72; i += 2) {
      int q = i / 18;
      int t = i - q * 18;
      const char* src = xCb
          + (((size_t)(b * 8 + ck * 4 + q) * 134 + h0) * 2304) + t * 1024 + lane * 16;
      char* dst = (char*)tile + i * 1024;
      __builtin_amdgcn_global_load_lds(
          (const __attribute__((address_space(1))) void*)src,
          (__attribute__((address_space(3))) void*)dst, 16, 0, 0);
    }
    __syncthreads();

    for (int tap = 0; tap < 49; tap++) {
      int dy7 = tap / 7;
      int dx7 = tap - dy7 * 7;
      bf16x8 a0 = wf[((tap * 2 + ck) * 2 + 0) * 64 + lane];
      bf16x8 a1 = wf[((tap * 2 + ck) * 2 + 1) * 64 + lane];
      const char* bp = tb + (lane >> 4) * 18432 + (wv + dy7) * 2304
                          + (dx7 + (lane & 15)) * 16;
#pragma unroll
      for (int nf = 0; nf < 8; nf++) {
        bf16x8 bv = *(const bf16x8*)(bp + nf * 256);
        acc[0][nf] = __builtin_amdgcn_mfma_f32_16x16x32_bf16(a0, bv, acc[0][nf], 0, 0, 0);
        acc[1][nf] = __builtin_amdgcn_mfma_f32_16x16x32_bf16(a1, bv, acc[1][nf], 0, 0, 0);
      }
    }
    __syncthreads();
  }

  int h = h0 + wv;
#pragma unroll
  for (int o16 = 0; o16 < 2; o16++) {
    int ob = o16 * 16 + ((lane >> 4) << 2);
    float bb0 = b1s[ob], bb1 = b1s[ob + 1], bb2 = b1s[ob + 2], bb3 = b1s[ob + 3];
#pragma unroll
    for (int nf = 0; nf < 8; nf++) {
      int px = nf * 16 + (lane & 15);
      bf16x4 r;
      r[0] = (__bf16)fmaxf(acc[o16][nf][0] + bb0, 0.f);
      r[1] = (__bf16)fmaxf(acc[o16][nf][1] + bb1, 0.f);
      r[2] = (__bf16)fmaxf(acc[o16][nf][2] + bb2, 0.f);
      r[3] = (__bf16)fmaxf(acc[o16][nf][3] + bb3, 0.f);
      *(bf16x4*)(t1T + (((size_t)(b * 128 + h) * 128 + px)) * 32 + ob) = r;
    }
  }
}

// ---------------------------------------------------------------------------
// K2: maxpool 2x2 -> p1T[b][hp68][wp68][32ch] bf16, zero-padded 2 ring.
// ---------------------------------------------------------------------------
__global__ __launch_bounds__(256) void k_pool(const __bf16* __restrict__ t1T,
                                              __bf16* __restrict__ p1T)
{
  int id = blockIdx.x * 256 + threadIdx.x;
  if (id >= 8 * 68 * 68) return;
  int wp = id % 68, hp = (id / 68) % 68, b = id / (68 * 68);
  __bf16* dst = p1T + (size_t)id * 32;
  int ph = hp - 2, pw = wp - 2;
  if (((unsigned)ph >= 64u) || ((unsigned)pw >= 64u)) {
    bf16x8 z = {};
#pragma unroll
    for (int g = 0; g < 4; g++) *(bf16x8*)(dst + g * 8) = z;
    return;
  }
  const __bf16* s = t1T + (((size_t)(b * 128) + ph * 2) * 128 + pw * 2) * 32;
#pragma unroll
  for (int g = 0; g < 4; g++) {
    bf16x8 v0 = *(const bf16x8*)(s + g * 8);
    bf16x8 v1 = *(const bf16x8*)(s + 32 + g * 8);
    bf16x8 v2 = *(const bf16x8*)(s + 4096 + g * 8);
    bf16x8 v3 = *(const bf16x8*)(s + 4128 + g * 8);
    bf16x8 r;
#pragma unroll
    for (int j = 0; j < 8; j++) {
      float m = fmaxf(fmaxf((float)v0[j], (float)v1[j]),
                      fmaxf((float)v2[j], (float)v3[j]));
      r[j] = (__bf16)m;
    }
    *(bf16x8*)(dst + g * 8) = r;
  }
}

// ---------------------------------------------------------------------------
// K3: conv2 via MFMA.
// ---------------------------------------------------------------------------
__global__ __launch_bounds__(256) void k_conv2m(
    const __bf16* __restrict__ p1T, const __bf16* __restrict__ w2frag,
    const float* __restrict__ b2s, float* __restrict__ t2)
{
  __shared__ alignas(16) char tile[34816];   // 8*68*64
  const int lane = threadIdx.x & 63;
  const int wv   = threadIdx.x >> 6;
  const int b    = blockIdx.x >> 4;
  const int h0   = (blockIdx.x & 15) * 4;

  f32x4 acc[4][4];
#pragma unroll
  for (int mf = 0; mf < 4; mf++)
#pragma unroll
    for (int nf = 0; nf < 4; nf++) acc[mf][nf] = (f32x4){0.f, 0.f, 0.f, 0.f};

  const char* src0 = (const char*)p1T + (((size_t)b * 68 + h0) * 68) * 64;
  for (int i = wv; i < 34; i += 4) {
    __builtin_amdgcn_global_load_lds(
        (const __attribute__((address_space(1))) void*)(src0 + i * 1024 + lane * 16),
        (__attribute__((address_space(3))) void*)((char*)tile + i * 1024), 16, 0, 0);
  }
  __syncthreads();

  const bf16x8* wf = (const bf16x8*)w2frag;
  const char* tb = (const char*)tile;
  for (int tap = 0; tap < 25; tap++) {
    int ky = tap / 5, kx = tap - ky * 5;
    bf16x8 a0 = wf[(tap * 4 + 0) * 64 + lane];
    bf16x8 a1 = wf[(tap * 4 + 1) * 64 + lane];
    bf16x8 a2 = wf[(tap * 4 + 2) * 64 + lane];
    bf16x8 a3 = wf[(tap * 4 + 3) * 64 + lane];
    const char* bp = tb + (((wv + ky) * 68 + kx + (lane & 15)) * 64) + (lane >> 4) * 16;
#pragma unroll
    for (int nf = 0; nf < 4; nf++) {
      bf16x8 bv = *(const bf16x8*)(bp + nf * 1024);
      acc[0][nf] = __builtin_amdgcn_mfma_f32_16x16x32_bf16(a0, bv, acc[0][nf], 0, 0, 0);
      acc[1][nf] = __builtin_amdgcn_mfma_f32_16x16x32_bf16(a1, bv, acc[1][nf], 0, 0, 0);
      acc[2][nf] = __builtin_amdgcn_mfma_f32_16x16x32_bf16(a2, bv, acc[2][nf], 0, 0, 0);
      acc[3][nf] = __builtin_amdgcn_mfma_f32_16x16x32_bf16(a3, bv, acc[3][nf], 0, 0, 0);
    }
  }

  int h = h0 + wv;
#pragma unroll
  for (int mf = 0; mf < 4; mf++) {
    int ob = mf * 16 + ((lane >> 4) << 2);
#pragma unroll
    for (int r = 0; r < 4; r++) {
      float bb = b2s[ob + r];
      float* orow = t2 + ((size_t)(b * 64 + ob + r)) * 4096 + h * 64 + (lane & 15);
#pragma unroll
      for (int nf = 0; nf < 4; nf++)
        orow[nf * 16] = fmaxf(acc[mf][nf][r] + bb, 0.f);
    }
  }
}

// ---------------------------------------------------------------------------
// K3b: deterministic spatial sum -> feat[b*64+co].
// ---------------------------------------------------------------------------
__global__ __launch_bounds__(256) void k_feat(const float* __restrict__ t2, float* __restrict__ feat)
{
  __shared__ float red[256];
  int bc = blockIdx.x;
  const float* s = t2 + (size_t)bc * 4096;
  float v = 0.f;
  for (int i = threadIdx.x; i < 4096; i += 256) v += s[i];
  red[threadIdx.x] = v;
  __syncthreads();
  for (int st = 128; st > 0; st >>= 1) {
    if (threadIdx.x < st) red[threadIdx.x] += red[threadIdx.x + st];
    __syncthreads();
  }
  if (threadIdx.x == 0) feat[bc] = red[0];
}

// ---------------------------------------------------------------------------
// K4: theta
// ---------------------------------------------------------------------------
__global__ void k_theta(const float* __restrict__ feat, const float* __restrict__ fc_w,
                        const float* __restrict__ fc_b, float* __restrict__ theta)
{
  int tid = threadIdx.x;
  if (tid >= 48) return;
  int b = tid / 6, i = tid - b * 6;
  float s = 0.f;
  for (int k = 0; k < 64; k++) s = fmaf(feat[b * 64 + k], fc_w[i * 64 + k], s);
  theta[tid] = fmaf(s, 1.f / 4096.f, fc_b[i]);
}

// ---------------------------------------------------------------------------
// Shared bilinear corner-address helper (clamped + masked weights).
// ---------------------------------------------------------------------------
__device__ __forceinline__ void bilin_setup(
    const __bf16* __restrict__ xb, float sy, float sx,
    const __bf16*& c00, const __bf16*& c01,
    const __bf16*& c10, const __bf16*& c11,
    float& w00, float& w01, float& w10, float& w11)
{
  float y0f = floorf(sy), x0f = floorf(sx);
  float wy1 = sy - y0f, wy0 = 1.f - wy1;
  float wx1 = sx - x0f, wx0 = 1.f - wx1;
  bool vy0 = (y0f >= 0.f) && (y0f <= 127.f);
  bool vy1 = (y0f >= -1.f) && (y0f <= 126.f);
  bool vx0 = (x0f >= 0.f) && (x0f <= 127.f);
  bool vx1 = (x0f >= -1.f) && (x0f <= 126.f);
  int yi0 = (int)fminf(fmaxf(y0f, 0.f), 127.f);
  int yi1 = (int)fminf(fmaxf(y0f + 1.f, 0.f), 127.f);
  int xi0 = (int)fminf(fmaxf(x0f, 0.f), 127.f);
  int xi1 = (int)fminf(fmaxf(x0f + 1.f, 0.f), 127.f);
  w00 = wy0 * wx0 * ((vy0 && vx0) ? 1.f : 0.f);
  w01 = wy0 * wx1 * ((vy0 && vx1) ? 1.f : 0.f);
  w10 = wy1 * wx0 * ((vy1 && vx0) ? 1.f : 0.f);
  w11 = wy1 * wx1 * ((vy1 && vx1) ? 1.f : 0.f);
  c00 = xb + ((size_t)((yi0 + 3) * 134) + xi0 + 3) * 64;
  c01 = xb + ((size_t)((yi0 + 3) * 134) + xi1 + 3) * 64;
  c10 = xb + ((size_t)((yi1 + 3) * 134) + xi0 + 3) * 64;
  c11 = xb + ((size_t)((yi1 + 3) * 134) + xi1 + 3) * 64;
}

// ---------------------------------------------------------------------------
// K6: deformable conv + fused STN sample — R12: quad-coalesced gathers
// (R11, confirmed) + DOUBLE-BUFFERED per-wave LDS staging (tap parity) so
// tap k+1's gathers/blend/LDS-write have no WAR hazard against tap k's
// LDS read -> scheduler can overlap the gather latency with MFMA tail.
// ---------------------------------------------------------------------------
__global__ __launch_bounds__(256) void k_dcnm(
    const __bf16* __restrict__ xT, const float* __restrict__ off,
    const float* __restrict__ theta,
    const __bf16* __restrict__ dcnD, const float* __restrict__ dcn_b,
    __bf16* __restrict__ FdT, __bf16* __restrict__ FsT)
{
  __shared__ alignas(16) char smem[4][2][2048];
  const int lane = threadIdx.x & 63;
  const int wv   = threadIdx.x >> 6;
  const int swz  = xcd_swz(blockIdx.x, 256);
  const int b    = swz >> 8;
  const int rem  = swz & 255;
  const int h    = rem >> 1;
  const int px0  = (rem & 1) * 64 + wv * 16;
  const int l15  = lane & 15;
  const int g    = lane >> 4;
  const int pg   = lane >> 2;          // gather pixel 0..15
  const int q    = lane & 3;           // 16B chunk within 64B half
  const int wg   = px0 + pg;           // gather lane's pixel column

  const __bf16* xb = xT + (size_t)b * 134 * 134 * 64;

  // offsets for the gather pixel (quad-uniform -> broadcast)
  const float* ob = off + (size_t)b * 18 * HWn + h * 128 + wg;
  float offs[18];
#pragma unroll
  for (int i = 0; i < 18; i++) offs[i] = ob[(size_t)i * HWn];

  // ---- fused STN sample: blend + coalesced store to FsT ----
  {
    const float* t = theta + b * 6;
    float xn = (float)(2 * wg + 1) * (1.f / 128.f) - 1.f;
    float yn = (float)(2 * h + 1) * (1.f / 128.f) - 1.f;
    float gxv = t[0] * xn + t[1] * yn + t[2];
    float gyv = t[3] * xn + t[4] * yn + t[5];
    float ix = fmaf(gxv, 64.f, 63.5f);
    float iy = fmaf(gyv, 64.f, 63.5f);
    const __bf16 *c00, *c01, *c10, *c11;
    float w00, w01, w10, w11;
    bilin_setup(xb, iy, ix, c00, c01, c10, c11, w00, w01, w10, w11);
    __bf16* dst = FsT + ((size_t)b * HWn + h * 128 + wg) * 64;
#pragma unroll
    for (int s = 0; s < 2; s++) {
      int eo = q * 8 + s * 32;
      bf16x8 v00 = *(const bf16x8*)(c00 + eo);
      bf16x8 v01 = *(const bf16x8*)(c01 + eo);
      bf16x8 v10 = *(const bf16x8*)(c10 + eo);
      bf16x8 v11 = *(const bf16x8*)(c11 + eo);
      bf16x8 r;
#pragma unroll
      for (int j = 0; j < 8; j++) {
        float f = w00 * (float)v00[j] + w01 * (float)v01[j]
                + w10 * (float)v10[j] + w11 * (float)v11[j];
        r[j] = (__bf16)f;
      }
      *(bf16x8*)(dst + eo) = r;
    }
  }

  // ---- deformable conv: 9 taps, double-buffered LDS ----
  f32x4 acc[4];
#pragma unroll
  for (int mf = 0; mf < 4; mf++) acc[mf] = (f32x4){0.f, 0.f, 0.f, 0.f};
  const bf16x8* aD = (const bf16x8*)dcnD;

#pragma unroll
  for (int k = 0; k < 9; k++) {
    char* sm = smem[wv][k & 1];
    float sy = (float)(h + k / 3 - 1) + offs[2 * k];
    float sx = (float)(wg + k % 3 - 1) + offs[2 * k + 1];
    const __bf16 *c00, *c01, *c10, *c11;
    float w00, w01, w10, w11;
    bilin_setup(xb, sy, sx, c00, c01, c10, c11, w00, w01, w10, w11);

    // gather (quad-coalesced), blend, LDS write (swizzled)
#pragma unroll
    for (int s = 0; s < 2; s++) {
      int eo = q * 8 + s * 32;
      bf16x8 v00 = *(const bf16x8*)(c00 + eo);
      bf16x8 v01 = *(const bf16x8*)(c01 + eo);
      bf16x8 v10 = *(const bf16x8*)(c10 + eo);
      bf16x8 v11 = *(const bf16x8*)(c11 + eo);
      bf16x8 r;
#pragma unroll
      for (int j = 0; j < 8; j++) {
        float f = w00 * (float)v00[j] + w01 * (float)v01[j]
                + w10 * (float)v10[j] + w11 * (float)v11[j];
        r[j] = (__bf16)f;
      }
      int c = s * 4 + q;
      *(bf16x8*)(sm + pg * 128 + ((c ^ (pg & 7)) * 16)) = r;
    }

    // fragment read (swizzled) + MFMA; same-wave lockstep, no barrier
#pragma unroll
    for (int s = 0; s < 2; s++) {
      int c = s * 4 + g;
      bf16x8 a = *(const bf16x8*)(sm + l15 * 128 + ((c ^ (l15 & 7)) * 16));
      acc[0] = __builtin_amdgcn_mfma_f32_16x16x32_bf16(
          a, aD[((k * 2 + s) * 4 + 0) * 64 + lane], acc[0], 0, 0, 0);
      acc[1] = __builtin_amdgcn_mfma_f32_16x16x32_bf16(
          a, aD[((k * 2 + s) * 4 + 1) * 64 + lane], acc[1], 0, 0, 0);
      acc[2] = __builtin_amdgcn_mfma_f32_16x16x32_bf16(
          a, aD[((k * 2 + s) * 4 + 2) * 64 + lane], acc[2], 0, 0, 0);
      acc[3] = __builtin_amdgcn_mfma_f32_16x16x32_bf16(
          a, aD[((k * 2 + s) * 4 + 3) * 64 + lane], acc[3], 0, 0, 0);
    }
  }

  // ---- epilogue: D row(pixel)=g*4+r, col(out)=mf*16+l15 ----
  __bf16* fb = FdT + ((size_t)b * HWn + h * 128 + px0) * 64;
#pragma unroll
  for (int mf = 0; mf < 4; mf++) {
    int o = mf * 16 + l15;
    float bias = dcn_b[o];
#pragma unroll
    for (int r = 0; r < 4; r++) {
      int pxl = g * 4 + r;
      fb[(size_t)pxl * 64 + o] = (__bf16)(acc[mf][r] + bias);
    }
  }
}

// ---------------------------------------------------------------------------
// K7: fusion -> fusedT bf16 OCTET-PLANAR [b][oct8][132][132][8ch], 2-pad ring.
// ---------------------------------------------------------------------------
#define FPL ((size_t)132 * 132 * 8)
__global__ __launch_bounds__(256) void k_fuseT(
    const __bf16* __restrict__ FsT, const __bf16* __restrict__ FdT,
    const float* __restrict__ wg_w, const float* __restrict__ wg_b,
    __bf16* __restrict__ fusedT)
{
  int id = blockIdx.x * 256 + threadIdx.x;
  if (id >= 8 * 132 * 132) return;
  int wp = id % 132;
  int hp = (id / 132) % 132;
  int b  = id / (132 * 132);
  size_t ppix = (size_t)(hp * 132 + wp) * 8;
  int h = hp - 2, w = wp - 2;
  if (((unsigned)h >= 128u) || ((unsigned)w >= 128u)) {
    bf16x8 z = {};
#pragma unroll
    for (int oct = 0; oct < 8; oct++)
      *(bf16x8*)(fusedT + ((size_t)b * 8 + oct) * FPL + ppix) = z;
    return;
  }
  const bf16x8* fs = (const bf16x8*)(FsT + ((size_t)b * HWn + h * 128 + w) * 64);
  const bf16x8* fd = (const bf16x8*)(FdT + ((size_t)b * HWn + h * 128 + w) * 64);
  bf16x8 fsv[8], fdv[8];
  float s0 = wg_b[0], s1 = wg_b[1];
#pragma unroll
  for (int oct = 0; oct < 8; oct++) {
    fsv[oct] = fs[oct];
    fdv[oct] = fd[oct];
#pragma unroll
    for (int j = 0; j < 8; j++) {
      int c = oct * 8 + j;
      float a = (float)fsv[oct][j], d = (float)fdv[oct][j];
      s0 = fmaf(wg_w[c],       a, fmaf(wg_w[64 + c],  d, s0));
      s1 = fmaf(wg_w[128 + c], a, fmaf(wg_w[192 + c], d, s1));
    }
  }
  float p0 = 1.f / (1.f + __expf(s1 - s0));
  float p1 = 1.f - p0;
#pragma unroll
  for (int oct = 0; oct < 8; oct++) {
    bf16x8 r;
#pragma unroll
    for (int j = 0; j < 8; j++)
      r[j] = (__bf16)(p0 * (float)fsv[oct][j] + p1 * (float)fdv[oct][j]);
    *(bf16x8*)(fusedT + ((size_t)b * 8 + oct) * FPL + ppix) = r;
  }
}

// ---------------------------------------------------------------------------
// K8: collapsed ELK via MFMA, planar fusedT reads (quad-coalesced).
// ---------------------------------------------------------------------------
__global__ __launch_bounds__(256) void k_elkm(
    const __bf16* __restrict__ fusedT, const __bf16* __restrict__ weffD,
    const float* __restrict__ beff, float* __restrict__ out)
{
  const int DY[13] = {-2,-1,-1,-1, 0, 0, 0, 0, 0, 1, 1, 1, 2};
  const int DX[13] = { 0,-1, 0, 1,-2,-1, 0, 1, 2,-1, 0, 1, 0};
  const int lane = threadIdx.x & 63;
  const int wv   = threadIdx.x >> 6;
  const int swz  = xcd_swz(blockIdx.x, 64);
  const int b    = swz >> 6;
  const int h    = (swz & 63) * 2 + (wv >> 1);
  const int half = wv & 1;
  const int l15  = lane & 15;
  const int g    = lane >> 4;

  f32x4 acc[4][4];
#pragma unroll
  for (int mf = 0; mf < 4; mf++)
#pragma unroll
    for (int nf = 0; nf < 4; nf++) acc[mf][nf] = (f32x4){0.f, 0.f, 0.f, 0.f};

  const bf16x8* aD = (const bf16x8*)weffD;
  const __bf16* pl0 = fusedT + ((size_t)b * 8 + g) * FPL;      // s=0 plane
  const __bf16* pl1 = pl0 + 4 * FPL;                            // s=1 plane

  for (int t = 0; t < 13; t++) {
    int hp = h + 2 + DY[t];
    size_t rowb = (size_t)(hp * 132 + half * 64 + 2 + DX[t] + l15) * 8;
#pragma unroll
    for (int s = 0; s < 2; s++) {
      const __bf16* pl = s ? pl1 : pl0;
      bf16x8 a0 = aD[((t * 2 + s) * 4 + 0) * 64 + lane];
      bf16x8 a1 = aD[((t * 2 + s) * 4 + 1) * 64 + lane];
      bf16x8 a2 = aD[((t * 2 + s) * 4 + 2) * 64 + lane];
      bf16x8 a3 = aD[((t * 2 + s) * 4 + 3) * 64 + lane];
#pragma unroll
      for (int nf = 0; nf < 4; nf++) {
        bf16x8 bv = *(const bf16x8*)(pl + rowb + (size_t)nf * 128);
        acc[0][nf] = __builtin_amdgcn_mfma_f32_16x16x32_bf16(a0, bv, acc[0][nf], 0, 0, 0);
        acc[1][nf] = __builtin_amdgcn_mfma_f32_16x16x32_bf16(a1, bv, acc[1][nf], 0, 0, 0);
        acc[2][nf] = __builtin_amdgcn_mfma_f32_16x16x32_bf16(a2, bv, acc[2][nf], 0, 0, 0);
        acc[3][nf] = __builtin_amdgcn_mfma_f32_16x16x32_bf16(a3, bv, acc[3][nf], 0, 0, 0);
      }
    }
  }

#pragma unroll
  for (int mf = 0; mf < 4; mf++) {
    int ob = mf * 16 + (g << 2);
#pragma unroll
    for (int r = 0; r < 4; r++) {
      int o = ob + r;
      float bb = beff[o];
      float* orow = out + ((size_t)(b * 64 + o)) * HWn + h * 128 + half * 64 + l15;
#pragma unroll
      for (int nf = 0; nf < 4; nf++)
        orow[nf * 16] = acc[mf][nf][r] + bb;
    }
  }
}

// ---------------------------------------------------------------------------
// Workspace layout unchanged from R5/R6 (sizes verified in floats):
// Region A [0, 4,596,736): xT -> fusedT (planar, same elem count; after dcnm).
// Region B [4,596,736, 9,536,512): xC -> FsT (after conv1m).
// Region C [9,536,512, 14,322,688): t1T/p1T/t2 -> FdT (after k_feat).
// Tail: feat/theta/wfrag/w2frag/beff/dcnD/weffD @14,322,688.. end 14,444,160.
// ---------------------------------------------------------------------------
extern "C" void kernel_launch(void* const* d_in, const int* in_sizes, int n_in,
                              void* d_out, int out_size, void* d_ws, size_t ws_size,
                              hipStream_t stream)
{
  (void)in_sizes; (void)n_in; (void)out_size; (void)ws_size;
  const float* x      = (const float*)d_in[0];
  const float* offset = (const float*)d_in[1];
  const float* stn_w1 = (const float*)d_in[2];
  const float* stn_b1 = (const float*)d_in[3];
  const float* stn_w2 = (const float*)d_in[4];
  const float* stn_b2 = (const float*)d_in[5];
  const float* fc_w   = (const float*)d_in[6];
  const float* fc_b   = (const float*)d_in[7];
  const float* dcn_w  = (const float*)d_in[8];
  const float* dcn_b  = (const float*)d_in[9];
  const float* wg_w   = (const float*)d_in[10];
  const float* wg_b   = (const float*)d_in[11];
  const float* w3     = (const float*)d_in[12];
  const float* b3     = (const float*)d_in[13];
  const float* w15    = (const float*)d_in[14];
  const float* b15    = (const float*)d_in[15];
  const float* w51    = (const float*)d_in[16];
  const float* b51    = (const float*)d_in[17];
  const float* w1     = (const float*)d_in[18];
  const float* b1     = (const float*)d_in[19];

  float* ws      = (float*)d_ws;
  __bf16* xT     = (__bf16*)ws;
  __bf16* fusedT = (__bf16*)ws;
  __bf16* xC     = (__bf16*)(ws + 4596736);
  __bf16* FsT    = (__bf16*)(ws + 4596736);
  __bf16* t1T    = (__bf16*)(ws + 9536512);
  __bf16* FdT    = (__bf16*)(ws + 9536512);
  __bf16* p1T    = (__bf16*)(ws + 11633664);
  float*  t2     = ws + 12225536;
  float*  feat   = ws + 14322688;
  float*  theta  = ws + 14323200;
  __bf16* wfrag  = (__bf16*)(ws + 14323264);
  __bf16* w2frag = (__bf16*)(ws + 14373440);
  float*  beff   = ws + 14399040;
  __bf16* dcnD   = (__bf16*)(ws + 14399104);
  __bf16* weffD  = (__bf16*)(ws + 14417536);
  float*  out    = (float*)d_out;

  k_prep  <<<1,    64,  0, stream>>>(w1, b3, b15, b51, b1, beff);
  k_xt    <<<1123, 256, 0, stream>>>(x, xT, xC);
  k_wf    <<<392,  256, 0, stream>>>(stn_w1, wfrag);
  k_frag  <<<552,  256, 0, stream>>>(dcn_w, w1, w3, w15, w51, stn_w2, dcnD, weffD, w2frag);
  k_conv1m<<<512,  128, 0, stream>>>(xC, wfrag, stn_b1, t1T);
  k_pool  <<<145,  256, 0, stream>>>(t1T, p1T);
  k_conv2m<<<128,  256, 0, stream>>>(p1T, w2frag, stn_b2, t2);
  k_feat  <<<512,  256, 0, stream>>>(t2, feat);
  k_theta <<<1,    64,  0, stream>>>(feat, fc_w, fc_b, theta);
  k_dcnm  <<<2048, 256, 0, stream>>>(xT, offset, theta, dcnD, dcn_b, FdT, FsT);
  k_fuseT <<<545,  256, 0, stream>>>(FsT, FdT, wg_w, wg_b, fusedT);
  k_elkm  <<<512,  256, 0, stream>>>(fusedT, weffD, beff, out);
}

// Round 13
// 192.035 us; speedup vs baseline: 1.5094x; 1.0957x over previous
//
#include <hip/hip_runtime.h>
#include <math.h>

// Problem dims
#define Bn 8
#define Cn 64
#define Hn 128
#define Wn 128
#define HWn 16384

typedef __attribute__((ext_vector_type(8))) __bf16 bf16x8;
typedef __attribute__((ext_vector_type(4))) __bf16 bf16x4;
typedef __attribute__((ext_vector_type(4))) float f32x4;

// XCD-aware bijective swizzle: grid = 8*chunk blocks.
__device__ __forceinline__ int xcd_swz(int bid, int chunk) {
  return (bid & 7) * chunk + (bid >> 3);
}

// ---------------------------------------------------------------------------
// K-wprep (R13): merged weight prep — wfrag + dcnD + weffD + w2frag + beff.
// ---------------------------------------------------------------------------
__global__ __launch_bounds__(256) void k_wprep(
    const float* __restrict__ stn_w1, const float* __restrict__ dcn_w,
    const float* __restrict__ w1, const float* __restrict__ w3,
    const float* __restrict__ w15, const float* __restrict__ w51,
    const float* __restrict__ stn_w2,
    const float* __restrict__ b3, const float* __restrict__ b15,
    const float* __restrict__ b51, const float* __restrict__ b1,
    __bf16* __restrict__ wfrag, __bf16* __restrict__ dcnD,
    __bf16* __restrict__ weffD, __bf16* __restrict__ w2frag,
    float* __restrict__ beff)
{
  int t = blockIdx.x * 256 + threadIdx.x;
  if (t < 100352) {                       // conv1 A-frags
    int e = t & 7, l = (t >> 3) & 63, o16 = (t >> 9) & 1, ck = (t >> 10) & 1;
    int tap = t >> 11;
    int o = o16 * 16 + (l & 15), c = ck * 32 + (l >> 4) * 8 + e;
    wfrag[t] = (__bf16)stn_w1[(o * 64 + c) * 49 + tap];
    return;
  }
  t -= 100352;
  if (t < 36864) {                        // dcn B-frags
    int e = t & 7, l = (t >> 3) & 63, mf = (t >> 9) & 3, s = (t >> 11) & 1;
    int tap = t >> 12;
    int o = mf * 16 + (l & 15), c = s * 32 + (l >> 4) * 8 + e;
    dcnD[t] = (__bf16)dcn_w[(o * 64 + c) * 9 + tap];
    return;
  }
  t -= 36864;
  if (t < 53248) {                        // collapsed ELK B-frags
    const int DY[13] = {-2,-1,-1,-1, 0, 0, 0, 0, 0, 1, 1, 1, 2};
    const int DX[13] = { 0,-1, 0, 1,-2,-1, 0, 1, 2,-1, 0, 1, 0};
    int e = t & 7, l = (t >> 3) & 63, mf = (t >> 9) & 3, s = (t >> 11) & 1;
    int tap = t >> 12;
    int o = mf * 16 + (l & 15), c = s * 32 + (l >> 4) * 8 + e;
    int dy = DY[tap], dx = DX[tap];
    float v = 0.f;
    if (dy >= -1 && dy <= 1 && dx >= -1 && dx <= 1) {
      int k3 = (dy + 1) * 3 + (dx + 1);
      for (int m = 0; m < 64; m++) v = fmaf(w1[o * 192 + m], w3[(m * 64 + c) * 9 + k3], v);
    }
    if (dy == 0) {
      int k15 = dx + 2;
      for (int m = 0; m < 64; m++) v = fmaf(w1[o * 192 + 64 + m], w15[(m * 64 + c) * 5 + k15], v);
    }
    if (dx == 0) {
      int k51 = dy + 2;
      for (int m = 0; m < 64; m++) v = fmaf(w1[o * 192 + 128 + m], w51[(m * 64 + c) * 5 + k51], v);
    }
    weffD[t] = (__bf16)v;
    return;
  }
  t -= 53248;
  if (t < 51200) {                        // conv2 A-frags
    int e = t & 7, l = (t >> 3) & 63, mf = (t >> 9) & 3;
    int tap = t >> 11;
    int o = mf * 16 + (l & 15), c = (l >> 4) * 8 + e;
    w2frag[t] = (__bf16)stn_w2[(o * 32 + c) * 25 + tap];
    return;
  }
  t -= 51200;
  if (t < 64) {                           // beff
    float s = b1[t];
    for (int m = 0; m < 64; m++) {
      s = fmaf(w1[t * 192 + m],       b3[m],  s);
      s = fmaf(w1[t * 192 + 64 + m],  b15[m], s);
      s = fmaf(w1[t * 192 + 128 + m], b51[m], s);
    }
    beff[t] = s;
  }
}

// ---------------------------------------------------------------------------
// K-xt v2: thread per (pixel, channel-half), 32 loads unrolled to regs.
// ---------------------------------------------------------------------------
__global__ __launch_bounds__(256) void k_xt(const float* __restrict__ x,
                                            __bf16* __restrict__ xT,
                                            __bf16* __restrict__ xC)
{
  int t = blockIdx.x * 256 + threadIdx.x;
  if (t >= 8 * 134 * 134 * 2) return;
  int half = t & 1;
  int p  = t >> 1;
  int wp = p % 134;
  int hp = (p / 134) % 134;
  int b  = p / (134 * 134);
  int h = hp - 3, w = wp - 3;
  bool inb = ((unsigned)h < 128u) && ((unsigned)w < 128u);
  const float* xb = x + (size_t)b * Cn * HWn + (size_t)(half * 32) * HWn + h * 128 + w;

  float v[32];
#pragma unroll
  for (int j = 0; j < 32; j++) v[j] = inb ? xb[(size_t)j * HWn] : 0.f;

  __bf16* dstT = xT + (size_t)p * 64 + half * 32;
#pragma unroll
  for (int g = 0; g < 4; g++) {
    bf16x8 r;
#pragma unroll
    for (int j = 0; j < 8; j++) r[j] = (__bf16)v[g * 8 + j];
    *(bf16x8*)(dstT + g * 8) = r;
    int oct = half * 4 + g;
    *(bf16x8*)(xC + ((((size_t)b * 8 + oct) * 134 + hp) * 144 + wp) * 8) = r;
  }
}

// ---------------------------------------------------------------------------
// K1: STN conv1 via MFMA — R13: 4 waves/block (2x waves/CU vs 128-thr).
// Wave = (row wv>>1, half wv&1): 32 out x 64 px. Same LDS tile/staging.
// ---------------------------------------------------------------------------
__global__ __launch_bounds__(256) void k_conv1m(
    const __bf16* __restrict__ xC, const __bf16* __restrict__ wfrag,
    const float* __restrict__ b1s, __bf16* __restrict__ t1T)
{
  __shared__ alignas(16) char tile[73728];   // [q4][r8][slot144][16B]
  const int lane = threadIdx.x & 63;
  const int wv   = threadIdx.x >> 6;
  const int swz  = xcd_swz(blockIdx.x, 64);
  const int b    = swz >> 6;
  const int h0   = (swz & 63) * 2;
  const int r    = wv >> 1;
  const int hf   = wv & 1;

  f32x4 acc[2][4];
#pragma unroll
  for (int o16 = 0; o16 < 2; o16++)
#pragma unroll
    for (int nf = 0; nf < 4; nf++) acc[o16][nf] = (f32x4){0.f, 0.f, 0.f, 0.f};

  const bf16x8* wf = (const bf16x8*)wfrag;
  const char* tb = (const char*)tile;
  const char* xCb = (const char*)xC;

  for (int ck = 0; ck < 2; ck++) {
    for (int i = wv; i < 72; i += 4) {
      int q = i / 18;
      int t = i - q * 18;
      const char* src = xCb
          + (((size_t)(b * 8 + ck * 4 + q) * 134 + h0) * 2304) + t * 1024 + lane * 16;
      char* dst = (char*)tile + i * 1024;
      __builtin_amdgcn_global_load_lds(
          (const __attribute__((address_space(1))) void*)src,
          (__attribute__((address_space(3))) void*)dst, 16, 0, 0);
    }
    __syncthreads();

    for (int tap = 0; tap < 49; tap++) {
      int dy7 = tap / 7;
      int dx7 = tap - dy7 * 7;
      bf16x8 a0 = wf[((tap * 2 + ck) * 2 + 0) * 64 + lane];
      bf16x8 a1 = wf[((tap * 2 + ck) * 2 + 1) * 64 + lane];
      const char* bp = tb + (lane >> 4) * 18432 + (r + dy7) * 2304
                          + (dx7 + hf * 64 + (lane & 15)) * 16;
#pragma unroll
      for (int nf = 0; nf < 4; nf++) {
        bf16x8 bv = *(const bf16x8*)(bp + nf * 256);
        acc[0][nf] = __builtin_amdgcn_mfma_f32_16x16x32_bf16(a0, bv, acc[0][nf], 0, 0, 0);
        acc[1][nf] = __builtin_amdgcn_mfma_f32_16x16x32_bf16(a1, bv, acc[1][nf], 0, 0, 0);
      }
    }
    __syncthreads();
  }

  int h = h0 + r;
#pragma unroll
  for (int o16 = 0; o16 < 2; o16++) {
    int ob = o16 * 16 + ((lane >> 4) << 2);
    float bb0 = b1s[ob], bb1 = b1s[ob + 1], bb2 = b1s[ob + 2], bb3 = b1s[ob + 3];
#pragma unroll
    for (int nf = 0; nf < 4; nf++) {
      int px = hf * 64 + nf * 16 + (lane & 15);
      bf16x4 rr;
      rr[0] = (__bf16)fmaxf(acc[o16][nf][0] + bb0, 0.f);
      rr[1] = (__bf16)fmaxf(acc[o16][nf][1] + bb1, 0.f);
      rr[2] = (__bf16)fmaxf(acc[o16][nf][2] + bb2, 0.f);
      rr[3] = (__bf16)fmaxf(acc[o16][nf][3] + bb3, 0.f);
      *(bf16x4*)(t1T + (((size_t)(b * 128 + h) * 128 + px)) * 32 + ob) = rr;
    }
  }
}

// ---------------------------------------------------------------------------
// K2: maxpool 2x2 -> p1T[b][hp68][wp68][32ch] bf16, zero-padded 2 ring.
// ---------------------------------------------------------------------------
__global__ __launch_bounds__(256) void k_pool(const __bf16* __restrict__ t1T,
                                              __bf16* __restrict__ p1T)
{
  int id = blockIdx.x * 256 + threadIdx.x;
  if (id >= 8 * 68 * 68) return;
  int wp = id % 68, hp = (id / 68) % 68, b = id / (68 * 68);
  __bf16* dst = p1T + (size_t)id * 32;
  int ph = hp - 2, pw = wp - 2;
  if (((unsigned)ph >= 64u) || ((unsigned)pw >= 64u)) {
    bf16x8 z = {};
#pragma unroll
    for (int g = 0; g < 4; g++) *(bf16x8*)(dst + g * 8) = z;
    return;
  }
  const __bf16* s = t1T + (((size_t)(b * 128) + ph * 2) * 128 + pw * 2) * 32;
#pragma unroll
  for (int g = 0; g < 4; g++) {
    bf16x8 v0 = *(const bf16x8*)(s + g * 8);
    bf16x8 v1 = *(const bf16x8*)(s + 32 + g * 8);
    bf16x8 v2 = *(const bf16x8*)(s + 4096 + g * 8);
    bf16x8 v3 = *(const bf16x8*)(s + 4128 + g * 8);
    bf16x8 r;
#pragma unroll
    for (int j = 0; j < 8; j++) {
      float m = fmaxf(fmaxf((float)v0[j], (float)v1[j]),
                      fmaxf((float)v2[j], (float)v3[j]));
      r[j] = (__bf16)m;
    }
    *(bf16x8*)(dst + g * 8) = r;
  }
}

// ---------------------------------------------------------------------------
// K3: conv2 via MFMA.
// ---------------------------------------------------------------------------
__global__ __launch_bounds__(256) void k_conv2m(
    const __bf16* __restrict__ p1T, const __bf16* __restrict__ w2frag,
    const float* __restrict__ b2s, float* __restrict__ t2)
{
  __shared__ alignas(16) char tile[34816];   // 8*68*64
  const int lane = threadIdx.x & 63;
  const int wv   = threadIdx.x >> 6;
  const int b    = blockIdx.x >> 4;
  const int h0   = (blockIdx.x & 15) * 4;

  f32x4 acc[4][4];
#pragma unroll
  for (int mf = 0; mf < 4; mf++)
#pragma unroll
    for (int nf = 0; nf < 4; nf++) acc[mf][nf] = (f32x4){0.f, 0.f, 0.f, 0.f};

  const char* src0 = (const char*)p1T + (((size_t)b * 68 + h0) * 68) * 64;
  for (int i = wv; i < 34; i += 4) {
    __builtin_amdgcn_global_load_lds(
        (const __attribute__((address_space(1))) void*)(src0 + i * 1024 + lane * 16),
        (__attribute__((address_space(3))) void*)((char*)tile + i * 1024), 16, 0, 0);
  }
  __syncthreads();

  const bf16x8* wf = (const bf16x8*)w2frag;
  const char* tb = (const char*)tile;
  for (int tap = 0; tap < 25; tap++) {
    int ky = tap / 5, kx = tap - ky * 5;
    bf16x8 a0 = wf[(tap * 4 + 0) * 64 + lane];
    bf16x8 a1 = wf[(tap * 4 + 1) * 64 + lane];
    bf16x8 a2 = wf[(tap * 4 + 2) * 64 + lane];
    bf16x8 a3 = wf[(tap * 4 + 3) * 64 + lane];
    const char* bp = tb + (((wv + ky) * 68 + kx + (lane & 15)) * 64) + (lane >> 4) * 16;
#pragma unroll
    for (int nf = 0; nf < 4; nf++) {
      bf16x8 bv = *(const bf16x8*)(bp + nf * 1024);
      acc[0][nf] = __builtin_amdgcn_mfma_f32_16x16x32_bf16(a0, bv, acc[0][nf], 0, 0, 0);
      acc[1][nf] = __builtin_amdgcn_mfma_f32_16x16x32_bf16(a1, bv, acc[1][nf], 0, 0, 0);
      acc[2][nf] = __builtin_amdgcn_mfma_f32_16x16x32_bf16(a2, bv, acc[2][nf], 0, 0, 0);
      acc[3][nf] = __builtin_amdgcn_mfma_f32_16x16x32_bf16(a3, bv, acc[3][nf], 0, 0, 0);
    }
  }

  int h = h0 + wv;
#pragma unroll
  for (int mf = 0; mf < 4; mf++) {
    int ob = mf * 16 + ((lane >> 4) << 2);
#pragma unroll
    for (int r = 0; r < 4; r++) {
      float bb = b2s[ob + r];
      float* orow = t2 + ((size_t)(b * 64 + ob + r)) * 4096 + h * 64 + (lane & 15);
#pragma unroll
      for (int nf = 0; nf < 4; nf++)
        orow[nf * 16] = fmaxf(acc[mf][nf][r] + bb, 0.f);
    }
  }
}

// ---------------------------------------------------------------------------
// K3b: deterministic spatial sum -> feat[b*64+co].
// ---------------------------------------------------------------------------
__global__ __launch_bounds__(256) void k_feat(const float* __restrict__ t2, float* __restrict__ feat)
{
  __shared__ float red[256];
  int bc = blockIdx.x;
  const float* s = t2 + (size_t)bc * 4096;
  float v = 0.f;
  for (int i = threadIdx.x; i < 4096; i += 256) v += s[i];
  red[threadIdx.x] = v;
  __syncthreads();
  for (int st = 128; st > 0; st >>= 1) {
    if (threadIdx.x < st) red[threadIdx.x] += red[threadIdx.x + st];
    __syncthreads();
  }
  if (threadIdx.x == 0) feat[bc] = red[0];
}

// ---------------------------------------------------------------------------
// K4: theta
// ---------------------------------------------------------------------------
__global__ void k_theta(const float* __restrict__ feat, const float* __restrict__ fc_w,
                        const float* __restrict__ fc_b, float* __restrict__ theta)
{
  int tid = threadIdx.x;
  if (tid >= 48) return;
  int b = tid / 6, i = tid - b * 6;
  float s = 0.f;
  for (int k = 0; k < 64; k++) s = fmaf(feat[b * 64 + k], fc_w[i * 64 + k], s);
  theta[tid] = fmaf(s, 1.f / 4096.f, fc_b[i]);
}

// ---------------------------------------------------------------------------
// Shared bilinear corner-address helper (clamped + masked weights).
// ---------------------------------------------------------------------------
__device__ __forceinline__ void bilin_setup(
    const __bf16* __restrict__ xb, float sy, float sx,
    const __bf16*& c00, const __bf16*& c01,
    const __bf16*& c10, const __bf16*& c11,
    float& w00, float& w01, float& w10, float& w11)
{
  float y0f = floorf(sy), x0f = floorf(sx);
  float wy1 = sy - y0f, wy0 = 1.f - wy1;
  float wx1 = sx - x0f, wx0 = 1.f - wx1;
  bool vy0 = (y0f >= 0.f) && (y0f <= 127.f);
  bool vy1 = (y0f >= -1.f) && (y0f <= 126.f);
  bool vx0 = (x0f >= 0.f) && (x0f <= 127.f);
  bool vx1 = (x0f >= -1.f) && (x0f <= 126.f);
  int yi0 = (int)fminf(fmaxf(y0f, 0.f), 127.f);
  int yi1 = (int)fminf(fmaxf(y0f + 1.f, 0.f), 127.f);
  int xi0 = (int)fminf(fmaxf(x0f, 0.f), 127.f);
  int xi1 = (int)fminf(fmaxf(x0f + 1.f, 0.f), 127.f);
  w00 = wy0 * wx0 * ((vy0 && vx0) ? 1.f : 0.f);
  w01 = wy0 * wx1 * ((vy0 && vx1) ? 1.f : 0.f);
  w10 = wy1 * wx0 * ((vy1 && vx0) ? 1.f : 0.f);
  w11 = wy1 * wx1 * ((vy1 && vx1) ? 1.f : 0.f);
  c00 = xb + ((size_t)((yi0 + 3) * 134) + xi0 + 3) * 64;
  c01 = xb + ((size_t)((yi0 + 3) * 134) + xi1 + 3) * 64;
  c10 = xb + ((size_t)((yi1 + 3) * 134) + xi0 + 3) * 64;
  c11 = xb + ((size_t)((yi1 + 3) * 134) + xi1 + 3) * 64;
}

// ---------------------------------------------------------------------------
// K6: deformable conv + fused STN sample — R13: 1-WAVE BLOCKS (64 thr).
// Waves are fully independent (per-wave LDS, no barriers); 4-wave blocks
// were capping residency at ~8 waves/CU (Occupancy 25%). 1-wave blocks let
// the CU pack to the VGPR limit (~24 waves/CU) -> TLP hides gather latency.
// Quad-coalesced gathers (R11) + tap-parity LDS double-buffer retained.
// ---------------------------------------------------------------------------
__global__ __launch_bounds__(64) void k_dcnm(
    const __bf16* __restrict__ xT, const float* __restrict__ off,
    const float* __restrict__ theta,
    const __bf16* __restrict__ dcnD, const float* __restrict__ dcn_b,
    __bf16* __restrict__ FdT, __bf16* __restrict__ FsT)
{
  __shared__ alignas(16) char smem[2][2048];
  const int lane = threadIdx.x;
  const int swz  = xcd_swz(blockIdx.x, 1024);
  const int b    = swz >> 10;
  const int rem  = swz & 1023;
  const int h    = rem >> 3;
  const int px0  = (rem & 7) * 16;
  const int l15  = lane & 15;
  const int g    = lane >> 4;
  const int pg   = lane >> 2;          // gather pixel 0..15
  const int q    = lane & 3;           // 16B chunk within 64B half
  const int wg   = px0 + pg;           // gather lane's pixel column

  const __bf16* xb = xT + (size_t)b * 134 * 134 * 64;

  // offsets for the gather pixel (quad-uniform -> broadcast)
  const float* ob = off + (size_t)b * 18 * HWn + h * 128 + wg;
  float offs[18];
#pragma unroll
  for (int i = 0; i < 18; i++) offs[i] = ob[(size_t)i * HWn];

  // ---- fused STN sample: blend + coalesced store to FsT ----
  {
    const float* t = theta + b * 6;
    float xn = (float)(2 * wg + 1) * (1.f / 128.f) - 1.f;
    float yn = (float)(2 * h + 1) * (1.f / 128.f) - 1.f;
    float gxv = t[0] * xn + t[1] * yn + t[2];
    float gyv = t[3] * xn + t[4] * yn + t[5];
    float ix = fmaf(gxv, 64.f, 63.5f);
    float iy = fmaf(gyv, 64.f, 63.5f);
    const __bf16 *c00, *c01, *c10, *c11;
    float w00, w01, w10, w11;
    bilin_setup(xb, iy, ix, c00, c01, c10, c11, w00, w01, w10, w11);
    __bf16* dst = FsT + ((size_t)b * HWn + h * 128 + wg) * 64;
#pragma unroll
    for (int s = 0; s < 2; s++) {
      int eo = q * 8 + s * 32;
      bf16x8 v00 = *(const bf16x8*)(c00 + eo);
      bf16x8 v01 = *(const bf16x8*)(c01 + eo);
      bf16x8 v10 = *(const bf16x8*)(c10 + eo);
      bf16x8 v11 = *(const bf16x8*)(c11 + eo);
      bf16x8 r;
#pragma unroll
      for (int j = 0; j < 8; j++) {
        float f = w00 * (float)v00[j] + w01 * (float)v01[j]
                + w10 * (float)v10[j] + w11 * (float)v11[j];
        r[j] = (__bf16)f;
      }
      *(bf16x8*)(dst + eo) = r;
    }
  }

  // ---- deformable conv: 9 taps, double-buffered LDS ----
  f32x4 acc[4];
#pragma unroll
  for (int mf = 0; mf < 4; mf++) acc[mf] = (f32x4){0.f, 0.f, 0.f, 0.f};
  const bf16x8* aD = (const bf16x8*)dcnD;

#pragma unroll
  for (int k = 0; k < 9; k++) {
    char* sm = smem[k & 1];
    float sy = (float)(h + k / 3 - 1) + offs[2 * k];
    float sx = (float)(wg + k % 3 - 1) + offs[2 * k + 1];
    const __bf16 *c00, *c01, *c10, *c11;
    float w00, w01, w10, w11;
    bilin_setup(xb, sy, sx, c00, c01, c10, c11, w00, w01, w10, w11);

    // gather (quad-coalesced), blend, LDS write (swizzled)
#pragma unroll
    for (int s = 0; s < 2; s++) {
      int eo = q * 8 + s * 32;
      bf16x8 v00 = *(const bf16x8*)(c00 + eo);
      bf16x8 v01 = *(const bf16x8*)(c01 + eo);
      bf16x8 v10 = *(const bf16x8*)(c10 + eo);
      bf16x8 v11 = *(const bf16x8*)(c11 + eo);
      bf16x8 r;
#pragma unroll
      for (int j = 0; j < 8; j++) {
        float f = w00 * (float)v00[j] + w01 * (float)v01[j]
                + w10 * (float)v10[j] + w11 * (float)v11[j];
        r[j] = (__bf16)f;
      }
      int c = s * 4 + q;
      *(bf16x8*)(sm + pg * 128 + ((c ^ (pg & 7)) * 16)) = r;
    }

    // fragment read (swizzled) + MFMA; same-wave lockstep, no barrier
#pragma unroll
    for (int s = 0; s < 2; s++) {
      int c = s * 4 + g;
      bf16x8 a = *(const bf16x8*)(sm + l15 * 128 + ((c ^ (l15 & 7)) * 16));
      acc[0] = __builtin_amdgcn_mfma_f32_16x16x32_bf16(
          a, aD[((k * 2 + s) * 4 + 0) * 64 + lane], acc[0], 0, 0, 0);
      acc[1] = __builtin_amdgcn_mfma_f32_16x16x32_bf16(
          a, aD[((k * 2 + s) * 4 + 1) * 64 + lane], acc[1], 0, 0, 0);
      acc[2] = __builtin_amdgcn_mfma_f32_16x16x32_bf16(
          a, aD[((k * 2 + s) * 4 + 2) * 64 + lane], acc[2], 0, 0, 0);
      acc[3] = __builtin_amdgcn_mfma_f32_16x16x32_bf16(
          a, aD[((k * 2 + s) * 4 + 3) * 64 + lane], acc[3], 0, 0, 0);
    }
  }

  // ---- epilogue: D row(pixel)=g*4+r, col(out)=mf*16+l15 ----
  __bf16* fb = FdT + ((size_t)b * HWn + h * 128 + px0) * 64;
#pragma unroll
  for (int mf = 0; mf < 4; mf++) {
    int o = mf * 16 + l15;
    float bias = dcn_b[o];
#pragma unroll
    for (int r = 0; r < 4; r++) {
      int pxl = g * 4 + r;
      fb[(size_t)pxl * 64 + o] = (__bf16)(acc[mf][r] + bias);
    }
  }
}

// ---------------------------------------------------------------------------
// K7: fusion -> fusedT bf16 OCTET-PLANAR [b][oct8][132][132][8ch], 2-pad ring.
// ---------------------------------------------------------------------------
#define FPL ((size_t)132 * 132 * 8)
__global__ __launch_bounds__(256) void k_fuseT(
    const __bf16* __restrict__ FsT, const __bf16* __restrict__ FdT,
    const float* __restrict__ wg_w, const float* __restrict__ wg_b,
    __bf16* __restrict__ fusedT)
{
  int id = blockIdx.x * 256 + threadIdx.x;
  if (id >= 8 * 132 * 132) return;
  int wp = id % 132;
  int hp = (id / 132) % 132;
  int b  = id / (132 * 132);
  size_t ppix = (size_t)(hp * 132 + wp) * 8;
  int h = hp - 2, w = wp - 2;
  if (((unsigned)h >= 128u) || ((unsigned)w >= 128u)) {
    bf16x8 z = {};
#pragma unroll
    for (int oct = 0; oct < 8; oct++)
      *(bf16x8*)(fusedT + ((size_t)b * 8 + oct) * FPL + ppix) = z;
    return;
  }
  const bf16x8* fs = (const bf16x8*)(FsT + ((size_t)b * HWn + h * 128 + w) * 64);
  const bf16x8* fd = (const bf16x8*)(FdT + ((size_t)b * HWn + h * 128 + w) * 64);
  bf16x8 fsv[8], fdv[8];
  float s0 = wg_b[0], s1 = wg_b[1];
#pragma unroll
  for (int oct = 0; oct < 8; oct++) {
    fsv[oct] = fs[oct];
    fdv[oct] = fd[oct];
#pragma unroll
    for (int j = 0; j < 8; j++) {
      int c = oct * 8 + j;
      float a = (float)fsv[oct][j], d = (float)fdv[oct][j];
      s0 = fmaf(wg_w[c],       a, fmaf(wg_w[64 + c],  d, s0));
      s1 = fmaf(wg_w[128 + c], a, fmaf(wg_w[192 + c], d, s1));
    }
  }
  float p0 = 1.f / (1.f + __expf(s1 - s0));
  float p1 = 1.f - p0;
#pragma unroll
  for (int oct = 0; oct < 8; oct++) {
    bf16x8 r;
#pragma unroll
    for (int j = 0; j < 8; j++)
      r[j] = (__bf16)(p0 * (float)fsv[oct][j] + p1 * (float)fdv[oct][j]);
    *(bf16x8*)(fusedT + ((size_t)b * 8 + oct) * FPL + ppix) = r;
  }
}

// ---------------------------------------------------------------------------
// K8: collapsed ELK via MFMA, planar fusedT reads (quad-coalesced).
// ---------------------------------------------------------------------------
__global__ __launch_bounds__(256) void k_elkm(
    const __bf16* __restrict__ fusedT, const __bf16* __restrict__ weffD,
    const float* __restrict__ beff, float* __restrict__ out)
{
  const int DY[13] = {-2,-1,-1,-1, 0, 0, 0, 0, 0, 1, 1, 1, 2};
  const int DX[13] = { 0,-1, 0, 1,-2,-1, 0, 1, 2,-1, 0, 1, 0};
  const int lane = threadIdx.x & 63;
  const int wv   = threadIdx.x >> 6;
  const int swz  = xcd_swz(blockIdx.x, 64);
  const int b    = swz >> 6;
  const int h    = (swz & 63) * 2 + (wv >> 1);
  const int half = wv & 1;
  const int l15  = lane & 15;
  const int g    = lane >> 4;

  f32x4 acc[4][4];
#pragma unroll
  for (int mf = 0; mf < 4; mf++)
#pragma unroll
    for (int nf = 0; nf < 4; nf++) acc[mf][nf] = (f32x4){0.f, 0.f, 0.f, 0.f};

  const bf16x8* aD = (const bf16x8*)weffD;
  const __bf16* pl0 = fusedT + ((size_t)b * 8 + g) * FPL;      // s=0 plane
  const __bf16* pl1 = pl0 + 4 * FPL;                            // s=1 plane

  for (int t = 0; t < 13; t++) {
    int hp = h + 2 + DY[t];
    size_t rowb = (size_t)(hp * 132 + half * 64 + 2 + DX[t] + l15) * 8;
#pragma unroll
    for (int s = 0; s < 2; s++) {
      const __bf16* pl = s ? pl1 : pl0;
      bf16x8 a0 = aD[((t * 2 + s) * 4 + 0) * 64 + lane];
      bf16x8 a1 = aD[((t * 2 + s) * 4 + 1) * 64 + lane];
      bf16x8 a2 = aD[((t * 2 + s) * 4 + 2) * 64 + lane];
      bf16x8 a3 = aD[((t * 2 + s) * 4 + 3) * 64 + lane];
#pragma unroll
      for (int nf = 0; nf < 4; nf++) {
        bf16x8 bv = *(const bf16x8*)(pl + rowb + (size_t)nf * 128);
        acc[0][nf] = __builtin_amdgcn_mfma_f32_16x16x32_bf16(a0, bv, acc[0][nf], 0, 0, 0);
        acc[1][nf] = __builtin_amdgcn_mfma_f32_16x16x32_bf16(a1, bv, acc[1][nf], 0, 0, 0);
        acc[2][nf] = __builtin_amdgcn_mfma_f32_16x16x32_bf16(a2, bv, acc[2][nf], 0, 0, 0);
        acc[3][nf] = __builtin_amdgcn_mfma_f32_16x16x32_bf16(a3, bv, acc[3][nf], 0, 0, 0);
      }
    }
  }

#pragma unroll
  for (int mf = 0; mf < 4; mf++) {
    int ob = mf * 16 + (g << 2);
#pragma unroll
    for (int r = 0; r < 4; r++) {
      int o = ob + r;
      float bb = beff[o];
      float* orow = out + ((size_t)(b * 64 + o)) * HWn + h * 128 + half * 64 + l15;
#pragma unroll
      for (int nf = 0; nf < 4; nf++)
        orow[nf * 16] = acc[mf][nf][r] + bb;
    }
  }
}

// ---------------------------------------------------------------------------
// Workspace layout unchanged from R5/R6 (sizes verified in floats):
// Region A [0, 4,596,736): xT -> fusedT (planar, same elem count; after dcnm).
// Region B [4,596,736, 9,536,512): xC -> FsT (after conv1m).
// Region C [9,536,512, 14,322,688): t1T/p1T/t2 -> FdT (after k_feat).
// Tail: feat/theta/wfrag/w2frag/beff/dcnD/weffD @14,322,688.. end 14,444,160.
// ---------------------------------------------------------------------------
extern "C" void kernel_launch(void* const* d_in, const int* in_sizes, int n_in,
                              void* d_out, int out_size, void* d_ws, size_t ws_size,
                              hipStream_t stream)
{
  (void)in_sizes; (void)n_in; (void)out_size; (void)ws_size;
  const float* x      = (const float*)d_in[0];
  const float* offset = (const float*)d_in[1];
  const float* stn_w1 = (const float*)d_in[2];
  const float* stn_b1 = (const float*)d_in[3];
  const float* stn_w2 = (const float*)d_in[4];
  const float* stn_b2 = (const float*)d_in[5];
  const float* fc_w   = (const float*)d_in[6];
  const float* fc_b   = (const float*)d_in[7];
  const float* dcn_w  = (const float*)d_in[8];
  const float* dcn_b  = (const float*)d_in[9];
  const float* wg_w   = (const float*)d_in[10];
  const float* wg_b   = (const float*)d_in[11];
  const float* w3     = (const float*)d_in[12];
  const float* b3     = (const float*)d_in[13];
  const float* w15    = (const float*)d_in[14];
  const float* b15    = (const float*)d_in[15];
  const float* w51    = (const float*)d_in[16];
  const float* b51    = (const float*)d_in[17];
  const float* w1     = (const float*)d_in[18];
  const float* b1     = (const float*)d_in[19];

  float* ws      = (float*)d_ws;
  __bf16* xT     = (__bf16*)ws;
  __bf16* fusedT = (__bf16*)ws;
  __bf16* xC     = (__bf16*)(ws + 4596736);
  __bf16* FsT    = (__bf16*)(ws + 4596736);
  __bf16* t1T    = (__bf16*)(ws + 9536512);
  __bf16* FdT    = (__bf16*)(ws + 9536512);
  __bf16* p1T    = (__bf16*)(ws + 11633664);
  float*  t2     = ws + 12225536;
  float*  feat   = ws + 14322688;
  float*  theta  = ws + 14323200;
  __bf16* wfrag  = (__bf16*)(ws + 14323264);
  __bf16* w2frag = (__bf16*)(ws + 14373440);
  float*  beff   = ws + 14399040;
  __bf16* dcnD   = (__bf16*)(ws + 14399104);
  __bf16* weffD  = (__bf16*)(ws + 14417536);
  float*  out    = (float*)d_out;

  k_wprep <<<945,  256, 0, stream>>>(stn_w1, dcn_w, w1, w3, w15, w51, stn_w2,
                                     b3, b15, b51, b1,
                                     wfrag, dcnD, weffD, w2frag, beff);
  k_xt    <<<1123, 256, 0, stream>>>(x, xT, xC);
  k_conv1m<<<512,  256, 0, stream>>>(xC, wfrag, stn_b1, t1T);
  k_pool  <<<145,  256, 0, stream>>>(t1T, p1T);
  k_conv2m<<<128,  256, 0, stream>>>(p1T, w2frag, stn_b2, t2);
  k_feat  <<<512,  256, 0, stream>>>(t2, feat);
  k_theta <<<1,    64,  0, stream>>>(feat, fc_w, fc_b, theta);
  k_dcnm  <<<8192, 64,  0, stream>>>(xT, offset, theta, dcnD, dcn_b, FdT, FsT);
  k_fuseT <<<545,  256, 0, stream>>>(FsT, FdT, wg_w, wg_b, fusedT);
  k_elkm  <<<512,  256, 0, stream>>>(fusedT, weffD, beff, out);
}